// Round 4
// baseline (681.514 us; speedup 1.0000x reference)
//
#include <hip/hip_runtime.h>

#define N_NODES 100000
#define N_EDGES 1600000
#define DIM 128
#define NBUK 391      // ceil(N_NODES / 256), bucket = dst >> 8
#define EPB 4096      // edges per block in hist / phaseA
#define NBLK 391      // ceil(N_EDGES / EPB)
#define CAP 38        // per-(block,bucket) LDS bin capacity
#define CAPB 5120     // max edges per bucket (mean 4092, +16 sigma)

// ---------------------------------------------------------------------------
// 1) bucket histogram: LDS-staged, 153K global atomics total
// ---------------------------------------------------------------------------
__global__ __launch_bounds__(256) void bucket_hist(
    const int* __restrict__ ei, int* __restrict__ bk_cnt)
{
    __shared__ int cnt[NBUK];
    for (int i = threadIdx.x; i < NBUK; i += 256) cnt[i] = 0;
    __syncthreads();
    int e0 = blockIdx.x * EPB;
    int e1 = min(e0 + EPB, N_EDGES);
    for (int e = e0 + threadIdx.x; e < e1; e += 256)
        atomicAdd(&cnt[ei[N_EDGES + e] >> 8], 1);
    __syncthreads();
    for (int b = threadIdx.x; b < NBUK; b += 256)
        if (cnt[b]) atomicAdd(&bk_cnt[b], cnt[b]);
}

// ---------------------------------------------------------------------------
// 2) scan of 391 bucket counts -> bk_base[0..NBUK], bk_cur
// ---------------------------------------------------------------------------
__global__ __launch_bounds__(512) void bucket_scan(
    int* __restrict__ bk, int* __restrict__ bk_cur)
{
    __shared__ int s[512];
    int t = threadIdx.x;
    int v = (t < NBUK) ? bk[t] : 0;
    s[t] = v;
    __syncthreads();
    for (int off = 1; off < 512; off <<= 1) {
        int x = (t >= off) ? s[t - off] : 0;
        __syncthreads();
        s[t] += x;
        __syncthreads();
    }
    if (t < NBUK) {
        bk[t + 1] = s[t];          // inclusive -> base[t+1]
        bk_cur[t] = s[t] - v;      // exclusive = run cursor start
    }
    if (t == 0) bk[0] = 0;
}

// ---------------------------------------------------------------------------
// 3) phase A: bin edges by bucket via LDS, flush contiguous runs.
// payload = src | attr<<17 | dst_local<<19  (17+2+8 = 27 bits)
// ---------------------------------------------------------------------------
__global__ __launch_bounds__(256) void phaseA_bin(
    const int* __restrict__ ei, const int* __restrict__ ea,
    int* __restrict__ bk_cur, int* __restrict__ ebuf)
{
    __shared__ int cnt[NBUK];
    __shared__ int bins[NBUK * CAP];
    for (int i = threadIdx.x; i < NBUK; i += 256) cnt[i] = 0;
    __syncthreads();

    int e0 = blockIdx.x * EPB;
    int e1 = min(e0 + EPB, N_EDGES);
    for (int e = e0 + threadIdx.x; e < e1; e += 256) {
        int src = ei[e];
        int dst = ei[N_EDGES + e];
        int at  = ea[e];
        int pay = src | (at << 17) | ((dst & 255) << 19);
        int b   = dst >> 8;
        int i   = atomicAdd(&cnt[b], 1);
        if (i < CAP) bins[b * CAP + i] = pay;
        else { int p = atomicAdd(&bk_cur[b], 1); ebuf[p] = pay; }  // spill (≈never)
    }
    __syncthreads();

    int lane = threadIdx.x & 63;
    for (int b = threadIdx.x >> 6; b < NBUK; b += 4) {
        int c = min(cnt[b], CAP);
        if (!c) continue;
        int pos = 0;
        if (lane == 0) pos = atomicAdd(&bk_cur[b], c);
        pos = __shfl(pos, 0);
        if (lane < c) ebuf[pos + lane] = bins[b * CAP + lane];
    }
}

// ---------------------------------------------------------------------------
// 4) phase B: per-bucket node sort. Writes rs[] and node-sorted col[].
// ---------------------------------------------------------------------------
__global__ __launch_bounds__(256) void phaseB_sort(
    const int* __restrict__ bk, const int* __restrict__ ebuf,
    int* __restrict__ rs, int* __restrict__ col)
{
    __shared__ int eb[CAPB];
    __shared__ int deg[256];
    __shared__ int cur[256];
    __shared__ int s[256];

    int b = blockIdx.x;
    int lo = bk[b], hi = bk[b + 1];
    int n_e = hi - lo;
    int t = threadIdx.x;

    for (int i = t; i < n_e; i += 256) eb[i] = ebuf[lo + i];
    deg[t] = 0;
    __syncthreads();

    for (int i = t; i < n_e; i += 256)
        atomicAdd(&deg[((unsigned)eb[i] >> 19)], 1);
    __syncthreads();

    int v = deg[t];
    s[t] = v;
    __syncthreads();
    for (int off = 1; off < 256; off <<= 1) {
        int x = (t >= off) ? s[t - off] : 0;
        __syncthreads();
        s[t] += x;
        __syncthreads();
    }
    int excl = s[t] - v;
    cur[t] = excl;
    int node = b * 256 + t;
    if (node < N_NODES) rs[node] = lo + excl;
    if (b == NBUK - 1 && t == 0) rs[N_NODES] = N_EDGES;
    __syncthreads();

    for (int i = t; i < n_e; i += 256) {
        int pk = eb[i];
        int p = atomicAdd(&cur[(unsigned)pk >> 19], 1);
        col[lo + p] = pk;
    }
}

// ---------------------------------------------------------------------------
// Gather aggregation: 32 lanes per node, float4 per lane, x4 unrolled edges.
// ---------------------------------------------------------------------------
__global__ __launch_bounds__(256) void gather_kernel(
    const float* __restrict__ x,
    const float* __restrict__ emb,
    const int* __restrict__ rs,
    const int* __restrict__ col,
    const float* __restrict__ eps_p,
    float* __restrict__ hbuf)
{
    int gid = blockIdx.x * 256 + threadIdx.x;
    int n = gid >> 5;
    if (n >= N_NODES) return;
    int c = gid & 31;

    int start = rs[n], end = rs[n + 1];
    float4 acc = make_float4(0.f, 0.f, 0.f, 0.f);

    int p = start;
    for (; p + 4 <= end; p += 4) {
        int pk0 = col[p + 0];
        int pk1 = col[p + 1];
        int pk2 = col[p + 2];
        int pk3 = col[p + 3];
        float4 x0 = ((const float4*)(x + (size_t)(pk0 & 0x1FFFF) * DIM))[c];
        float4 x1 = ((const float4*)(x + (size_t)(pk1 & 0x1FFFF) * DIM))[c];
        float4 x2 = ((const float4*)(x + (size_t)(pk2 & 0x1FFFF) * DIM))[c];
        float4 x3 = ((const float4*)(x + (size_t)(pk3 & 0x1FFFF) * DIM))[c];
        float4 e0 = ((const float4*)(emb + (size_t)(((unsigned)pk0 >> 17) & 3) * DIM))[c];
        float4 e1 = ((const float4*)(emb + (size_t)(((unsigned)pk1 >> 17) & 3) * DIM))[c];
        float4 e2 = ((const float4*)(emb + (size_t)(((unsigned)pk2 >> 17) & 3) * DIM))[c];
        float4 e3 = ((const float4*)(emb + (size_t)(((unsigned)pk3 >> 17) & 3) * DIM))[c];
        acc.x += fmaxf(x0.x + e0.x, 0.f) + fmaxf(x1.x + e1.x, 0.f)
               + fmaxf(x2.x + e2.x, 0.f) + fmaxf(x3.x + e3.x, 0.f);
        acc.y += fmaxf(x0.y + e0.y, 0.f) + fmaxf(x1.y + e1.y, 0.f)
               + fmaxf(x2.y + e2.y, 0.f) + fmaxf(x3.y + e3.y, 0.f);
        acc.z += fmaxf(x0.z + e0.z, 0.f) + fmaxf(x1.z + e1.z, 0.f)
               + fmaxf(x2.z + e2.z, 0.f) + fmaxf(x3.z + e3.z, 0.f);
        acc.w += fmaxf(x0.w + e0.w, 0.f) + fmaxf(x1.w + e1.w, 0.f)
               + fmaxf(x2.w + e2.w, 0.f) + fmaxf(x3.w + e3.w, 0.f);
    }
    for (; p < end; ++p) {
        int pk = col[p];
        float4 xv = ((const float4*)(x + (size_t)(pk & 0x1FFFF) * DIM))[c];
        float4 ev = ((const float4*)(emb + (size_t)(((unsigned)pk >> 17) & 3) * DIM))[c];
        acc.x += fmaxf(xv.x + ev.x, 0.f);
        acc.y += fmaxf(xv.y + ev.y, 0.f);
        acc.z += fmaxf(xv.z + ev.z, 0.f);
        acc.w += fmaxf(xv.w + ev.w, 0.f);
    }

    float epsv = 1.0f + eps_p[0];
    float4 xn = ((const float4*)(x + (size_t)n * DIM))[c];
    float4 o;
    o.x = epsv * xn.x + acc.x;
    o.y = epsv * xn.y + acc.y;
    o.z = epsv * xn.z + acc.z;
    o.w = epsv * xn.w + acc.w;
    ((float4*)(hbuf + (size_t)n * DIM))[c] = o;
}

// ---------------------------------------------------------------------------
// MLP1 in-place: h1 = relu(LN(h@W1 + b1)). 32-node tile, thread = 4 nodes x 4 cols.
// ---------------------------------------------------------------------------
__global__ __launch_bounds__(256) void gine_mlp1(
    float* __restrict__ hio,
    const float* __restrict__ W1,
    const float* __restrict__ b1,
    const float* __restrict__ ln_g,
    const float* __restrict__ ln_b)
{
    __shared__ float w1s[DIM * DIM];
    __shared__ float hrow[32][DIM];

    for (int i = threadIdx.x; i < DIM * DIM / 4; i += 256)
        ((float4*)w1s)[i] = ((const float4*)W1)[i];

    const int tx = threadIdx.x & 31;
    const int ty = threadIdx.x >> 5;
    const int jj = tx * 4;
    const int base = blockIdx.x * 32;

    for (int i = threadIdx.x; i < 1024; i += 256) {
        int r = i >> 5, cc = i & 31;
        ((float4*)hrow[r])[cc] = ((const float4*)(hio + (size_t)(base + r) * DIM))[cc];
    }
    __syncthreads();

    const float4 bv = *(const float4*)(b1 + jj);
    const float4 gv = *(const float4*)(ln_g + jj);
    const float4 bb = *(const float4*)(ln_b + jj);

    float4 a0 = bv, a1 = bv, a2 = bv, a3 = bv;
    #pragma unroll 4
    for (int k = 0; k < DIM; ++k) {
        float4 wv = *(const float4*)(w1s + k * DIM + jj);
        float h0 = hrow[ty +  0][k];
        float h1 = hrow[ty +  8][k];
        float h2 = hrow[ty + 16][k];
        float h3 = hrow[ty + 24][k];
        a0.x = fmaf(h0, wv.x, a0.x); a0.y = fmaf(h0, wv.y, a0.y);
        a0.z = fmaf(h0, wv.z, a0.z); a0.w = fmaf(h0, wv.w, a0.w);
        a1.x = fmaf(h1, wv.x, a1.x); a1.y = fmaf(h1, wv.y, a1.y);
        a1.z = fmaf(h1, wv.z, a1.z); a1.w = fmaf(h1, wv.w, a1.w);
        a2.x = fmaf(h2, wv.x, a2.x); a2.y = fmaf(h2, wv.y, a2.y);
        a2.z = fmaf(h2, wv.z, a2.z); a2.w = fmaf(h2, wv.w, a2.w);
        a3.x = fmaf(h3, wv.x, a3.x); a3.y = fmaf(h3, wv.y, a3.y);
        a3.z = fmaf(h3, wv.z, a3.z); a3.w = fmaf(h3, wv.w, a3.w);
    }

    #pragma unroll
    for (int q = 0; q < 4; ++q) {
        float4 acc = (q == 0) ? a0 : (q == 1) ? a1 : (q == 2) ? a2 : a3;
        float s1 = acc.x + acc.y + acc.z + acc.w;
        float s2 = acc.x * acc.x + acc.y * acc.y + acc.z * acc.z + acc.w * acc.w;
        #pragma unroll
        for (int m = 16; m; m >>= 1) {
            s1 += __shfl_xor(s1, m);
            s2 += __shfl_xor(s2, m);
        }
        float mu  = s1 * (1.0f / DIM);
        float var = s2 * (1.0f / DIM) - mu * mu;
        float rs_ = rsqrtf(var + 1e-5f);
        float4 o;
        o.x = fmaxf((acc.x - mu) * rs_ * gv.x + bb.x, 0.0f);
        o.y = fmaxf((acc.y - mu) * rs_ * gv.y + bb.y, 0.0f);
        o.z = fmaxf((acc.z - mu) * rs_ * gv.z + bb.z, 0.0f);
        o.w = fmaxf((acc.w - mu) * rs_ * gv.w + bb.w, 0.0f);
        *(float4*)(hio + (size_t)(base + ty + 8 * q) * DIM + jj) = o;
    }
}

// ---------------------------------------------------------------------------
// MLP2: out = h1@W2 + b2
// ---------------------------------------------------------------------------
__global__ __launch_bounds__(256) void gine_mlp2(
    const float* __restrict__ hio,
    const float* __restrict__ W2,
    const float* __restrict__ b2,
    float* __restrict__ out)
{
    __shared__ float w2s[DIM * DIM];
    __shared__ float hrow[32][DIM];

    for (int i = threadIdx.x; i < DIM * DIM / 4; i += 256)
        ((float4*)w2s)[i] = ((const float4*)W2)[i];

    const int tx = threadIdx.x & 31;
    const int ty = threadIdx.x >> 5;
    const int jj = tx * 4;
    const int base = blockIdx.x * 32;

    for (int i = threadIdx.x; i < 1024; i += 256) {
        int r = i >> 5, cc = i & 31;
        ((float4*)hrow[r])[cc] = ((const float4*)(hio + (size_t)(base + r) * DIM))[cc];
    }
    __syncthreads();

    const float4 bv = *(const float4*)(b2 + jj);
    float4 a0 = bv, a1 = bv, a2 = bv, a3 = bv;
    #pragma unroll 4
    for (int k = 0; k < DIM; ++k) {
        float4 wv = *(const float4*)(w2s + k * DIM + jj);
        float h0 = hrow[ty +  0][k];
        float h1 = hrow[ty +  8][k];
        float h2 = hrow[ty + 16][k];
        float h3 = hrow[ty + 24][k];
        a0.x = fmaf(h0, wv.x, a0.x); a0.y = fmaf(h0, wv.y, a0.y);
        a0.z = fmaf(h0, wv.z, a0.z); a0.w = fmaf(h0, wv.w, a0.w);
        a1.x = fmaf(h1, wv.x, a1.x); a1.y = fmaf(h1, wv.y, a1.y);
        a1.z = fmaf(h1, wv.z, a1.z); a1.w = fmaf(h1, wv.w, a1.w);
        a2.x = fmaf(h2, wv.x, a2.x); a2.y = fmaf(h2, wv.y, a2.y);
        a2.z = fmaf(h2, wv.z, a2.z); a2.w = fmaf(h2, wv.w, a2.w);
        a3.x = fmaf(h3, wv.x, a3.x); a3.y = fmaf(h3, wv.y, a3.y);
        a3.z = fmaf(h3, wv.z, a3.z); a3.w = fmaf(h3, wv.w, a3.w);
    }

    *(float4*)(out + (size_t)(base + ty +  0) * DIM + jj) = a0;
    *(float4*)(out + (size_t)(base + ty +  8) * DIM + jj) = a1;
    *(float4*)(out + (size_t)(base + ty + 16) * DIM + jj) = a2;
    *(float4*)(out + (size_t)(base + ty + 24) * DIM + jj) = a3;
}

extern "C" void kernel_launch(void* const* d_in, const int* in_sizes, int n_in,
                              void* d_out, int out_size, void* d_ws, size_t ws_size,
                              hipStream_t stream) {
    const float* x    = (const float*)d_in[0];
    const int*   ei   = (const int*)d_in[1];
    const int*   ea   = (const int*)d_in[2];
    const float* emb  = (const float*)d_in[3];
    const float* epsp = (const float*)d_in[4];
    const float* W1   = (const float*)d_in[5];
    const float* b1   = (const float*)d_in[6];
    const float* lng  = (const float*)d_in[7];
    const float* lnb  = (const float*)d_in[8];
    const float* W2   = (const float*)d_in[9];
    const float* b2   = (const float*)d_in[10];
    float* out = (float*)d_out;

    // workspace layout (bytes)
    char* ws = (char*)d_ws;
    int* rs     = (int*)(ws);                   // [N_NODES+1]
    int* bk     = (int*)(ws + 400128);          // [NBUK+1] counts -> bases
    int* bk_cur = (int*)(ws + 401920);          // [NBUK]
    int* col    = (int*)(ws + 403968);          // [N_EDGES] sorted payloads
    int* ebuf   = (int*)(ws + 6803968);         // [N_EDGES] bucket-binned (phase A)
    float* hbuf = (float*)(ws + 6803968);       // [N,128] aliases ebuf (dead by then)

    hipMemsetAsync(bk, 0, (NBUK + 1) * sizeof(int), stream);

    bucket_hist<<<NBLK, 256, 0, stream>>>(ei, bk);
    bucket_scan<<<1, 512, 0, stream>>>(bk, bk_cur);
    phaseA_bin<<<NBLK, 256, 0, stream>>>(ei, ea, bk_cur, ebuf);
    phaseB_sort<<<NBUK, 256, 0, stream>>>(bk, ebuf, rs, col);

    gather_kernel<<<(N_NODES * 32) / 256, 256, 0, stream>>>(
        x, emb, rs, col, epsp, hbuf);

    gine_mlp1<<<N_NODES / 32, 256, 0, stream>>>(hbuf, W1, b1, lng, lnb);
    gine_mlp2<<<N_NODES / 32, 256, 0, stream>>>(hbuf, W2, b2, out);
}

// Round 5
// 309.454 us; speedup vs baseline: 2.2023x; 2.2023x over previous
//
#include <hip/hip_runtime.h>

#define N_NODES 100000
#define N_EDGES 1600000
#define DIM 128
#define NBUK 391      // ceil(N_NODES / 256), bucket = dst >> 8
#define EPB 4096      // edges per block in hist / scatter
#define NBLK 391      // ceil(N_EDGES / EPB)
#define NCNT (NBUK * NBLK)   // 152881 (block,bucket) counters
#define NSC 150       // ceil(NCNT / 1024) scan blocks
#define CAPB 5120     // max edges per bucket (mean 4092, +16 sigma)

// ---------------------------------------------------------------------------
// 1) per-block bucket histogram -> counts[bucket*NBLK + block]  (no g-atomics)
// ---------------------------------------------------------------------------
__global__ __launch_bounds__(256) void hist2(
    const int* __restrict__ ei, int* __restrict__ cnts)
{
    __shared__ int cnt[NBUK];
    for (int i = threadIdx.x; i < NBUK; i += 256) cnt[i] = 0;
    __syncthreads();
    int e0 = blockIdx.x * EPB;
    int e1 = min(e0 + EPB, N_EDGES);
    for (int e = e0 + threadIdx.x; e < e1; e += 256)
        atomicAdd(&cnt[ei[N_EDGES + e] >> 8], 1);
    __syncthreads();
    for (int b = threadIdx.x; b < NBUK; b += 256)
        cnts[b * NBLK + blockIdx.x] = cnt[b];
}

// ---------------------------------------------------------------------------
// 2) exclusive scan of NCNT counts (3 kernels)
// ---------------------------------------------------------------------------
__global__ __launch_bounds__(256) void scanA(
    const int* __restrict__ cnts, int* __restrict__ ebase, int* __restrict__ bsums)
{
    __shared__ int s[256];
    int t = threadIdx.x;
    int base = blockIdx.x * 1024 + t * 4;
    int v0 = (base + 0 < NCNT) ? cnts[base + 0] : 0;
    int v1 = (base + 1 < NCNT) ? cnts[base + 1] : 0;
    int v2 = (base + 2 < NCNT) ? cnts[base + 2] : 0;
    int v3 = (base + 3 < NCNT) ? cnts[base + 3] : 0;
    int sum = v0 + v1 + v2 + v3;
    s[t] = sum;
    __syncthreads();
    for (int off = 1; off < 256; off <<= 1) {
        int x = (t >= off) ? s[t - off] : 0;
        __syncthreads();
        s[t] += x;
        __syncthreads();
    }
    int excl = s[t] - sum;
    if (base + 0 < NCNT) ebase[base + 0] = excl;  excl += v0;
    if (base + 1 < NCNT) ebase[base + 1] = excl;  excl += v1;
    if (base + 2 < NCNT) ebase[base + 2] = excl;  excl += v2;
    if (base + 3 < NCNT) ebase[base + 3] = excl;
    if (t == 255) bsums[blockIdx.x] = s[255];
}

__global__ __launch_bounds__(256) void scanB(int* __restrict__ bsums)
{
    __shared__ int s[256];
    int t = threadIdx.x;
    int v = (t < NSC) ? bsums[t] : 0;
    s[t] = v;
    __syncthreads();
    for (int off = 1; off < 256; off <<= 1) {
        int x = (t >= off) ? s[t - off] : 0;
        __syncthreads();
        s[t] += x;
        __syncthreads();
    }
    if (t < NSC) bsums[t] = s[t] - v;   // exclusive
}

__global__ __launch_bounds__(256) void scanC(
    int* __restrict__ ebase, const int* __restrict__ bsums, int* __restrict__ bk)
{
    int i = blockIdx.x * 256 + threadIdx.x;
    if (i < NCNT) {
        int v = ebase[i] + bsums[i >> 10];
        ebase[i] = v;
        if (i % NBLK == 0) bk[i / NBLK] = v;   // bucket base
    }
    if (i == 0) bk[NBUK] = N_EDGES;
}

// ---------------------------------------------------------------------------
// 3) scatter: payload = src | attr<<17 | dst_local<<19, slot = mybase[b]+rank
//    LDS: 391 counters + 391 staged bases only -> high occupancy, no g-atomics
// ---------------------------------------------------------------------------
__global__ __launch_bounds__(256) void pass2_scatter(
    const int* __restrict__ ei, const int* __restrict__ ea,
    const int* __restrict__ ebase, int* __restrict__ ebuf)
{
    __shared__ int cnt[NBUK];
    __shared__ int mybase[NBUK];
    for (int i = threadIdx.x; i < NBUK; i += 256) {
        cnt[i] = 0;
        mybase[i] = ebase[i * NBLK + blockIdx.x];
    }
    __syncthreads();
    int e0 = blockIdx.x * EPB;
    int e1 = min(e0 + EPB, N_EDGES);
    for (int e = e0 + threadIdx.x; e < e1; e += 256) {
        int src = ei[e];
        int dst = ei[N_EDGES + e];
        int at  = ea[e];
        int pay = src | (at << 17) | ((dst & 255) << 19);
        int b   = dst >> 8;
        int r   = atomicAdd(&cnt[b], 1);
        ebuf[mybase[b] + r] = pay;
    }
}

// ---------------------------------------------------------------------------
// 4) per-bucket node sort. Writes rs[] and node-sorted col[].
// ---------------------------------------------------------------------------
__global__ __launch_bounds__(256) void phaseB_sort(
    const int* __restrict__ bk, const int* __restrict__ ebuf,
    int* __restrict__ rs, int* __restrict__ col)
{
    __shared__ int eb[CAPB];
    __shared__ int deg[256];
    __shared__ int cur[256];
    __shared__ int s[256];

    int b = blockIdx.x;
    int lo = bk[b], hi = bk[b + 1];
    int n_e = min(hi - lo, CAPB);
    int t = threadIdx.x;

    for (int i = t; i < n_e; i += 256) eb[i] = ebuf[lo + i];
    deg[t] = 0;
    __syncthreads();

    for (int i = t; i < n_e; i += 256)
        atomicAdd(&deg[((unsigned)eb[i] >> 19)], 1);
    __syncthreads();

    int v = deg[t];
    s[t] = v;
    __syncthreads();
    for (int off = 1; off < 256; off <<= 1) {
        int x = (t >= off) ? s[t - off] : 0;
        __syncthreads();
        s[t] += x;
        __syncthreads();
    }
    int excl = s[t] - v;
    cur[t] = excl;
    int node = b * 256 + t;
    if (node < N_NODES) rs[node] = lo + excl;
    if (b == NBUK - 1 && t == 0) rs[N_NODES] = N_EDGES;
    __syncthreads();

    for (int i = t; i < n_e; i += 256) {
        int pk = eb[i];
        int p = atomicAdd(&cur[(unsigned)pk >> 19], 1);
        col[lo + p] = pk;
    }
}

// ---------------------------------------------------------------------------
// Gather aggregation: 32 lanes per node, float4 per lane, x4 unrolled edges.
// ---------------------------------------------------------------------------
__global__ __launch_bounds__(256) void gather_kernel(
    const float* __restrict__ x,
    const float* __restrict__ emb,
    const int* __restrict__ rs,
    const int* __restrict__ col,
    const float* __restrict__ eps_p,
    float* __restrict__ hbuf)
{
    int gid = blockIdx.x * 256 + threadIdx.x;
    int n = gid >> 5;
    if (n >= N_NODES) return;
    int c = gid & 31;

    int start = rs[n], end = rs[n + 1];
    float4 acc = make_float4(0.f, 0.f, 0.f, 0.f);

    int p = start;
    for (; p + 4 <= end; p += 4) {
        int pk0 = col[p + 0];
        int pk1 = col[p + 1];
        int pk2 = col[p + 2];
        int pk3 = col[p + 3];
        float4 x0 = ((const float4*)(x + (size_t)(pk0 & 0x1FFFF) * DIM))[c];
        float4 x1 = ((const float4*)(x + (size_t)(pk1 & 0x1FFFF) * DIM))[c];
        float4 x2 = ((const float4*)(x + (size_t)(pk2 & 0x1FFFF) * DIM))[c];
        float4 x3 = ((const float4*)(x + (size_t)(pk3 & 0x1FFFF) * DIM))[c];
        float4 e0 = ((const float4*)(emb + (size_t)(((unsigned)pk0 >> 17) & 3) * DIM))[c];
        float4 e1 = ((const float4*)(emb + (size_t)(((unsigned)pk1 >> 17) & 3) * DIM))[c];
        float4 e2 = ((const float4*)(emb + (size_t)(((unsigned)pk2 >> 17) & 3) * DIM))[c];
        float4 e3 = ((const float4*)(emb + (size_t)(((unsigned)pk3 >> 17) & 3) * DIM))[c];
        acc.x += fmaxf(x0.x + e0.x, 0.f) + fmaxf(x1.x + e1.x, 0.f)
               + fmaxf(x2.x + e2.x, 0.f) + fmaxf(x3.x + e3.x, 0.f);
        acc.y += fmaxf(x0.y + e0.y, 0.f) + fmaxf(x1.y + e1.y, 0.f)
               + fmaxf(x2.y + e2.y, 0.f) + fmaxf(x3.y + e3.y, 0.f);
        acc.z += fmaxf(x0.z + e0.z, 0.f) + fmaxf(x1.z + e1.z, 0.f)
               + fmaxf(x2.z + e2.z, 0.f) + fmaxf(x3.z + e3.z, 0.f);
        acc.w += fmaxf(x0.w + e0.w, 0.f) + fmaxf(x1.w + e1.w, 0.f)
               + fmaxf(x2.w + e2.w, 0.f) + fmaxf(x3.w + e3.w, 0.f);
    }
    for (; p < end; ++p) {
        int pk = col[p];
        float4 xv = ((const float4*)(x + (size_t)(pk & 0x1FFFF) * DIM))[c];
        float4 ev = ((const float4*)(emb + (size_t)(((unsigned)pk >> 17) & 3) * DIM))[c];
        acc.x += fmaxf(xv.x + ev.x, 0.f);
        acc.y += fmaxf(xv.y + ev.y, 0.f);
        acc.z += fmaxf(xv.z + ev.z, 0.f);
        acc.w += fmaxf(xv.w + ev.w, 0.f);
    }

    float epsv = 1.0f + eps_p[0];
    float4 xn = ((const float4*)(x + (size_t)n * DIM))[c];
    float4 o;
    o.x = epsv * xn.x + acc.x;
    o.y = epsv * xn.y + acc.y;
    o.z = epsv * xn.z + acc.z;
    o.w = epsv * xn.w + acc.w;
    ((float4*)(hbuf + (size_t)n * DIM))[c] = o;
}

// ---------------------------------------------------------------------------
// MLP1 in-place: h1 = relu(LN(h@W1 + b1)). 32-node tile, k-loop by 4 (float4 h)
// ---------------------------------------------------------------------------
#define MLP_FMA4(hv, wv) \
    a0.x = fmaf(hv##0, wv.x, a0.x); a0.y = fmaf(hv##0, wv.y, a0.y); \
    a0.z = fmaf(hv##0, wv.z, a0.z); a0.w = fmaf(hv##0, wv.w, a0.w); \
    a1.x = fmaf(hv##1, wv.x, a1.x); a1.y = fmaf(hv##1, wv.y, a1.y); \
    a1.z = fmaf(hv##1, wv.z, a1.z); a1.w = fmaf(hv##1, wv.w, a1.w); \
    a2.x = fmaf(hv##2, wv.x, a2.x); a2.y = fmaf(hv##2, wv.y, a2.y); \
    a2.z = fmaf(hv##2, wv.z, a2.z); a2.w = fmaf(hv##2, wv.w, a2.w); \
    a3.x = fmaf(hv##3, wv.x, a3.x); a3.y = fmaf(hv##3, wv.y, a3.y); \
    a3.z = fmaf(hv##3, wv.z, a3.z); a3.w = fmaf(hv##3, wv.w, a3.w);

#define MLP_KLOOP(WS) \
    for (int k4 = 0; k4 < 32; ++k4) { \
        float4 hq0 = ((const float4*)hrow[ty +  0])[k4]; \
        float4 hq1 = ((const float4*)hrow[ty +  8])[k4]; \
        float4 hq2 = ((const float4*)hrow[ty + 16])[k4]; \
        float4 hq3 = ((const float4*)hrow[ty + 24])[k4]; \
        { float4 wv = *(const float4*)(WS + (k4 * 4 + 0) * DIM + jj); \
          float hx0 = hq0.x, hx1 = hq1.x, hx2 = hq2.x, hx3 = hq3.x; MLP_FMA4(hx, wv) } \
        { float4 wv = *(const float4*)(WS + (k4 * 4 + 1) * DIM + jj); \
          float hx0 = hq0.y, hx1 = hq1.y, hx2 = hq2.y, hx3 = hq3.y; MLP_FMA4(hx, wv) } \
        { float4 wv = *(const float4*)(WS + (k4 * 4 + 2) * DIM + jj); \
          float hx0 = hq0.z, hx1 = hq1.z, hx2 = hq2.z, hx3 = hq3.z; MLP_FMA4(hx, wv) } \
        { float4 wv = *(const float4*)(WS + (k4 * 4 + 3) * DIM + jj); \
          float hx0 = hq0.w, hx1 = hq1.w, hx2 = hq2.w, hx3 = hq3.w; MLP_FMA4(hx, wv) } \
    }

__global__ __launch_bounds__(256) void gine_mlp1(
    float* __restrict__ hio,
    const float* __restrict__ W1,
    const float* __restrict__ b1,
    const float* __restrict__ ln_g,
    const float* __restrict__ ln_b)
{
    __shared__ float w1s[DIM * DIM];
    __shared__ float hrow[32][DIM];

    for (int i = threadIdx.x; i < DIM * DIM / 4; i += 256)
        ((float4*)w1s)[i] = ((const float4*)W1)[i];

    const int tx = threadIdx.x & 31;
    const int ty = threadIdx.x >> 5;
    const int jj = tx * 4;
    const int base = blockIdx.x * 32;

    for (int i = threadIdx.x; i < 1024; i += 256) {
        int r = i >> 5, cc = i & 31;
        ((float4*)hrow[r])[cc] = ((const float4*)(hio + (size_t)(base + r) * DIM))[cc];
    }
    __syncthreads();

    const float4 bv = *(const float4*)(b1 + jj);
    const float4 gv = *(const float4*)(ln_g + jj);
    const float4 bb = *(const float4*)(ln_b + jj);

    float4 a0 = bv, a1 = bv, a2 = bv, a3 = bv;
    MLP_KLOOP(w1s)

    #pragma unroll
    for (int q = 0; q < 4; ++q) {
        float4 acc = (q == 0) ? a0 : (q == 1) ? a1 : (q == 2) ? a2 : a3;
        float s1 = acc.x + acc.y + acc.z + acc.w;
        float s2 = acc.x * acc.x + acc.y * acc.y + acc.z * acc.z + acc.w * acc.w;
        #pragma unroll
        for (int m = 16; m; m >>= 1) {
            s1 += __shfl_xor(s1, m);
            s2 += __shfl_xor(s2, m);
        }
        float mu  = s1 * (1.0f / DIM);
        float var = s2 * (1.0f / DIM) - mu * mu;
        float rs_ = rsqrtf(var + 1e-5f);
        float4 o;
        o.x = fmaxf((acc.x - mu) * rs_ * gv.x + bb.x, 0.0f);
        o.y = fmaxf((acc.y - mu) * rs_ * gv.y + bb.y, 0.0f);
        o.z = fmaxf((acc.z - mu) * rs_ * gv.z + bb.z, 0.0f);
        o.w = fmaxf((acc.w - mu) * rs_ * gv.w + bb.w, 0.0f);
        *(float4*)(hio + (size_t)(base + ty + 8 * q) * DIM + jj) = o;
    }
}

// ---------------------------------------------------------------------------
// MLP2: out = h1@W2 + b2
// ---------------------------------------------------------------------------
__global__ __launch_bounds__(256) void gine_mlp2(
    const float* __restrict__ hio,
    const float* __restrict__ W2,
    const float* __restrict__ b2,
    float* __restrict__ out)
{
    __shared__ float w2s[DIM * DIM];
    __shared__ float hrow[32][DIM];

    for (int i = threadIdx.x; i < DIM * DIM / 4; i += 256)
        ((float4*)w2s)[i] = ((const float4*)W2)[i];

    const int tx = threadIdx.x & 31;
    const int ty = threadIdx.x >> 5;
    const int jj = tx * 4;
    const int base = blockIdx.x * 32;

    for (int i = threadIdx.x; i < 1024; i += 256) {
        int r = i >> 5, cc = i & 31;
        ((float4*)hrow[r])[cc] = ((const float4*)(hio + (size_t)(base + r) * DIM))[cc];
    }
    __syncthreads();

    const float4 bv = *(const float4*)(b2 + jj);
    float4 a0 = bv, a1 = bv, a2 = bv, a3 = bv;
    MLP_KLOOP(w2s)

    *(float4*)(out + (size_t)(base + ty +  0) * DIM + jj) = a0;
    *(float4*)(out + (size_t)(base + ty +  8) * DIM + jj) = a1;
    *(float4*)(out + (size_t)(base + ty + 16) * DIM + jj) = a2;
    *(float4*)(out + (size_t)(base + ty + 24) * DIM + jj) = a3;
}

extern "C" void kernel_launch(void* const* d_in, const int* in_sizes, int n_in,
                              void* d_out, int out_size, void* d_ws, size_t ws_size,
                              hipStream_t stream) {
    const float* x    = (const float*)d_in[0];
    const int*   ei   = (const int*)d_in[1];
    const int*   ea   = (const int*)d_in[2];
    const float* emb  = (const float*)d_in[3];
    const float* epsp = (const float*)d_in[4];
    const float* W1   = (const float*)d_in[5];
    const float* b1   = (const float*)d_in[6];
    const float* lng  = (const float*)d_in[7];
    const float* lnb  = (const float*)d_in[8];
    const float* W2   = (const float*)d_in[9];
    const float* b2   = (const float*)d_in[10];
    float* out = (float*)d_out;

    // workspace layout (bytes, 128-aligned)
    char* ws = (char*)d_ws;
    int* rs    = (int*)(ws);                  // [N_NODES+1]
    int* bk    = (int*)(ws +   400128);       // [NBUK+1]
    int* bsums = (int*)(ws +   401792);       // [NSC]
    int* cnts  = (int*)(ws +   402816);       // [NCNT]
    int* ebase = (int*)(ws +  1014400);       // [NCNT]
    int* col   = (int*)(ws +  1625984);       // [N_EDGES]
    int* ebuf  = (int*)(ws +  8025984);       // [N_EDGES]
    float* hbuf = (float*)(ws + 8025984);     // [N,128] aliases ebuf (dead by then)

    hist2<<<NBLK, 256, 0, stream>>>(ei, cnts);
    scanA<<<NSC, 256, 0, stream>>>(cnts, ebase, bsums);
    scanB<<<1, 256, 0, stream>>>(bsums);
    scanC<<<(NCNT + 255) / 256, 256, 0, stream>>>(ebase, bsums, bk);
    pass2_scatter<<<NBLK, 256, 0, stream>>>(ei, ea, ebase, ebuf);
    phaseB_sort<<<NBUK, 256, 0, stream>>>(bk, ebuf, rs, col);

    gather_kernel<<<(N_NODES * 32) / 256, 256, 0, stream>>>(
        x, emb, rs, col, epsp, hbuf);

    gine_mlp1<<<N_NODES / 32, 256, 0, stream>>>(hbuf, W1, b1, lng, lnb);
    gine_mlp2<<<N_NODES / 32, 256, 0, stream>>>(hbuf, W2, b2, out);
}

// Round 6
// 308.222 us; speedup vs baseline: 2.2111x; 1.0040x over previous
//
#include <hip/hip_runtime.h>

#define N_NODES 100000
#define N_EDGES 1600000
#define DIM 128
#define NBUK 391      // ceil(N_NODES / 256), bucket = dst >> 8
#define EPB 4096      // edges per block in hist / scatter
#define NBLK 391      // ceil(N_EDGES / EPB)
#define NCNT (NBUK * NBLK)   // 152881 (block,bucket) counters
#define NSC 150       // ceil(NCNT / 1024) scan blocks
#define CAPB 5120     // max edges per bucket (mean 4092, +16 sigma)

// ---------------------------------------------------------------------------
// 1) per-block bucket histogram -> counts[bucket*NBLK + block]  (no g-atomics)
// ---------------------------------------------------------------------------
__global__ __launch_bounds__(256) void hist2(
    const int* __restrict__ ei, int* __restrict__ cnts)
{
    __shared__ int cnt[NBUK];
    for (int i = threadIdx.x; i < NBUK; i += 256) cnt[i] = 0;
    __syncthreads();
    int e0 = blockIdx.x * EPB;
    int e1 = min(e0 + EPB, N_EDGES);
    for (int e = e0 + threadIdx.x; e < e1; e += 256)
        atomicAdd(&cnt[ei[N_EDGES + e] >> 8], 1);
    __syncthreads();
    for (int b = threadIdx.x; b < NBUK; b += 256)
        cnts[b * NBLK + blockIdx.x] = cnt[b];
}

// ---------------------------------------------------------------------------
// 2) exclusive scan of NCNT counts (3 kernels)
// ---------------------------------------------------------------------------
__global__ __launch_bounds__(256) void scanA(
    const int* __restrict__ cnts, int* __restrict__ ebase, int* __restrict__ bsums)
{
    __shared__ int s[256];
    int t = threadIdx.x;
    int base = blockIdx.x * 1024 + t * 4;
    int v0 = (base + 0 < NCNT) ? cnts[base + 0] : 0;
    int v1 = (base + 1 < NCNT) ? cnts[base + 1] : 0;
    int v2 = (base + 2 < NCNT) ? cnts[base + 2] : 0;
    int v3 = (base + 3 < NCNT) ? cnts[base + 3] : 0;
    int sum = v0 + v1 + v2 + v3;
    s[t] = sum;
    __syncthreads();
    for (int off = 1; off < 256; off <<= 1) {
        int x = (t >= off) ? s[t - off] : 0;
        __syncthreads();
        s[t] += x;
        __syncthreads();
    }
    int excl = s[t] - sum;
    if (base + 0 < NCNT) ebase[base + 0] = excl;  excl += v0;
    if (base + 1 < NCNT) ebase[base + 1] = excl;  excl += v1;
    if (base + 2 < NCNT) ebase[base + 2] = excl;  excl += v2;
    if (base + 3 < NCNT) ebase[base + 3] = excl;
    if (t == 255) bsums[blockIdx.x] = s[255];
}

__global__ __launch_bounds__(256) void scanB(int* __restrict__ bsums)
{
    __shared__ int s[256];
    int t = threadIdx.x;
    int v = (t < NSC) ? bsums[t] : 0;
    s[t] = v;
    __syncthreads();
    for (int off = 1; off < 256; off <<= 1) {
        int x = (t >= off) ? s[t - off] : 0;
        __syncthreads();
        s[t] += x;
        __syncthreads();
    }
    if (t < NSC) bsums[t] = s[t] - v;   // exclusive
}

__global__ __launch_bounds__(256) void scanC(
    int* __restrict__ ebase, const int* __restrict__ bsums, int* __restrict__ bk)
{
    int i = blockIdx.x * 256 + threadIdx.x;
    if (i < NCNT) {
        int v = ebase[i] + bsums[i >> 10];
        ebase[i] = v;
        if (i % NBLK == 0) bk[i / NBLK] = v;   // bucket base
    }
    if (i == 0) bk[NBUK] = N_EDGES;
}

// ---------------------------------------------------------------------------
// 3) scatter: payload = src | attr<<17 | dst_local<<19, slot = mybase[b]+rank
// ---------------------------------------------------------------------------
__global__ __launch_bounds__(256) void pass2_scatter(
    const int* __restrict__ ei, const int* __restrict__ ea,
    const int* __restrict__ ebase, int* __restrict__ ebuf)
{
    __shared__ int cnt[NBUK];
    __shared__ int mybase[NBUK];
    for (int i = threadIdx.x; i < NBUK; i += 256) {
        cnt[i] = 0;
        mybase[i] = ebase[i * NBLK + blockIdx.x];
    }
    __syncthreads();
    int e0 = blockIdx.x * EPB;
    int e1 = min(e0 + EPB, N_EDGES);
    for (int e = e0 + threadIdx.x; e < e1; e += 256) {
        int src = ei[e];
        int dst = ei[N_EDGES + e];
        int at  = ea[e];
        int pay = src | (at << 17) | ((dst & 255) << 19);
        int b   = dst >> 8;
        int r   = atomicAdd(&cnt[b], 1);
        ebuf[mybase[b] + r] = pay;
    }
}

// ---------------------------------------------------------------------------
// 4) per-bucket node sort. Writes rs[] and node-sorted col[].
// ---------------------------------------------------------------------------
__global__ __launch_bounds__(256) void phaseB_sort(
    const int* __restrict__ bk, const int* __restrict__ ebuf,
    int* __restrict__ rs, int* __restrict__ col)
{
    __shared__ int eb[CAPB];
    __shared__ int deg[256];
    __shared__ int cur[256];
    __shared__ int s[256];

    int b = blockIdx.x;
    int lo = bk[b], hi = bk[b + 1];
    int n_e = min(hi - lo, CAPB);
    int t = threadIdx.x;

    for (int i = t; i < n_e; i += 256) eb[i] = ebuf[lo + i];
    deg[t] = 0;
    __syncthreads();

    for (int i = t; i < n_e; i += 256)
        atomicAdd(&deg[((unsigned)eb[i] >> 19)], 1);
    __syncthreads();

    int v = deg[t];
    s[t] = v;
    __syncthreads();
    for (int off = 1; off < 256; off <<= 1) {
        int x = (t >= off) ? s[t - off] : 0;
        __syncthreads();
        s[t] += x;
        __syncthreads();
    }
    int excl = s[t] - v;
    cur[t] = excl;
    int node = b * 256 + t;
    if (node < N_NODES) rs[node] = lo + excl;
    if (b == NBUK - 1 && t == 0) rs[N_NODES] = N_EDGES;
    __syncthreads();

    for (int i = t; i < n_e; i += 256) {
        int pk = eb[i];
        int p = atomicAdd(&cur[(unsigned)pk >> 19], 1);
        col[lo + p] = pk;
    }
}

// ---------------------------------------------------------------------------
// Gather: 32 lanes/node, float4/lane, x4 edge unroll, emb slice in REGISTERS
// (selected by attr via cndmask) -> 1 VMEM op per edge instead of 2.
// ---------------------------------------------------------------------------
__device__ __forceinline__ float4 sel4(
    float4 e0, float4 e1, float4 e2, float4 e3, int at)
{
    float4 a = (at & 1) ? e1 : e0;
    float4 b = (at & 1) ? e3 : e2;
    return (at & 2) ? b : a;
}

__global__ __launch_bounds__(256) void gather_kernel(
    const float* __restrict__ x,
    const float* __restrict__ emb,
    const int* __restrict__ rs,
    const int* __restrict__ col,
    const float* __restrict__ eps_p,
    float* __restrict__ hbuf)
{
    int gid = blockIdx.x * 256 + threadIdx.x;
    int n = gid >> 5;
    if (n >= N_NODES) return;
    int c = gid & 31;

    // stage all 4 emb row-slices in registers (16 VGPR)
    float4 er0 = ((const float4*)(emb + 0 * DIM))[c];
    float4 er1 = ((const float4*)(emb + 1 * DIM))[c];
    float4 er2 = ((const float4*)(emb + 2 * DIM))[c];
    float4 er3 = ((const float4*)(emb + 3 * DIM))[c];

    int start = rs[n], end = rs[n + 1];
    float4 acc = make_float4(0.f, 0.f, 0.f, 0.f);

    int p = start;
    for (; p + 4 <= end; p += 4) {
        int pk0 = col[p + 0];
        int pk1 = col[p + 1];
        int pk2 = col[p + 2];
        int pk3 = col[p + 3];
        float4 x0 = ((const float4*)(x + (size_t)(pk0 & 0x1FFFF) * DIM))[c];
        float4 x1 = ((const float4*)(x + (size_t)(pk1 & 0x1FFFF) * DIM))[c];
        float4 x2 = ((const float4*)(x + (size_t)(pk2 & 0x1FFFF) * DIM))[c];
        float4 x3 = ((const float4*)(x + (size_t)(pk3 & 0x1FFFF) * DIM))[c];
        float4 e0 = sel4(er0, er1, er2, er3, ((unsigned)pk0 >> 17) & 3);
        float4 e1 = sel4(er0, er1, er2, er3, ((unsigned)pk1 >> 17) & 3);
        float4 e2 = sel4(er0, er1, er2, er3, ((unsigned)pk2 >> 17) & 3);
        float4 e3 = sel4(er0, er1, er2, er3, ((unsigned)pk3 >> 17) & 3);
        acc.x += fmaxf(x0.x + e0.x, 0.f) + fmaxf(x1.x + e1.x, 0.f)
               + fmaxf(x2.x + e2.x, 0.f) + fmaxf(x3.x + e3.x, 0.f);
        acc.y += fmaxf(x0.y + e0.y, 0.f) + fmaxf(x1.y + e1.y, 0.f)
               + fmaxf(x2.y + e2.y, 0.f) + fmaxf(x3.y + e3.y, 0.f);
        acc.z += fmaxf(x0.z + e0.z, 0.f) + fmaxf(x1.z + e1.z, 0.f)
               + fmaxf(x2.z + e2.z, 0.f) + fmaxf(x3.z + e3.z, 0.f);
        acc.w += fmaxf(x0.w + e0.w, 0.f) + fmaxf(x1.w + e1.w, 0.f)
               + fmaxf(x2.w + e2.w, 0.f) + fmaxf(x3.w + e3.w, 0.f);
    }
    for (; p < end; ++p) {
        int pk = col[p];
        float4 xv = ((const float4*)(x + (size_t)(pk & 0x1FFFF) * DIM))[c];
        float4 ev = sel4(er0, er1, er2, er3, ((unsigned)pk >> 17) & 3);
        acc.x += fmaxf(xv.x + ev.x, 0.f);
        acc.y += fmaxf(xv.y + ev.y, 0.f);
        acc.z += fmaxf(xv.z + ev.z, 0.f);
        acc.w += fmaxf(xv.w + ev.w, 0.f);
    }

    float epsv = 1.0f + eps_p[0];
    float4 xn = ((const float4*)(x + (size_t)n * DIM))[c];
    float4 o;
    o.x = epsv * xn.x + acc.x;
    o.y = epsv * xn.y + acc.y;
    o.z = epsv * xn.z + acc.z;
    o.w = epsv * xn.w + acc.w;
    ((float4*)(hbuf + (size_t)n * DIM))[c] = o;
}

// ---------------------------------------------------------------------------
// MLP kernels: PERSISTENT blocks (512 = 2/CU). W staged in LDS ONCE, then
// grid-stride over 32-node tiles. Thread = 4 nodes x 4 cols.
// ---------------------------------------------------------------------------
#define MLP_FMA4(hv, wv) \
    a0.x = fmaf(hv##0, wv.x, a0.x); a0.y = fmaf(hv##0, wv.y, a0.y); \
    a0.z = fmaf(hv##0, wv.z, a0.z); a0.w = fmaf(hv##0, wv.w, a0.w); \
    a1.x = fmaf(hv##1, wv.x, a1.x); a1.y = fmaf(hv##1, wv.y, a1.y); \
    a1.z = fmaf(hv##1, wv.z, a1.z); a1.w = fmaf(hv##1, wv.w, a1.w); \
    a2.x = fmaf(hv##2, wv.x, a2.x); a2.y = fmaf(hv##2, wv.y, a2.y); \
    a2.z = fmaf(hv##2, wv.z, a2.z); a2.w = fmaf(hv##2, wv.w, a2.w); \
    a3.x = fmaf(hv##3, wv.x, a3.x); a3.y = fmaf(hv##3, wv.y, a3.y); \
    a3.z = fmaf(hv##3, wv.z, a3.z); a3.w = fmaf(hv##3, wv.w, a3.w);

#define MLP_KLOOP(WS) \
    for (int k4 = 0; k4 < 32; ++k4) { \
        float4 hq0 = ((const float4*)hrow[ty +  0])[k4]; \
        float4 hq1 = ((const float4*)hrow[ty +  8])[k4]; \
        float4 hq2 = ((const float4*)hrow[ty + 16])[k4]; \
        float4 hq3 = ((const float4*)hrow[ty + 24])[k4]; \
        { float4 wv = *(const float4*)(WS + (k4 * 4 + 0) * DIM + jj); \
          float hx0 = hq0.x, hx1 = hq1.x, hx2 = hq2.x, hx3 = hq3.x; MLP_FMA4(hx, wv) } \
        { float4 wv = *(const float4*)(WS + (k4 * 4 + 1) * DIM + jj); \
          float hx0 = hq0.y, hx1 = hq1.y, hx2 = hq2.y, hx3 = hq3.y; MLP_FMA4(hx, wv) } \
        { float4 wv = *(const float4*)(WS + (k4 * 4 + 2) * DIM + jj); \
          float hx0 = hq0.z, hx1 = hq1.z, hx2 = hq2.z, hx3 = hq3.z; MLP_FMA4(hx, wv) } \
        { float4 wv = *(const float4*)(WS + (k4 * 4 + 3) * DIM + jj); \
          float hx0 = hq0.w, hx1 = hq1.w, hx2 = hq2.w, hx3 = hq3.w; MLP_FMA4(hx, wv) } \
    }

__global__ __launch_bounds__(256) void gine_mlp1(
    float* __restrict__ hio,
    const float* __restrict__ W1,
    const float* __restrict__ b1,
    const float* __restrict__ ln_g,
    const float* __restrict__ ln_b)
{
    __shared__ float w1s[DIM * DIM];   // 64KB, loaded once
    __shared__ float hrow[32][DIM];    // 16KB, per tile

    for (int i = threadIdx.x; i < DIM * DIM / 4; i += 256)
        ((float4*)w1s)[i] = ((const float4*)W1)[i];

    const int tx = threadIdx.x & 31;
    const int ty = threadIdx.x >> 5;
    const int jj = tx * 4;

    const float4 bv = *(const float4*)(b1 + jj);
    const float4 gv = *(const float4*)(ln_g + jj);
    const float4 bb = *(const float4*)(ln_b + jj);

    for (int base = blockIdx.x * 32; base < N_NODES; base += gridDim.x * 32) {
        __syncthreads();   // W ready (1st pass) / hrow consumers done (later)
        for (int i = threadIdx.x; i < 1024; i += 256) {
            int r = i >> 5, cc = i & 31;
            ((float4*)hrow[r])[cc] = ((const float4*)(hio + (size_t)(base + r) * DIM))[cc];
        }
        __syncthreads();

        float4 a0 = bv, a1 = bv, a2 = bv, a3 = bv;
        MLP_KLOOP(w1s)

        #pragma unroll
        for (int q = 0; q < 4; ++q) {
            float4 acc = (q == 0) ? a0 : (q == 1) ? a1 : (q == 2) ? a2 : a3;
            float s1 = acc.x + acc.y + acc.z + acc.w;
            float s2 = acc.x * acc.x + acc.y * acc.y + acc.z * acc.z + acc.w * acc.w;
            #pragma unroll
            for (int m = 16; m; m >>= 1) {
                s1 += __shfl_xor(s1, m);
                s2 += __shfl_xor(s2, m);
            }
            float mu  = s1 * (1.0f / DIM);
            float var = s2 * (1.0f / DIM) - mu * mu;
            float rs_ = rsqrtf(var + 1e-5f);
            float4 o;
            o.x = fmaxf((acc.x - mu) * rs_ * gv.x + bb.x, 0.0f);
            o.y = fmaxf((acc.y - mu) * rs_ * gv.y + bb.y, 0.0f);
            o.z = fmaxf((acc.z - mu) * rs_ * gv.z + bb.z, 0.0f);
            o.w = fmaxf((acc.w - mu) * rs_ * gv.w + bb.w, 0.0f);
            *(float4*)(hio + (size_t)(base + ty + 8 * q) * DIM + jj) = o;
        }
    }
}

__global__ __launch_bounds__(256) void gine_mlp2(
    const float* __restrict__ hio,
    const float* __restrict__ W2,
    const float* __restrict__ b2,
    float* __restrict__ out)
{
    __shared__ float w2s[DIM * DIM];
    __shared__ float hrow[32][DIM];

    for (int i = threadIdx.x; i < DIM * DIM / 4; i += 256)
        ((float4*)w2s)[i] = ((const float4*)W2)[i];

    const int tx = threadIdx.x & 31;
    const int ty = threadIdx.x >> 5;
    const int jj = tx * 4;
    const float4 bv = *(const float4*)(b2 + jj);

    for (int base = blockIdx.x * 32; base < N_NODES; base += gridDim.x * 32) {
        __syncthreads();
        for (int i = threadIdx.x; i < 1024; i += 256) {
            int r = i >> 5, cc = i & 31;
            ((float4*)hrow[r])[cc] = ((const float4*)(hio + (size_t)(base + r) * DIM))[cc];
        }
        __syncthreads();

        float4 a0 = bv, a1 = bv, a2 = bv, a3 = bv;
        MLP_KLOOP(w2s)

        *(float4*)(out + (size_t)(base + ty +  0) * DIM + jj) = a0;
        *(float4*)(out + (size_t)(base + ty +  8) * DIM + jj) = a1;
        *(float4*)(out + (size_t)(base + ty + 16) * DIM + jj) = a2;
        *(float4*)(out + (size_t)(base + ty + 24) * DIM + jj) = a3;
    }
}

extern "C" void kernel_launch(void* const* d_in, const int* in_sizes, int n_in,
                              void* d_out, int out_size, void* d_ws, size_t ws_size,
                              hipStream_t stream) {
    const float* x    = (const float*)d_in[0];
    const int*   ei   = (const int*)d_in[1];
    const int*   ea   = (const int*)d_in[2];
    const float* emb  = (const float*)d_in[3];
    const float* epsp = (const float*)d_in[4];
    const float* W1   = (const float*)d_in[5];
    const float* b1   = (const float*)d_in[6];
    const float* lng  = (const float*)d_in[7];
    const float* lnb  = (const float*)d_in[8];
    const float* W2   = (const float*)d_in[9];
    const float* b2   = (const float*)d_in[10];
    float* out = (float*)d_out;

    // workspace layout (bytes, 128-aligned)
    char* ws = (char*)d_ws;
    int* rs    = (int*)(ws);                  // [N_NODES+1]
    int* bk    = (int*)(ws +   400128);       // [NBUK+1]
    int* bsums = (int*)(ws +   401792);       // [NSC]
    int* cnts  = (int*)(ws +   402816);       // [NCNT]
    int* ebase = (int*)(ws +  1014400);       // [NCNT]
    int* col   = (int*)(ws +  1625984);       // [N_EDGES]
    int* ebuf  = (int*)(ws +  8025984);       // [N_EDGES]
    float* hbuf = (float*)(ws + 8025984);     // [N,128] aliases ebuf (dead by then)

    hist2<<<NBLK, 256, 0, stream>>>(ei, cnts);
    scanA<<<NSC, 256, 0, stream>>>(cnts, ebase, bsums);
    scanB<<<1, 256, 0, stream>>>(bsums);
    scanC<<<(NCNT + 255) / 256, 256, 0, stream>>>(ebase, bsums, bk);
    pass2_scatter<<<NBLK, 256, 0, stream>>>(ei, ea, ebase, ebuf);
    phaseB_sort<<<NBUK, 256, 0, stream>>>(bk, ebuf, rs, col);

    gather_kernel<<<(N_NODES * 32) / 256, 256, 0, stream>>>(
        x, emb, rs, col, epsp, hbuf);

    gine_mlp1<<<512, 256, 0, stream>>>(hbuf, W1, b1, lng, lnb);
    gine_mlp2<<<512, 256, 0, stream>>>(hbuf, W2, b2, out);
}

// Round 7
// 261.794 us; speedup vs baseline: 2.6032x; 1.1773x over previous
//
#include <hip/hip_runtime.h>

#define N_NODES 100000
#define N_EDGES 1600000
#define DIM 128
#define NBUK 391      // ceil(N_NODES / 256), bucket = dst >> 8
#define EPB 4096      // edges per block in hist / scatter
#define NBLK 391      // ceil(N_EDGES / EPB)
#define NCNT (NBUK * NBLK)   // 152881 (block,bucket) counters
#define NSC 150       // ceil(NCNT / 1024) scan blocks
#define CAPB 5120     // max edges per bucket (mean 4092, +16 sigma)

// ---------------------------------------------------------------------------
// 1) per-block bucket histogram -> counts[bucket*NBLK + block]  (no g-atomics)
// ---------------------------------------------------------------------------
__global__ __launch_bounds__(256) void hist2(
    const int* __restrict__ ei, int* __restrict__ cnts)
{
    __shared__ int cnt[NBUK];
    for (int i = threadIdx.x; i < NBUK; i += 256) cnt[i] = 0;
    __syncthreads();
    int e0 = blockIdx.x * EPB;
    int e1 = min(e0 + EPB, N_EDGES);
    for (int e = e0 + threadIdx.x; e < e1; e += 256)
        atomicAdd(&cnt[ei[N_EDGES + e] >> 8], 1);
    __syncthreads();
    for (int b = threadIdx.x; b < NBUK; b += 256)
        cnts[b * NBLK + blockIdx.x] = cnt[b];
}

// ---------------------------------------------------------------------------
// 2) exclusive scan of NCNT counts (3 kernels)
// ---------------------------------------------------------------------------
__global__ __launch_bounds__(256) void scanA(
    const int* __restrict__ cnts, int* __restrict__ ebase, int* __restrict__ bsums)
{
    __shared__ int s[256];
    int t = threadIdx.x;
    int base = blockIdx.x * 1024 + t * 4;
    int v0 = (base + 0 < NCNT) ? cnts[base + 0] : 0;
    int v1 = (base + 1 < NCNT) ? cnts[base + 1] : 0;
    int v2 = (base + 2 < NCNT) ? cnts[base + 2] : 0;
    int v3 = (base + 3 < NCNT) ? cnts[base + 3] : 0;
    int sum = v0 + v1 + v2 + v3;
    s[t] = sum;
    __syncthreads();
    for (int off = 1; off < 256; off <<= 1) {
        int x = (t >= off) ? s[t - off] : 0;
        __syncthreads();
        s[t] += x;
        __syncthreads();
    }
    int excl = s[t] - sum;
    if (base + 0 < NCNT) ebase[base + 0] = excl;  excl += v0;
    if (base + 1 < NCNT) ebase[base + 1] = excl;  excl += v1;
    if (base + 2 < NCNT) ebase[base + 2] = excl;  excl += v2;
    if (base + 3 < NCNT) ebase[base + 3] = excl;
    if (t == 255) bsums[blockIdx.x] = s[255];
}

__global__ __launch_bounds__(256) void scanB(int* __restrict__ bsums)
{
    __shared__ int s[256];
    int t = threadIdx.x;
    int v = (t < NSC) ? bsums[t] : 0;
    s[t] = v;
    __syncthreads();
    for (int off = 1; off < 256; off <<= 1) {
        int x = (t >= off) ? s[t - off] : 0;
        __syncthreads();
        s[t] += x;
        __syncthreads();
    }
    if (t < NSC) bsums[t] = s[t] - v;   // exclusive
}

__global__ __launch_bounds__(256) void scanC(
    int* __restrict__ ebase, const int* __restrict__ bsums, int* __restrict__ bk)
{
    int i = blockIdx.x * 256 + threadIdx.x;
    if (i < NCNT) {
        int v = ebase[i] + bsums[i >> 10];
        ebase[i] = v;
        if (i % NBLK == 0) bk[i / NBLK] = v;   // bucket base
    }
    if (i == 0) bk[NBUK] = N_EDGES;
}

// ---------------------------------------------------------------------------
// 3) scatter: payload = src | attr<<17 | dst_local<<19, slot = mybase[b]+rank
// ---------------------------------------------------------------------------
__global__ __launch_bounds__(256) void pass2_scatter(
    const int* __restrict__ ei, const int* __restrict__ ea,
    const int* __restrict__ ebase, int* __restrict__ ebuf)
{
    __shared__ int cnt[NBUK];
    __shared__ int mybase[NBUK];
    for (int i = threadIdx.x; i < NBUK; i += 256) {
        cnt[i] = 0;
        mybase[i] = ebase[i * NBLK + blockIdx.x];
    }
    __syncthreads();
    int e0 = blockIdx.x * EPB;
    int e1 = min(e0 + EPB, N_EDGES);
    for (int e = e0 + threadIdx.x; e < e1; e += 256) {
        int src = ei[e];
        int dst = ei[N_EDGES + e];
        int at  = ea[e];
        int pay = src | (at << 17) | ((dst & 255) << 19);
        int b   = dst >> 8;
        int r   = atomicAdd(&cnt[b], 1);
        ebuf[mybase[b] + r] = pay;
    }
}

// ---------------------------------------------------------------------------
// 4) per-bucket node sort. Writes rs[] and node-sorted col[].
// ---------------------------------------------------------------------------
__global__ __launch_bounds__(256) void phaseB_sort(
    const int* __restrict__ bk, const int* __restrict__ ebuf,
    int* __restrict__ rs, int* __restrict__ col)
{
    __shared__ int eb[CAPB];
    __shared__ int deg[256];
    __shared__ int cur[256];
    __shared__ int s[256];

    int b = blockIdx.x;
    int lo = bk[b], hi = bk[b + 1];
    int n_e = min(hi - lo, CAPB);
    int t = threadIdx.x;

    for (int i = t; i < n_e; i += 256) eb[i] = ebuf[lo + i];
    deg[t] = 0;
    __syncthreads();

    for (int i = t; i < n_e; i += 256)
        atomicAdd(&deg[((unsigned)eb[i] >> 19)], 1);
    __syncthreads();

    int v = deg[t];
    s[t] = v;
    __syncthreads();
    for (int off = 1; off < 256; off <<= 1) {
        int x = (t >= off) ? s[t - off] : 0;
        __syncthreads();
        s[t] += x;
        __syncthreads();
    }
    int excl = s[t] - v;
    cur[t] = excl;
    int node = b * 256 + t;
    if (node < N_NODES) rs[node] = lo + excl;
    if (b == NBUK - 1 && t == 0) rs[N_NODES] = N_EDGES;
    __syncthreads();

    for (int i = t; i < n_e; i += 256) {
        int pk = eb[i];
        int p = atomicAdd(&cur[(unsigned)pk >> 19], 1);
        col[lo + p] = pk;
    }
}

// ---------------------------------------------------------------------------
// Gather: 32 lanes/node, float4/lane, x8 edge unroll, emb rows in registers.
// ---------------------------------------------------------------------------
__device__ __forceinline__ float4 sel4(
    float4 e0, float4 e1, float4 e2, float4 e3, int at)
{
    float4 a = (at & 1) ? e1 : e0;
    float4 b = (at & 1) ? e3 : e2;
    return (at & 2) ? b : a;
}

__global__ __launch_bounds__(256) void gather_kernel(
    const float* __restrict__ x,
    const float* __restrict__ emb,
    const int* __restrict__ rs,
    const int* __restrict__ col,
    const float* __restrict__ eps_p,
    float* __restrict__ hbuf)
{
    int gid = blockIdx.x * 256 + threadIdx.x;
    int n = gid >> 5;
    if (n >= N_NODES) return;
    int c = gid & 31;

    float4 er0 = ((const float4*)(emb + 0 * DIM))[c];
    float4 er1 = ((const float4*)(emb + 1 * DIM))[c];
    float4 er2 = ((const float4*)(emb + 2 * DIM))[c];
    float4 er3 = ((const float4*)(emb + 3 * DIM))[c];

    int start = rs[n], end = rs[n + 1];
    float4 acc = make_float4(0.f, 0.f, 0.f, 0.f);

    int p = start;
    for (; p + 8 <= end; p += 8) {
        int pk[8];
        float4 xv[8];
        #pragma unroll
        for (int u = 0; u < 8; ++u) pk[u] = col[p + u];
        #pragma unroll
        for (int u = 0; u < 8; ++u)
            xv[u] = ((const float4*)(x + (size_t)(pk[u] & 0x1FFFF) * DIM))[c];
        #pragma unroll
        for (int u = 0; u < 8; ++u) {
            float4 ev = sel4(er0, er1, er2, er3, ((unsigned)pk[u] >> 17) & 3);
            acc.x += fmaxf(xv[u].x + ev.x, 0.f);
            acc.y += fmaxf(xv[u].y + ev.y, 0.f);
            acc.z += fmaxf(xv[u].z + ev.z, 0.f);
            acc.w += fmaxf(xv[u].w + ev.w, 0.f);
        }
    }
    for (; p + 4 <= end; p += 4) {
        int pk[4];
        float4 xv[4];
        #pragma unroll
        for (int u = 0; u < 4; ++u) pk[u] = col[p + u];
        #pragma unroll
        for (int u = 0; u < 4; ++u)
            xv[u] = ((const float4*)(x + (size_t)(pk[u] & 0x1FFFF) * DIM))[c];
        #pragma unroll
        for (int u = 0; u < 4; ++u) {
            float4 ev = sel4(er0, er1, er2, er3, ((unsigned)pk[u] >> 17) & 3);
            acc.x += fmaxf(xv[u].x + ev.x, 0.f);
            acc.y += fmaxf(xv[u].y + ev.y, 0.f);
            acc.z += fmaxf(xv[u].z + ev.z, 0.f);
            acc.w += fmaxf(xv[u].w + ev.w, 0.f);
        }
    }
    for (; p < end; ++p) {
        int pk = col[p];
        float4 xv = ((const float4*)(x + (size_t)(pk & 0x1FFFF) * DIM))[c];
        float4 ev = sel4(er0, er1, er2, er3, ((unsigned)pk >> 17) & 3);
        acc.x += fmaxf(xv.x + ev.x, 0.f);
        acc.y += fmaxf(xv.y + ev.y, 0.f);
        acc.z += fmaxf(xv.z + ev.z, 0.f);
        acc.w += fmaxf(xv.w + ev.w, 0.f);
    }

    float epsv = 1.0f + eps_p[0];
    float4 xn = ((const float4*)(x + (size_t)n * DIM))[c];
    float4 o;
    o.x = epsv * xn.x + acc.x;
    o.y = epsv * xn.y + acc.y;
    o.z = epsv * xn.z + acc.z;
    o.w = epsv * xn.w + acc.w;
    ((float4*)(hbuf + (size_t)n * DIM))[c] = o;
}

// ---------------------------------------------------------------------------
// Fused MLP via MFMA (split-bf16):
//   h1 = relu(LN(h@W1 + b1));  out = h1@W2 + b2
// Persistent blocks (256 = 1/CU), 512 threads = 8 waves. Each wave owns
// 16 nodes x 128 cols per tile (128-node tiles).
// GEMM1: A = h split into bf16 hi+lo (2-term, ~f32 A-precision), B = bf16(W1).
// GEMM2: A = bf16(h1) (post-LN O(1) values), B = bf16(W2).
// W staged once in LDS in MFMA fragment layout (conflict-free ds_read_b128).
// h1 round-trips through a per-wave XOR-swizzled LDS scratch (no x-wave sync).
// C/D layout (m89-verified): col = lane&15, row = (lane>>4)*4 + reg.
// A/B k-slots use a consistent (lane>>4)*8+j mapping on both operands.
// ---------------------------------------------------------------------------
typedef __attribute__((ext_vector_type(8))) short short8v;
typedef __attribute__((ext_vector_type(4))) float f32x4;

__device__ __forceinline__ unsigned short f2bf(float f) {
    unsigned u = __float_as_uint(f);
    unsigned r = u + 0x7FFFu + ((u >> 16) & 1u);   // RTN-even
    return (unsigned short)(r >> 16);
}
__device__ __forceinline__ float bf2f(unsigned short b) {
    return __uint_as_float(((unsigned)b) << 16);
}

__global__ __launch_bounds__(512) void fused_mlp(
    const float* __restrict__ hbuf,
    const float* __restrict__ W1, const float* __restrict__ b1,
    const float* __restrict__ lng, const float* __restrict__ lnb,
    const float* __restrict__ W2, const float* __restrict__ b2,
    float* __restrict__ out)
{
    __shared__ short w1s[DIM * DIM];        // 32KB, fragment layout bf16
    __shared__ short w2s[DIM * DIM];        // 32KB
    __shared__ short scr[8 * 16 * DIM];     // 32KB: per-wave h1 scratch (swizzled)

    // Stage W1/W2 -> bf16 fragment layout:
    // frag element (kt,nt,lane,j) holds W[kt*32 + (lane>>4)*8 + j][nt*16 + (lane&15)]
    for (int i = threadIdx.x; i < DIM * DIM; i += 512) {
        int k = i >> 7, n = i & 127;
        int lane = (((k >> 3) & 3) << 4) | (n & 15);
        int off = (((k >> 5) * 8 + (n >> 4)) * 64 + lane) * 8 + (k & 7);
        w1s[off] = (short)f2bf(W1[i]);
        w2s[off] = (short)f2bf(W2[i]);
    }
    __syncthreads();

    const int w  = threadIdx.x >> 6;   // wave 0..7
    const int l  = threadIdx.x & 63;
    const int lc = l & 15;
    const int lr = l >> 4;             // 0..3

    float g[8], bb[8], bi1[8], bi2[8];
    #pragma unroll
    for (int nt = 0; nt < 8; ++nt) {
        g[nt]  = lng[nt * 16 + lc];
        bb[nt] = lnb[nt * 16 + lc];
        bi1[nt] = b1[nt * 16 + lc];
        bi2[nt] = b2[nt * 16 + lc];
    }

    const int NTILES = (N_NODES + 127) / 128;   // 782
    for (int tile = blockIdx.x; tile < NTILES; tile += gridDim.x) {
        int rbase = tile * 128 + w * 16;
        int arow = min(rbase + lc, N_NODES - 1);   // A-frag row this lane loads
        const float* hp = hbuf + (size_t)arow * DIM;

        f32x4 acc[8];
        #pragma unroll
        for (int nt = 0; nt < 8; ++nt)
            acc[nt] = (f32x4){bi1[nt], bi1[nt], bi1[nt], bi1[nt]};

        #pragma unroll
        for (int kt = 0; kt < 4; ++kt) {
            float4 p0 = *(const float4*)(hp + kt * 32 + lr * 8);
            float4 p1 = *(const float4*)(hp + kt * 32 + lr * 8 + 4);
            float hv[8] = {p0.x, p0.y, p0.z, p0.w, p1.x, p1.y, p1.z, p1.w};
            short8v ahi, alo;
            #pragma unroll
            for (int j = 0; j < 8; ++j) {
                unsigned short hb = f2bf(hv[j]);
                ahi[j] = (short)hb;
                alo[j] = (short)f2bf(hv[j] - bf2f(hb));
            }
            #pragma unroll
            for (int nt = 0; nt < 8; ++nt) {
                short8v bf = *(const short8v*)&w1s[((kt * 8 + nt) * 64 + l) * 8];
                acc[nt] = __builtin_amdgcn_mfma_f32_16x16x32_bf16(ahi, bf, acc[nt], 0, 0, 0);
                acc[nt] = __builtin_amdgcn_mfma_f32_16x16x32_bf16(alo, bf, acc[nt], 0, 0, 0);
            }
        }

        // LayerNorm (reduce 128 cols of each row across 16-lane group) + relu,
        // then write bf16 h1 into per-wave swizzled scratch.
        #pragma unroll
        for (int r = 0; r < 4; ++r) {
            float s1 = 0.f, s2 = 0.f;
            #pragma unroll
            for (int nt = 0; nt < 8; ++nt) { float v = acc[nt][r]; s1 += v; s2 += v * v; }
            s1 += __shfl_xor(s1, 1);  s2 += __shfl_xor(s2, 1);
            s1 += __shfl_xor(s1, 2);  s2 += __shfl_xor(s2, 2);
            s1 += __shfl_xor(s1, 4);  s2 += __shfl_xor(s2, 4);
            s1 += __shfl_xor(s1, 8);  s2 += __shfl_xor(s2, 8);
            float mu  = s1 * (1.0f / DIM);
            float var = s2 * (1.0f / DIM) - mu * mu;
            float rsd = rsqrtf(var + 1e-5f);
            int row = lr * 4 + r;
            #pragma unroll
            for (int nt = 0; nt < 8; ++nt) {
                float v = (acc[nt][r] - mu) * rsd * g[nt] + bb[nt];
                v = fmaxf(v, 0.f);
                int cidx = nt * 16 + lc;
                // 16B-unit swizzle: physical unit = (cidx>>3) ^ row
                scr[w * 2048 + row * 128 + (((cidx >> 3) ^ row) << 3) + (cidx & 7)]
                    = (short)f2bf(v);
            }
        }

        // GEMM2 from scratch (A row = lc, k-slot (kt*4+lr) -> conflict-free b128)
        f32x4 acc2[8];
        #pragma unroll
        for (int nt = 0; nt < 8; ++nt)
            acc2[nt] = (f32x4){bi2[nt], bi2[nt], bi2[nt], bi2[nt]};

        #pragma unroll
        for (int kt = 0; kt < 4; ++kt) {
            short8v a2 = *(const short8v*)&scr[w * 2048 + lc * 128 + (((kt * 4 + lr) ^ lc) << 3)];
            #pragma unroll
            for (int nt = 0; nt < 8; ++nt) {
                short8v bf = *(const short8v*)&w2s[((kt * 8 + nt) * 64 + l) * 8];
                acc2[nt] = __builtin_amdgcn_mfma_f32_16x16x32_bf16(a2, bf, acc2[nt], 0, 0, 0);
            }
        }

        #pragma unroll
        for (int r = 0; r < 4; ++r) {
            int orow = rbase + lr * 4 + r;
            if (orow < N_NODES) {
                #pragma unroll
                for (int nt = 0; nt < 8; ++nt)
                    out[(size_t)orow * DIM + nt * 16 + lc] = acc2[nt][r];
            }
        }
    }
}

extern "C" void kernel_launch(void* const* d_in, const int* in_sizes, int n_in,
                              void* d_out, int out_size, void* d_ws, size_t ws_size,
                              hipStream_t stream) {
    const float* x    = (const float*)d_in[0];
    const int*   ei   = (const int*)d_in[1];
    const int*   ea   = (const int*)d_in[2];
    const float* emb  = (const float*)d_in[3];
    const float* epsp = (const float*)d_in[4];
    const float* W1   = (const float*)d_in[5];
    const float* b1   = (const float*)d_in[6];
    const float* lng  = (const float*)d_in[7];
    const float* lnb  = (const float*)d_in[8];
    const float* W2   = (const float*)d_in[9];
    const float* b2   = (const float*)d_in[10];
    float* out = (float*)d_out;

    // workspace layout (bytes, 128-aligned)
    char* ws = (char*)d_ws;
    int* rs    = (int*)(ws);                  // [N_NODES+1]
    int* bk    = (int*)(ws +   400128);       // [NBUK+1]
    int* bsums = (int*)(ws +   401792);       // [NSC]
    int* cnts  = (int*)(ws +   402816);       // [NCNT]
    int* ebase = (int*)(ws +  1014400);       // [NCNT]
    int* col   = (int*)(ws +  1625984);       // [N_EDGES]
    int* ebuf  = (int*)(ws +  8025984);       // [N_EDGES]
    float* hbuf = (float*)(ws + 8025984);     // [N,128] aliases ebuf (dead by then)

    hist2<<<NBLK, 256, 0, stream>>>(ei, cnts);
    scanA<<<NSC, 256, 0, stream>>>(cnts, ebase, bsums);
    scanB<<<1, 256, 0, stream>>>(bsums);
    scanC<<<(NCNT + 255) / 256, 256, 0, stream>>>(ebase, bsums, bk);
    pass2_scatter<<<NBLK, 256, 0, stream>>>(ei, ea, ebase, ebuf);
    phaseB_sort<<<NBUK, 256, 0, stream>>>(bk, ebuf, rs, col);

    gather_kernel<<<(N_NODES * 32) / 256, 256, 0, stream>>>(
        x, emb, rs, col, epsp, hbuf);

    fused_mlp<<<256, 512, 0, stream>>>(hbuf, W1, b1, lng, lnb, W2, b2, out);
}

// Round 8
// 226.766 us; speedup vs baseline: 3.0054x; 1.1545x over previous
//
#include <hip/hip_runtime.h>
#include <hip/hip_fp16.h>

#define N_NODES 100000
#define N_EDGES 1600000
#define DIM 128
#define NBUK 391      // ceil(N_NODES / 256), bucket = dst >> 8
#define EPB 4096      // edges per block in hist / scatter
#define NBLK 391      // ceil(N_EDGES / EPB)
#define NCNT (NBUK * NBLK)   // 152881 (block,bucket) counters
#define NSC 150       // ceil(NCNT / 1024) scan blocks
#define CAPB 5120     // max edges per bucket (mean 4092, +16 sigma)

// ---------------------------------------------------------------------------
// 1) per-block bucket histogram -> counts[bucket*NBLK + block]  (no g-atomics)
// ---------------------------------------------------------------------------
__global__ __launch_bounds__(256) void hist2(
    const int* __restrict__ ei, int* __restrict__ cnts)
{
    __shared__ int cnt[NBUK];
    for (int i = threadIdx.x; i < NBUK; i += 256) cnt[i] = 0;
    __syncthreads();
    int e0 = blockIdx.x * EPB;
    int e1 = min(e0 + EPB, N_EDGES);
    for (int e = e0 + threadIdx.x; e < e1; e += 256)
        atomicAdd(&cnt[ei[N_EDGES + e] >> 8], 1);
    __syncthreads();
    for (int b = threadIdx.x; b < NBUK; b += 256)
        cnts[b * NBLK + blockIdx.x] = cnt[b];
}

// ---------------------------------------------------------------------------
// 2) exclusive scan of NCNT counts (3 kernels)
// ---------------------------------------------------------------------------
__global__ __launch_bounds__(256) void scanA(
    const int* __restrict__ cnts, int* __restrict__ ebase, int* __restrict__ bsums)
{
    __shared__ int s[256];
    int t = threadIdx.x;
    int base = blockIdx.x * 1024 + t * 4;
    int v0 = (base + 0 < NCNT) ? cnts[base + 0] : 0;
    int v1 = (base + 1 < NCNT) ? cnts[base + 1] : 0;
    int v2 = (base + 2 < NCNT) ? cnts[base + 2] : 0;
    int v3 = (base + 3 < NCNT) ? cnts[base + 3] : 0;
    int sum = v0 + v1 + v2 + v3;
    s[t] = sum;
    __syncthreads();
    for (int off = 1; off < 256; off <<= 1) {
        int x = (t >= off) ? s[t - off] : 0;
        __syncthreads();
        s[t] += x;
        __syncthreads();
    }
    int excl = s[t] - sum;
    if (base + 0 < NCNT) ebase[base + 0] = excl;  excl += v0;
    if (base + 1 < NCNT) ebase[base + 1] = excl;  excl += v1;
    if (base + 2 < NCNT) ebase[base + 2] = excl;  excl += v2;
    if (base + 3 < NCNT) ebase[base + 3] = excl;
    if (t == 255) bsums[blockIdx.x] = s[255];
}

__global__ __launch_bounds__(256) void scanB(int* __restrict__ bsums)
{
    __shared__ int s[256];
    int t = threadIdx.x;
    int v = (t < NSC) ? bsums[t] : 0;
    s[t] = v;
    __syncthreads();
    for (int off = 1; off < 256; off <<= 1) {
        int x = (t >= off) ? s[t - off] : 0;
        __syncthreads();
        s[t] += x;
        __syncthreads();
    }
    if (t < NSC) bsums[t] = s[t] - v;   // exclusive
}

__global__ __launch_bounds__(256) void scanC(
    int* __restrict__ ebase, const int* __restrict__ bsums, int* __restrict__ bk)
{
    int i = blockIdx.x * 256 + threadIdx.x;
    if (i < NCNT) {
        int v = ebase[i] + bsums[i >> 10];
        ebase[i] = v;
        if (i % NBLK == 0) bk[i / NBLK] = v;   // bucket base
    }
    if (i == 0) bk[NBUK] = N_EDGES;
}

// ---------------------------------------------------------------------------
// 3) scatter: payload = src | attr<<17 | dst_local<<19, slot = mybase[b]+rank
// ---------------------------------------------------------------------------
__global__ __launch_bounds__(256) void pass2_scatter(
    const int* __restrict__ ei, const int* __restrict__ ea,
    const int* __restrict__ ebase, int* __restrict__ ebuf)
{
    __shared__ int cnt[NBUK];
    __shared__ int mybase[NBUK];
    for (int i = threadIdx.x; i < NBUK; i += 256) {
        cnt[i] = 0;
        mybase[i] = ebase[i * NBLK + blockIdx.x];
    }
    __syncthreads();
    int e0 = blockIdx.x * EPB;
    int e1 = min(e0 + EPB, N_EDGES);
    for (int e = e0 + threadIdx.x; e < e1; e += 256) {
        int src = ei[e];
        int dst = ei[N_EDGES + e];
        int at  = ea[e];
        int pay = src | (at << 17) | ((dst & 255) << 19);
        int b   = dst >> 8;
        int r   = atomicAdd(&cnt[b], 1);
        ebuf[mybase[b] + r] = pay;
    }
}

// ---------------------------------------------------------------------------
// 4) per-bucket node sort. Writes rs[] and node-sorted col[].
// ---------------------------------------------------------------------------
__global__ __launch_bounds__(256) void phaseB_sort(
    const int* __restrict__ bk, const int* __restrict__ ebuf,
    int* __restrict__ rs, int* __restrict__ col)
{
    __shared__ int eb[CAPB];
    __shared__ int deg[256];
    __shared__ int cur[256];
    __shared__ int s[256];

    int b = blockIdx.x;
    int lo = bk[b], hi = bk[b + 1];
    int n_e = min(hi - lo, CAPB);
    int t = threadIdx.x;

    for (int i = t; i < n_e; i += 256) eb[i] = ebuf[lo + i];
    deg[t] = 0;
    __syncthreads();

    for (int i = t; i < n_e; i += 256)
        atomicAdd(&deg[((unsigned)eb[i] >> 19)], 1);
    __syncthreads();

    int v = deg[t];
    s[t] = v;
    __syncthreads();
    for (int off = 1; off < 256; off <<= 1) {
        int x = (t >= off) ? s[t - off] : 0;
        __syncthreads();
        s[t] += x;
        __syncthreads();
    }
    int excl = s[t] - v;
    cur[t] = excl;
    int node = b * 256 + t;
    if (node < N_NODES) rs[node] = lo + excl;
    if (b == NBUK - 1 && t == 0) rs[N_NODES] = N_EDGES;
    __syncthreads();

    for (int i = t; i < n_e; i += 256) {
        int pk = eb[i];
        int p = atomicAdd(&cur[(unsigned)pk >> 19], 1);
        col[lo + p] = pk;
    }
}

// ---------------------------------------------------------------------------
// x -> fp16 conversion (streamed, one float4 -> ushort4 per thread)
// ---------------------------------------------------------------------------
__global__ __launch_bounds__(256) void conv_f16(
    const float* __restrict__ x, ushort* __restrict__ xh)
{
    int i = blockIdx.x * 256 + threadIdx.x;   // float4 index
    if (i < N_NODES * DIM / 4) {
        float4 v = ((const float4*)x)[i];
        ushort4 o;
        o.x = __half_as_ushort(__float2half(v.x));
        o.y = __half_as_ushort(__float2half(v.y));
        o.z = __half_as_ushort(__float2half(v.z));
        o.w = __half_as_ushort(__float2half(v.w));
        ((ushort4*)xh)[i] = o;
    }
}

// ---------------------------------------------------------------------------
// Gather (fp16 x): 32 lanes/node, half4 (8B)/lane -> 256B per random row.
// emb rows stay f32 in registers; self term read from f32 x (exact).
// ---------------------------------------------------------------------------
__device__ __forceinline__ float4 sel4(
    float4 e0, float4 e1, float4 e2, float4 e3, int at)
{
    float4 a = (at & 1) ? e1 : e0;
    float4 b = (at & 1) ? e3 : e2;
    return (at & 2) ? b : a;
}

__device__ __forceinline__ float4 h4tof4(ushort4 h) {
    float4 r;
    r.x = __half2float(__ushort_as_half(h.x));
    r.y = __half2float(__ushort_as_half(h.y));
    r.z = __half2float(__ushort_as_half(h.z));
    r.w = __half2float(__ushort_as_half(h.w));
    return r;
}

__global__ __launch_bounds__(256) void gather_f16(
    const float* __restrict__ x,
    const ushort* __restrict__ xh,
    const float* __restrict__ emb,
    const int* __restrict__ rs,
    const int* __restrict__ col,
    const float* __restrict__ eps_p,
    float* __restrict__ hbuf)
{
    int gid = blockIdx.x * 256 + threadIdx.x;
    int n = gid >> 5;
    if (n >= N_NODES) return;
    int c = gid & 31;

    float4 er0 = ((const float4*)(emb + 0 * DIM))[c];
    float4 er1 = ((const float4*)(emb + 1 * DIM))[c];
    float4 er2 = ((const float4*)(emb + 2 * DIM))[c];
    float4 er3 = ((const float4*)(emb + 3 * DIM))[c];

    int start = rs[n], end = rs[n + 1];
    float4 acc = make_float4(0.f, 0.f, 0.f, 0.f);

    int p = start;
    for (; p + 8 <= end; p += 8) {
        int pk[8];
        ushort4 hv[8];
        #pragma unroll
        for (int u = 0; u < 8; ++u) pk[u] = col[p + u];
        #pragma unroll
        for (int u = 0; u < 8; ++u)
            hv[u] = ((const ushort4*)(xh + (size_t)(pk[u] & 0x1FFFF) * DIM))[c];
        #pragma unroll
        for (int u = 0; u < 8; ++u) {
            float4 xv = h4tof4(hv[u]);
            float4 ev = sel4(er0, er1, er2, er3, ((unsigned)pk[u] >> 17) & 3);
            acc.x += fmaxf(xv.x + ev.x, 0.f);
            acc.y += fmaxf(xv.y + ev.y, 0.f);
            acc.z += fmaxf(xv.z + ev.z, 0.f);
            acc.w += fmaxf(xv.w + ev.w, 0.f);
        }
    }
    for (; p < end; ++p) {
        int pk = col[p];
        ushort4 hraw = ((const ushort4*)(xh + (size_t)(pk & 0x1FFFF) * DIM))[c];
        float4 xv = h4tof4(hraw);
        float4 ev = sel4(er0, er1, er2, er3, ((unsigned)pk >> 17) & 3);
        acc.x += fmaxf(xv.x + ev.x, 0.f);
        acc.y += fmaxf(xv.y + ev.y, 0.f);
        acc.z += fmaxf(xv.z + ev.z, 0.f);
        acc.w += fmaxf(xv.w + ev.w, 0.f);
    }

    float epsv = 1.0f + eps_p[0];
    float4 xn = ((const float4*)(x + (size_t)n * DIM))[c];
    float4 o;
    o.x = epsv * xn.x + acc.x;
    o.y = epsv * xn.y + acc.y;
    o.z = epsv * xn.z + acc.z;
    o.w = epsv * xn.w + acc.w;
    ((float4*)(hbuf + (size_t)n * DIM))[c] = o;
}

// f32 fallback gather (used only if ws_size can't fit xh)
__global__ __launch_bounds__(256) void gather_f32(
    const float* __restrict__ x,
    const float* __restrict__ emb,
    const int* __restrict__ rs,
    const int* __restrict__ col,
    const float* __restrict__ eps_p,
    float* __restrict__ hbuf)
{
    int gid = blockIdx.x * 256 + threadIdx.x;
    int n = gid >> 5;
    if (n >= N_NODES) return;
    int c = gid & 31;

    float4 er0 = ((const float4*)(emb + 0 * DIM))[c];
    float4 er1 = ((const float4*)(emb + 1 * DIM))[c];
    float4 er2 = ((const float4*)(emb + 2 * DIM))[c];
    float4 er3 = ((const float4*)(emb + 3 * DIM))[c];

    int start = rs[n], end = rs[n + 1];
    float4 acc = make_float4(0.f, 0.f, 0.f, 0.f);

    int p = start;
    for (; p + 4 <= end; p += 4) {
        int pk[4];
        float4 xv[4];
        #pragma unroll
        for (int u = 0; u < 4; ++u) pk[u] = col[p + u];
        #pragma unroll
        for (int u = 0; u < 4; ++u)
            xv[u] = ((const float4*)(x + (size_t)(pk[u] & 0x1FFFF) * DIM))[c];
        #pragma unroll
        for (int u = 0; u < 4; ++u) {
            float4 ev = sel4(er0, er1, er2, er3, ((unsigned)pk[u] >> 17) & 3);
            acc.x += fmaxf(xv[u].x + ev.x, 0.f);
            acc.y += fmaxf(xv[u].y + ev.y, 0.f);
            acc.z += fmaxf(xv[u].z + ev.z, 0.f);
            acc.w += fmaxf(xv[u].w + ev.w, 0.f);
        }
    }
    for (; p < end; ++p) {
        int pk = col[p];
        float4 xv = ((const float4*)(x + (size_t)(pk & 0x1FFFF) * DIM))[c];
        float4 ev = sel4(er0, er1, er2, er3, ((unsigned)pk >> 17) & 3);
        acc.x += fmaxf(xv.x + ev.x, 0.f);
        acc.y += fmaxf(xv.y + ev.y, 0.f);
        acc.z += fmaxf(xv.z + ev.z, 0.f);
        acc.w += fmaxf(xv.w + ev.w, 0.f);
    }

    float epsv = 1.0f + eps_p[0];
    float4 xn = ((const float4*)(x + (size_t)n * DIM))[c];
    float4 o;
    o.x = epsv * xn.x + acc.x;
    o.y = epsv * xn.y + acc.y;
    o.z = epsv * xn.z + acc.z;
    o.w = epsv * xn.w + acc.w;
    ((float4*)(hbuf + (size_t)n * DIM))[c] = o;
}

// ---------------------------------------------------------------------------
// Fused MLP via MFMA (split-bf16), persistent 256 blocks x 512 threads.
// ---------------------------------------------------------------------------
typedef __attribute__((ext_vector_type(8))) short short8v;
typedef __attribute__((ext_vector_type(4))) float f32x4;

__device__ __forceinline__ unsigned short f2bf(float f) {
    unsigned u = __float_as_uint(f);
    unsigned r = u + 0x7FFFu + ((u >> 16) & 1u);   // RTN-even
    return (unsigned short)(r >> 16);
}
__device__ __forceinline__ float bf2f(unsigned short b) {
    return __uint_as_float(((unsigned)b) << 16);
}

__global__ __launch_bounds__(512) void fused_mlp(
    const float* __restrict__ hbuf,
    const float* __restrict__ W1, const float* __restrict__ b1,
    const float* __restrict__ lng, const float* __restrict__ lnb,
    const float* __restrict__ W2, const float* __restrict__ b2,
    float* __restrict__ out)
{
    __shared__ short w1s[DIM * DIM];
    __shared__ short w2s[DIM * DIM];
    __shared__ short scr[8 * 16 * DIM];

    for (int i = threadIdx.x; i < DIM * DIM; i += 512) {
        int k = i >> 7, n = i & 127;
        int lane = (((k >> 3) & 3) << 4) | (n & 15);
        int off = (((k >> 5) * 8 + (n >> 4)) * 64 + lane) * 8 + (k & 7);
        w1s[off] = (short)f2bf(W1[i]);
        w2s[off] = (short)f2bf(W2[i]);
    }
    __syncthreads();

    const int w  = threadIdx.x >> 6;
    const int l  = threadIdx.x & 63;
    const int lc = l & 15;
    const int lr = l >> 4;

    float g[8], bb[8], bi1[8], bi2[8];
    #pragma unroll
    for (int nt = 0; nt < 8; ++nt) {
        g[nt]  = lng[nt * 16 + lc];
        bb[nt] = lnb[nt * 16 + lc];
        bi1[nt] = b1[nt * 16 + lc];
        bi2[nt] = b2[nt * 16 + lc];
    }

    const int NTILES = (N_NODES + 127) / 128;
    for (int tile = blockIdx.x; tile < NTILES; tile += gridDim.x) {
        int rbase = tile * 128 + w * 16;
        int arow = min(rbase + lc, N_NODES - 1);
        const float* hp = hbuf + (size_t)arow * DIM;

        f32x4 acc[8];
        #pragma unroll
        for (int nt = 0; nt < 8; ++nt)
            acc[nt] = (f32x4){bi1[nt], bi1[nt], bi1[nt], bi1[nt]};

        #pragma unroll
        for (int kt = 0; kt < 4; ++kt) {
            float4 p0 = *(const float4*)(hp + kt * 32 + lr * 8);
            float4 p1 = *(const float4*)(hp + kt * 32 + lr * 8 + 4);
            float hv[8] = {p0.x, p0.y, p0.z, p0.w, p1.x, p1.y, p1.z, p1.w};
            short8v ahi, alo;
            #pragma unroll
            for (int j = 0; j < 8; ++j) {
                unsigned short hb = f2bf(hv[j]);
                ahi[j] = (short)hb;
                alo[j] = (short)f2bf(hv[j] - bf2f(hb));
            }
            #pragma unroll
            for (int nt = 0; nt < 8; ++nt) {
                short8v bf = *(const short8v*)&w1s[((kt * 8 + nt) * 64 + l) * 8];
                acc[nt] = __builtin_amdgcn_mfma_f32_16x16x32_bf16(ahi, bf, acc[nt], 0, 0, 0);
                acc[nt] = __builtin_amdgcn_mfma_f32_16x16x32_bf16(alo, bf, acc[nt], 0, 0, 0);
            }
        }

        #pragma unroll
        for (int r = 0; r < 4; ++r) {
            float s1 = 0.f, s2 = 0.f;
            #pragma unroll
            for (int nt = 0; nt < 8; ++nt) { float v = acc[nt][r]; s1 += v; s2 += v * v; }
            s1 += __shfl_xor(s1, 1);  s2 += __shfl_xor(s2, 1);
            s1 += __shfl_xor(s1, 2);  s2 += __shfl_xor(s2, 2);
            s1 += __shfl_xor(s1, 4);  s2 += __shfl_xor(s2, 4);
            s1 += __shfl_xor(s1, 8);  s2 += __shfl_xor(s2, 8);
            float mu  = s1 * (1.0f / DIM);
            float var = s2 * (1.0f / DIM) - mu * mu;
            float rsd = rsqrtf(var + 1e-5f);
            int row = lr * 4 + r;
            #pragma unroll
            for (int nt = 0; nt < 8; ++nt) {
                float v = (acc[nt][r] - mu) * rsd * g[nt] + bb[nt];
                v = fmaxf(v, 0.f);
                int cidx = nt * 16 + lc;
                scr[w * 2048 + row * 128 + (((cidx >> 3) ^ row) << 3) + (cidx & 7)]
                    = (short)f2bf(v);
            }
        }

        f32x4 acc2[8];
        #pragma unroll
        for (int nt = 0; nt < 8; ++nt)
            acc2[nt] = (f32x4){bi2[nt], bi2[nt], bi2[nt], bi2[nt]};

        #pragma unroll
        for (int kt = 0; kt < 4; ++kt) {
            short8v a2 = *(const short8v*)&scr[w * 2048 + lc * 128 + (((kt * 4 + lr) ^ lc) << 3)];
            #pragma unroll
            for (int nt = 0; nt < 8; ++nt) {
                short8v bf = *(const short8v*)&w2s[((kt * 8 + nt) * 64 + l) * 8];
                acc2[nt] = __builtin_amdgcn_mfma_f32_16x16x32_bf16(a2, bf, acc2[nt], 0, 0, 0);
            }
        }

        #pragma unroll
        for (int r = 0; r < 4; ++r) {
            int orow = rbase + lr * 4 + r;
            if (orow < N_NODES) {
                #pragma unroll
                for (int nt = 0; nt < 8; ++nt)
                    out[(size_t)orow * DIM + nt * 16 + lc] = acc2[nt][r];
            }
        }
    }
}

extern "C" void kernel_launch(void* const* d_in, const int* in_sizes, int n_in,
                              void* d_out, int out_size, void* d_ws, size_t ws_size,
                              hipStream_t stream) {
    const float* x    = (const float*)d_in[0];
    const int*   ei   = (const int*)d_in[1];
    const int*   ea   = (const int*)d_in[2];
    const float* emb  = (const float*)d_in[3];
    const float* epsp = (const float*)d_in[4];
    const float* W1   = (const float*)d_in[5];
    const float* b1   = (const float*)d_in[6];
    const float* lng  = (const float*)d_in[7];
    const float* lnb  = (const float*)d_in[8];
    const float* W2   = (const float*)d_in[9];
    const float* b2   = (const float*)d_in[10];
    float* out = (float*)d_out;

    // workspace layout (bytes, 128-aligned)
    char* ws = (char*)d_ws;
    int* rs    = (int*)(ws);                  // [N_NODES+1]
    int* bk    = (int*)(ws +   400128);       // [NBUK+1]
    int* bsums = (int*)(ws +   401792);       // [NSC]
    int* cnts  = (int*)(ws +   402816);       // [NCNT]
    int* ebase = (int*)(ws +  1014400);       // [NCNT]
    int* col   = (int*)(ws +  1625984);       // [N_EDGES]
    int* ebuf  = (int*)(ws +  8025984);       // [N_EDGES]
    float* hbuf = (float*)(ws + 8025984);     // [N,128] f32, aliases ebuf (dead)
    ushort* xh = (ushort*)(ws + 59225984);    // [N,128] fp16
    const size_t NEED = 59225984 + (size_t)N_NODES * DIM * 2;   // ~84.8 MB

    hist2<<<NBLK, 256, 0, stream>>>(ei, cnts);
    scanA<<<NSC, 256, 0, stream>>>(cnts, ebase, bsums);
    scanB<<<1, 256, 0, stream>>>(bsums);
    scanC<<<(NCNT + 255) / 256, 256, 0, stream>>>(ebase, bsums, bk);
    pass2_scatter<<<NBLK, 256, 0, stream>>>(ei, ea, ebase, ebuf);
    phaseB_sort<<<NBUK, 256, 0, stream>>>(bk, ebuf, rs, col);

    if (ws_size >= NEED) {
        conv_f16<<<(N_NODES * DIM / 4 + 255) / 256, 256, 0, stream>>>(x, xh);
        gather_f16<<<(N_NODES * 32) / 256, 256, 0, stream>>>(
            x, xh, emb, rs, col, epsp, hbuf);
    } else {
        gather_f32<<<(N_NODES * 32) / 256, 256, 0, stream>>>(
            x, emb, rs, col, epsp, hbuf);
    }

    fused_mlp<<<256, 512, 0, stream>>>(hbuf, W1, b1, lng, lnb, W2, b2, out);
}

// Round 9
// 202.705 us; speedup vs baseline: 3.3621x; 1.1187x over previous
//
#include <hip/hip_runtime.h>
#include <hip/hip_fp16.h>

#define N_NODES 100000
#define N_EDGES 1600000
#define DIM 128
#define NBUK 391      // ceil(N_NODES / 256), bucket = dst >> 8
#define EPB 4096      // edges per block in hist / scatter
#define NBLK 391      // ceil(N_EDGES / EPB)
#define NCNT (NBUK * NBLK)   // 152881 (block,bucket) counters
#define NSC 150       // ceil(NCNT / 1024) scan blocks
#define CAPB 5120     // max edges per bucket (mean 4092, +16 sigma)

typedef __attribute__((ext_vector_type(8))) short short8v;
typedef __attribute__((ext_vector_type(4))) float f32x4;

__device__ __forceinline__ unsigned short f2bf(float f) {
    unsigned u = __float_as_uint(f);
    unsigned r = u + 0x7FFFu + ((u >> 16) & 1u);   // RTN-even
    return (unsigned short)(r >> 16);
}
__device__ __forceinline__ float bf2f(unsigned short b) {
    return __uint_as_float(((unsigned)b) << 16);
}

// ---------------------------------------------------------------------------
// 1) per-block bucket histogram -> counts[bucket*NBLK + block]  (no g-atomics)
// ---------------------------------------------------------------------------
__global__ __launch_bounds__(256) void hist2(
    const int* __restrict__ ei, int* __restrict__ cnts)
{
    __shared__ int cnt[NBUK];
    for (int i = threadIdx.x; i < NBUK; i += 256) cnt[i] = 0;
    __syncthreads();
    int e0 = blockIdx.x * EPB;
    int e1 = min(e0 + EPB, N_EDGES);
    for (int e = e0 + threadIdx.x; e < e1; e += 256)
        atomicAdd(&cnt[ei[N_EDGES + e] >> 8], 1);
    __syncthreads();
    for (int b = threadIdx.x; b < NBUK; b += 256)
        cnts[b * NBLK + blockIdx.x] = cnt[b];
}

// ---------------------------------------------------------------------------
// 2) exclusive scan of NCNT counts (3 kernels)
// ---------------------------------------------------------------------------
__global__ __launch_bounds__(256) void scanA(
    const int* __restrict__ cnts, int* __restrict__ ebase, int* __restrict__ bsums)
{
    __shared__ int s[256];
    int t = threadIdx.x;
    int base = blockIdx.x * 1024 + t * 4;
    int v0 = (base + 0 < NCNT) ? cnts[base + 0] : 0;
    int v1 = (base + 1 < NCNT) ? cnts[base + 1] : 0;
    int v2 = (base + 2 < NCNT) ? cnts[base + 2] : 0;
    int v3 = (base + 3 < NCNT) ? cnts[base + 3] : 0;
    int sum = v0 + v1 + v2 + v3;
    s[t] = sum;
    __syncthreads();
    for (int off = 1; off < 256; off <<= 1) {
        int x = (t >= off) ? s[t - off] : 0;
        __syncthreads();
        s[t] += x;
        __syncthreads();
    }
    int excl = s[t] - sum;
    if (base + 0 < NCNT) ebase[base + 0] = excl;  excl += v0;
    if (base + 1 < NCNT) ebase[base + 1] = excl;  excl += v1;
    if (base + 2 < NCNT) ebase[base + 2] = excl;  excl += v2;
    if (base + 3 < NCNT) ebase[base + 3] = excl;
    if (t == 255) bsums[blockIdx.x] = s[255];
}

__global__ __launch_bounds__(256) void scanB(int* __restrict__ bsums)
{
    __shared__ int s[256];
    int t = threadIdx.x;
    int v = (t < NSC) ? bsums[t] : 0;
    s[t] = v;
    __syncthreads();
    for (int off = 1; off < 256; off <<= 1) {
        int x = (t >= off) ? s[t - off] : 0;
        __syncthreads();
        s[t] += x;
        __syncthreads();
    }
    if (t < NSC) bsums[t] = s[t] - v;   // exclusive
}

__global__ __launch_bounds__(256) void scanC(
    int* __restrict__ ebase, const int* __restrict__ bsums, int* __restrict__ bk)
{
    int i = blockIdx.x * 256 + threadIdx.x;
    if (i < NCNT) {
        int v = ebase[i] + bsums[i >> 10];
        ebase[i] = v;
        if (i % NBLK == 0) bk[i / NBLK] = v;   // bucket base
    }
    if (i == 0) bk[NBUK] = N_EDGES;
}

// ---------------------------------------------------------------------------
// 3) scatter: payload = src | attr<<17 | dst_local<<19, slot = mybase[b]+rank
// ---------------------------------------------------------------------------
__global__ __launch_bounds__(256) void pass2_scatter(
    const int* __restrict__ ei, const int* __restrict__ ea,
    const int* __restrict__ ebase, int* __restrict__ ebuf)
{
    __shared__ int cnt[NBUK];
    __shared__ int mybase[NBUK];
    for (int i = threadIdx.x; i < NBUK; i += 256) {
        cnt[i] = 0;
        mybase[i] = ebase[i * NBLK + blockIdx.x];
    }
    __syncthreads();
    int e0 = blockIdx.x * EPB;
    int e1 = min(e0 + EPB, N_EDGES);
    for (int e = e0 + threadIdx.x; e < e1; e += 256) {
        int src = ei[e];
        int dst = ei[N_EDGES + e];
        int at  = ea[e];
        int pay = src | (at << 17) | ((dst & 255) << 19);
        int b   = dst >> 8;
        int r   = atomicAdd(&cnt[b], 1);
        ebuf[mybase[b] + r] = pay;
    }
}

// ---------------------------------------------------------------------------
// 4) per-bucket node sort. Writes rs[] and node-sorted col[].
// ---------------------------------------------------------------------------
__global__ __launch_bounds__(256) void phaseB_sort(
    const int* __restrict__ bk, const int* __restrict__ ebuf,
    int* __restrict__ rs, int* __restrict__ col)
{
    __shared__ int eb[CAPB];
    __shared__ int deg[256];
    __shared__ int cur[256];
    __shared__ int s[256];

    int b = blockIdx.x;
    int lo = bk[b], hi = bk[b + 1];
    int n_e = min(hi - lo, CAPB);
    int t = threadIdx.x;

    for (int i = t; i < n_e; i += 256) eb[i] = ebuf[lo + i];
    deg[t] = 0;
    __syncthreads();

    for (int i = t; i < n_e; i += 256)
        atomicAdd(&deg[((unsigned)eb[i] >> 19)], 1);
    __syncthreads();

    int v = deg[t];
    s[t] = v;
    __syncthreads();
    for (int off = 1; off < 256; off <<= 1) {
        int x = (t >= off) ? s[t - off] : 0;
        __syncthreads();
        s[t] += x;
        __syncthreads();
    }
    int excl = s[t] - v;
    cur[t] = excl;
    int node = b * 256 + t;
    if (node < N_NODES) rs[node] = lo + excl;
    if (b == NBUK - 1 && t == 0) rs[N_NODES] = N_EDGES;
    __syncthreads();

    for (int i = t; i < n_e; i += 256) {
        int pk = eb[i];
        int p = atomicAdd(&cur[(unsigned)pk >> 19], 1);
        col[lo + p] = pk;
    }
}

// ---------------------------------------------------------------------------
// x -> fp16 conversion (streamed)
// ---------------------------------------------------------------------------
__global__ __launch_bounds__(256) void conv_f16(
    const float* __restrict__ x, ushort* __restrict__ xh)
{
    int i = blockIdx.x * 256 + threadIdx.x;   // float4 index
    if (i < N_NODES * DIM / 4) {
        float4 v = ((const float4*)x)[i];
        ushort4 o;
        o.x = __half_as_ushort(__float2half(v.x));
        o.y = __half_as_ushort(__float2half(v.y));
        o.z = __half_as_ushort(__float2half(v.z));
        o.w = __half_as_ushort(__float2half(v.w));
        ((ushort4*)xh)[i] = o;
    }
}

// ---------------------------------------------------------------------------
// Gather (fp16 x). Output h written as SPLIT bf16 planes (hi + lo), so the
// MFMA MLP consumes A-fragments with plain 16B loads (no repack VALU).
// ---------------------------------------------------------------------------
__device__ __forceinline__ float4 sel4(
    float4 e0, float4 e1, float4 e2, float4 e3, int at)
{
    float4 a = (at & 1) ? e1 : e0;
    float4 b = (at & 1) ? e3 : e2;
    return (at & 2) ? b : a;
}

__device__ __forceinline__ float4 h4tof4(ushort4 h) {
    float4 r;
    r.x = __half2float(__ushort_as_half(h.x));
    r.y = __half2float(__ushort_as_half(h.y));
    r.z = __half2float(__ushort_as_half(h.z));
    r.w = __half2float(__ushort_as_half(h.w));
    return r;
}

__device__ __forceinline__ void write_split(
    ushort* hhi, ushort* hlo, int n, int c, float4 o)
{
    ushort4 hi4, lo4;
    hi4.x = f2bf(o.x); lo4.x = f2bf(o.x - bf2f(hi4.x));
    hi4.y = f2bf(o.y); lo4.y = f2bf(o.y - bf2f(hi4.y));
    hi4.z = f2bf(o.z); lo4.z = f2bf(o.z - bf2f(hi4.z));
    hi4.w = f2bf(o.w); lo4.w = f2bf(o.w - bf2f(hi4.w));
    ((ushort4*)(hhi + (size_t)n * DIM))[c] = hi4;
    ((ushort4*)(hlo + (size_t)n * DIM))[c] = lo4;
}

__global__ __launch_bounds__(256) void gather_f16(
    const float* __restrict__ x,
    const ushort* __restrict__ xh,
    const float* __restrict__ emb,
    const int* __restrict__ rs,
    const int* __restrict__ col,
    const float* __restrict__ eps_p,
    ushort* __restrict__ hhi, ushort* __restrict__ hlo)
{
    int gid = blockIdx.x * 256 + threadIdx.x;
    int n = gid >> 5;
    if (n >= N_NODES) return;
    int c = gid & 31;

    float4 er0 = ((const float4*)(emb + 0 * DIM))[c];
    float4 er1 = ((const float4*)(emb + 1 * DIM))[c];
    float4 er2 = ((const float4*)(emb + 2 * DIM))[c];
    float4 er3 = ((const float4*)(emb + 3 * DIM))[c];

    int start = rs[n], end = rs[n + 1];
    float4 acc = make_float4(0.f, 0.f, 0.f, 0.f);

    int p = start;
    for (; p + 8 <= end; p += 8) {
        int pk[8];
        ushort4 hv[8];
        #pragma unroll
        for (int u = 0; u < 8; ++u) pk[u] = col[p + u];
        #pragma unroll
        for (int u = 0; u < 8; ++u)
            hv[u] = ((const ushort4*)(xh + (size_t)(pk[u] & 0x1FFFF) * DIM))[c];
        #pragma unroll
        for (int u = 0; u < 8; ++u) {
            float4 xv = h4tof4(hv[u]);
            float4 ev = sel4(er0, er1, er2, er3, ((unsigned)pk[u] >> 17) & 3);
            acc.x += fmaxf(xv.x + ev.x, 0.f);
            acc.y += fmaxf(xv.y + ev.y, 0.f);
            acc.z += fmaxf(xv.z + ev.z, 0.f);
            acc.w += fmaxf(xv.w + ev.w, 0.f);
        }
    }
    for (; p < end; ++p) {
        int pk = col[p];
        ushort4 hraw = ((const ushort4*)(xh + (size_t)(pk & 0x1FFFF) * DIM))[c];
        float4 xv = h4tof4(hraw);
        float4 ev = sel4(er0, er1, er2, er3, ((unsigned)pk >> 17) & 3);
        acc.x += fmaxf(xv.x + ev.x, 0.f);
        acc.y += fmaxf(xv.y + ev.y, 0.f);
        acc.z += fmaxf(xv.z + ev.z, 0.f);
        acc.w += fmaxf(xv.w + ev.w, 0.f);
    }

    float epsv = 1.0f + eps_p[0];
    float4 xn = ((const float4*)(x + (size_t)n * DIM))[c];
    float4 o;
    o.x = epsv * xn.x + acc.x;
    o.y = epsv * xn.y + acc.y;
    o.z = epsv * xn.z + acc.z;
    o.w = epsv * xn.w + acc.w;
    write_split(hhi, hlo, n, c, o);
}

// f32 fallback gather (used only if ws_size can't fit xh)
__global__ __launch_bounds__(256) void gather_f32(
    const float* __restrict__ x,
    const float* __restrict__ emb,
    const int* __restrict__ rs,
    const int* __restrict__ col,
    const float* __restrict__ eps_p,
    ushort* __restrict__ hhi, ushort* __restrict__ hlo)
{
    int gid = blockIdx.x * 256 + threadIdx.x;
    int n = gid >> 5;
    if (n >= N_NODES) return;
    int c = gid & 31;

    float4 er0 = ((const float4*)(emb + 0 * DIM))[c];
    float4 er1 = ((const float4*)(emb + 1 * DIM))[c];
    float4 er2 = ((const float4*)(emb + 2 * DIM))[c];
    float4 er3 = ((const float4*)(emb + 3 * DIM))[c];

    int start = rs[n], end = rs[n + 1];
    float4 acc = make_float4(0.f, 0.f, 0.f, 0.f);

    int p = start;
    for (; p + 4 <= end; p += 4) {
        int pk[4];
        float4 xv[4];
        #pragma unroll
        for (int u = 0; u < 4; ++u) pk[u] = col[p + u];
        #pragma unroll
        for (int u = 0; u < 4; ++u)
            xv[u] = ((const float4*)(x + (size_t)(pk[u] & 0x1FFFF) * DIM))[c];
        #pragma unroll
        for (int u = 0; u < 4; ++u) {
            float4 ev = sel4(er0, er1, er2, er3, ((unsigned)pk[u] >> 17) & 3);
            acc.x += fmaxf(xv[u].x + ev.x, 0.f);
            acc.y += fmaxf(xv[u].y + ev.y, 0.f);
            acc.z += fmaxf(xv[u].z + ev.z, 0.f);
            acc.w += fmaxf(xv[u].w + ev.w, 0.f);
        }
    }
    for (; p < end; ++p) {
        int pk = col[p];
        float4 xv = ((const float4*)(x + (size_t)(pk & 0x1FFFF) * DIM))[c];
        float4 ev = sel4(er0, er1, er2, er3, ((unsigned)pk >> 17) & 3);
        acc.x += fmaxf(xv.x + ev.x, 0.f);
        acc.y += fmaxf(xv.y + ev.y, 0.f);
        acc.z += fmaxf(xv.z + ev.z, 0.f);
        acc.w += fmaxf(xv.w + ev.w, 0.f);
    }

    float epsv = 1.0f + eps_p[0];
    float4 xn = ((const float4*)(x + (size_t)n * DIM))[c];
    float4 o;
    o.x = epsv * xn.x + acc.x;
    o.y = epsv * xn.y + acc.y;
    o.z = epsv * xn.z + acc.z;
    o.w = epsv * xn.w + acc.w;
    write_split(hhi, hlo, n, c, o);
}

// ---------------------------------------------------------------------------
// Fused MLP via MFMA. NON-persistent: one 64-node tile per 256-thread block
// (4 waves x 16 nodes), grid = 1563. LDS 80KB -> 2 blocks/CU; W staging of
// one block overlaps compute of the co-resident one. A-fragments come from
// pre-split bf16 hi/lo planes (plain 16B loads, no repack).
// ---------------------------------------------------------------------------
__global__ __launch_bounds__(256) void fused_mlp(
    const ushort* __restrict__ hhi, const ushort* __restrict__ hlo,
    const float* __restrict__ W1, const float* __restrict__ b1,
    const float* __restrict__ lng, const float* __restrict__ lnb,
    const float* __restrict__ W2, const float* __restrict__ b2,
    float* __restrict__ out)
{
    __shared__ short w1s[DIM * DIM];    // 32KB  fragment-layout bf16
    __shared__ short w2s[DIM * DIM];    // 32KB
    __shared__ short scr[4 * 16 * DIM]; // 16KB  per-wave swizzled h1 scratch

    // Stage W1/W2 -> bf16 fragment layout (element (k,n)):
    for (int i4 = threadIdx.x; i4 < DIM * DIM / 4; i4 += 256) {
        int i = i4 * 4;
        int k = i >> 7, n0 = i & 127;
        float4 v1 = ((const float4*)W1)[i4];
        float4 v2 = ((const float4*)W2)[i4];
        float a1[4] = {v1.x, v1.y, v1.z, v1.w};
        float a2[4] = {v2.x, v2.y, v2.z, v2.w};
        #pragma unroll
        for (int q = 0; q < 4; ++q) {
            int n = n0 + q;
            int lane = (((k >> 3) & 3) << 4) | (n & 15);
            int off = (((k >> 5) * 8 + (n >> 4)) * 64 + lane) * 8 + (k & 7);
            w1s[off] = (short)f2bf(a1[q]);
            w2s[off] = (short)f2bf(a2[q]);
        }
    }
    __syncthreads();

    const int w  = threadIdx.x >> 6;   // wave 0..3
    const int l  = threadIdx.x & 63;
    const int lc = l & 15;
    const int lr = l >> 4;             // 0..3

    const int rbase = blockIdx.x * 64 + w * 16;
    const int arow = min(rbase + lc, N_NODES - 1);
    const ushort* hph = hhi + (size_t)arow * DIM;
    const ushort* hpl = hlo + (size_t)arow * DIM;

    float g[8], bb[8], bi1[8], bi2[8];
    #pragma unroll
    for (int nt = 0; nt < 8; ++nt) {
        g[nt]  = lng[nt * 16 + lc];
        bb[nt] = lnb[nt * 16 + lc];
        bi1[nt] = b1[nt * 16 + lc];
        bi2[nt] = b2[nt * 16 + lc];
    }

    f32x4 acc[8];
    #pragma unroll
    for (int nt = 0; nt < 8; ++nt)
        acc[nt] = (f32x4){bi1[nt], bi1[nt], bi1[nt], bi1[nt]};

    #pragma unroll
    for (int kt = 0; kt < 4; ++kt) {
        short8v ahi = *(const short8v*)(hph + kt * 32 + lr * 8);
        short8v alo = *(const short8v*)(hpl + kt * 32 + lr * 8);
        #pragma unroll
        for (int nt = 0; nt < 8; ++nt) {
            short8v bf = *(const short8v*)&w1s[((kt * 8 + nt) * 64 + l) * 8];
            acc[nt] = __builtin_amdgcn_mfma_f32_16x16x32_bf16(ahi, bf, acc[nt], 0, 0, 0);
            acc[nt] = __builtin_amdgcn_mfma_f32_16x16x32_bf16(alo, bf, acc[nt], 0, 0, 0);
        }
    }

    // LayerNorm + relu -> bf16 into per-wave swizzled scratch
    #pragma unroll
    for (int r = 0; r < 4; ++r) {
        float s1 = 0.f, s2 = 0.f;
        #pragma unroll
        for (int nt = 0; nt < 8; ++nt) { float v = acc[nt][r]; s1 += v; s2 += v * v; }
        s1 += __shfl_xor(s1, 1);  s2 += __shfl_xor(s2, 1);
        s1 += __shfl_xor(s1, 2);  s2 += __shfl_xor(s2, 2);
        s1 += __shfl_xor(s1, 4);  s2 += __shfl_xor(s2, 4);
        s1 += __shfl_xor(s1, 8);  s2 += __shfl_xor(s2, 8);
        float mu  = s1 * (1.0f / DIM);
        float var = s2 * (1.0f / DIM) - mu * mu;
        float rsd = rsqrtf(var + 1e-5f);
        int row = lr * 4 + r;
        #pragma unroll
        for (int nt = 0; nt < 8; ++nt) {
            float v = (acc[nt][r] - mu) * rsd * g[nt] + bb[nt];
            v = fmaxf(v, 0.f);
            int cidx = nt * 16 + lc;
            scr[w * 2048 + row * 128 + (((cidx >> 3) ^ row) << 3) + (cidx & 7)]
                = (short)f2bf(v);
        }
    }

    // GEMM2 from scratch
    f32x4 acc2[8];
    #pragma unroll
    for (int nt = 0; nt < 8; ++nt)
        acc2[nt] = (f32x4){bi2[nt], bi2[nt], bi2[nt], bi2[nt]};

    #pragma unroll
    for (int kt = 0; kt < 4; ++kt) {
        short8v a2 = *(const short8v*)&scr[w * 2048 + lc * 128 + (((kt * 4 + lr) ^ lc) << 3)];
        #pragma unroll
        for (int nt = 0; nt < 8; ++nt) {
            short8v bf = *(const short8v*)&w2s[((kt * 8 + nt) * 64 + l) * 8];
            acc2[nt] = __builtin_amdgcn_mfma_f32_16x16x32_bf16(a2, bf, acc2[nt], 0, 0, 0);
        }
    }

    #pragma unroll
    for (int r = 0; r < 4; ++r) {
        int orow = rbase + lr * 4 + r;
        if (orow < N_NODES) {
            #pragma unroll
            for (int nt = 0; nt < 8; ++nt)
                out[(size_t)orow * DIM + nt * 16 + lc] = acc2[nt][r];
        }
    }
}

extern "C" void kernel_launch(void* const* d_in, const int* in_sizes, int n_in,
                              void* d_out, int out_size, void* d_ws, size_t ws_size,
                              hipStream_t stream) {
    const float* x    = (const float*)d_in[0];
    const int*   ei   = (const int*)d_in[1];
    const int*   ea   = (const int*)d_in[2];
    const float* emb  = (const float*)d_in[3];
    const float* epsp = (const float*)d_in[4];
    const float* W1   = (const float*)d_in[5];
    const float* b1   = (const float*)d_in[6];
    const float* lng  = (const float*)d_in[7];
    const float* lnb  = (const float*)d_in[8];
    const float* W2   = (const float*)d_in[9];
    const float* b2   = (const float*)d_in[10];
    float* out = (float*)d_out;

    // workspace layout (bytes, 128-aligned)
    char* ws = (char*)d_ws;
    int* rs    = (int*)(ws);                  // [N_NODES+1]
    int* bk    = (int*)(ws +   400128);       // [NBUK+1]
    int* bsums = (int*)(ws +   401792);       // [NSC]
    int* cnts  = (int*)(ws +   402816);       // [NCNT]
    int* ebase = (int*)(ws +  1014400);       // [NCNT]
    int* col   = (int*)(ws +  1625984);       // [N_EDGES]
    int* ebuf  = (int*)(ws +  8025984);       // [N_EDGES]
    ushort* hhi = (ushort*)(ws + 8025984);    // [N,128] bf16 hi (aliases ebuf, dead)
    ushort* hlo = (ushort*)(ws + 33625984);   // [N,128] bf16 lo
    ushort* xh  = (ushort*)(ws + 59225984);   // [N,128] fp16
    const size_t NEED = 59225984 + (size_t)N_NODES * DIM * 2;   // ~84.8 MB

    hist2<<<NBLK, 256, 0, stream>>>(ei, cnts);
    scanA<<<NSC, 256, 0, stream>>>(cnts, ebase, bsums);
    scanB<<<1, 256, 0, stream>>>(bsums);
    scanC<<<(NCNT + 255) / 256, 256, 0, stream>>>(ebase, bsums, bk);
    pass2_scatter<<<NBLK, 256, 0, stream>>>(ei, ea, ebase, ebuf);
    phaseB_sort<<<NBUK, 256, 0, stream>>>(bk, ebuf, rs, col);

    if (ws_size >= NEED) {
        conv_f16<<<(N_NODES * DIM / 4 + 255) / 256, 256, 0, stream>>>(x, xh);
        gather_f16<<<(N_NODES * 32) / 256, 256, 0, stream>>>(
            x, xh, emb, rs, col, epsp, hhi, hlo);
    } else {
        gather_f32<<<(N_NODES * 32) / 256, 256, 0, stream>>>(
            x, emb, rs, col, epsp, hhi, hlo);
    }

    fused_mlp<<<(N_NODES + 63) / 64, 256, 0, stream>>>(
        hhi, hlo, W1, b1, lng, lnb, W2, b2, out);
}

// Round 11
// 195.439 us; speedup vs baseline: 3.4871x; 1.0372x over previous
//
#include <hip/hip_runtime.h>
#include <hip/hip_fp16.h>

#define N_NODES 100000
#define N_EDGES 1600000
#define DIM 128
#define NBUK 391      // ceil(N_NODES / 256), bucket = dst >> 8
#define EPB 4096      // edges per block in hist / scatter
#define NBLK 391      // ceil(N_EDGES / EPB)
#define NCNT (NBUK * NBLK)   // 152881 (block,bucket) counters
#define NSC 150       // ceil(NCNT / 1024) scan blocks
#define CAPB 5120     // max edges per bucket (mean 4092, +16 sigma)

typedef __attribute__((ext_vector_type(8))) short short8v;
typedef __attribute__((ext_vector_type(4))) float f32x4;
typedef _Float16 h2 __attribute__((ext_vector_type(2)));

__device__ __forceinline__ unsigned short f2bf(float f) {
    unsigned u = __float_as_uint(f);
    unsigned r = u + 0x7FFFu + ((u >> 16) & 1u);   // RTN-even
    return (unsigned short)(r >> 16);
}
__device__ __forceinline__ float bf2f(unsigned short b) {
    return __uint_as_float(((unsigned)b) << 16);
}

// ---------------------------------------------------------------------------
// 1) per-block bucket histogram  +  x->fp16 conversion (merged, independent)
// ---------------------------------------------------------------------------
__global__ __launch_bounds__(256) void hist2_conv(
    const int* __restrict__ ei, int* __restrict__ cnts,
    const float* __restrict__ x, ushort* __restrict__ xh, int do_conv)
{
    __shared__ int cnt[NBUK];
    for (int i = threadIdx.x; i < NBUK; i += 256) cnt[i] = 0;

    if (do_conv) {
        for (int i = blockIdx.x * 256 + threadIdx.x; i < N_NODES * DIM / 4;
             i += NBLK * 256) {
            float4 v = ((const float4*)x)[i];
            ushort4 o;
            o.x = __half_as_ushort(__float2half(v.x));
            o.y = __half_as_ushort(__float2half(v.y));
            o.z = __half_as_ushort(__float2half(v.z));
            o.w = __half_as_ushort(__float2half(v.w));
            ((ushort4*)xh)[i] = o;
        }
    }
    __syncthreads();

    int e0 = blockIdx.x * EPB;
    int e1 = min(e0 + EPB, N_EDGES);
    for (int e = e0 + threadIdx.x; e < e1; e += 256)
        atomicAdd(&cnt[ei[N_EDGES + e] >> 8], 1);
    __syncthreads();
    for (int b = threadIdx.x; b < NBUK; b += 256)
        cnts[b * NBLK + blockIdx.x] = cnt[b];
}

// ---------------------------------------------------------------------------
// 2) exclusive scan of NCNT counts (3 kernels)
// ---------------------------------------------------------------------------
__global__ __launch_bounds__(256) void scanA(
    const int* __restrict__ cnts, int* __restrict__ ebase, int* __restrict__ bsums)
{
    __shared__ int s[256];
    int t = threadIdx.x;
    int base = blockIdx.x * 1024 + t * 4;
    int v0 = (base + 0 < NCNT) ? cnts[base + 0] : 0;
    int v1 = (base + 1 < NCNT) ? cnts[base + 1] : 0;
    int v2 = (base + 2 < NCNT) ? cnts[base + 2] : 0;
    int v3 = (base + 3 < NCNT) ? cnts[base + 3] : 0;
    int sum = v0 + v1 + v2 + v3;
    s[t] = sum;
    __syncthreads();
    for (int off = 1; off < 256; off <<= 1) {
        int x = (t >= off) ? s[t - off] : 0;
        __syncthreads();
        s[t] += x;
        __syncthreads();
    }
    int excl = s[t] - sum;
    if (base + 0 < NCNT) ebase[base + 0] = excl;  excl += v0;
    if (base + 1 < NCNT) ebase[base + 1] = excl;  excl += v1;
    if (base + 2 < NCNT) ebase[base + 2] = excl;  excl += v2;
    if (base + 3 < NCNT) ebase[base + 3] = excl;
    if (t == 255) bsums[blockIdx.x] = s[255];
}

__global__ __launch_bounds__(256) void scanB(int* __restrict__ bsums)
{
    __shared__ int s[256];
    int t = threadIdx.x;
    int v = (t < NSC) ? bsums[t] : 0;
    s[t] = v;
    __syncthreads();
    for (int off = 1; off < 256; off <<= 1) {
        int x = (t >= off) ? s[t - off] : 0;
        __syncthreads();
        s[t] += x;
        __syncthreads();
    }
    if (t < NSC) bsums[t] = s[t] - v;   // exclusive
}

__global__ __launch_bounds__(256) void scanC(
    int* __restrict__ ebase, const int* __restrict__ bsums, int* __restrict__ bk)
{
    int i = blockIdx.x * 256 + threadIdx.x;
    if (i < NCNT) {
        int v = ebase[i] + bsums[i >> 10];
        ebase[i] = v;
        if (i % NBLK == 0) bk[i / NBLK] = v;   // bucket base
    }
    if (i == 0) bk[NBUK] = N_EDGES;
}

// ---------------------------------------------------------------------------
// 3) scatter: payload = src | attr<<17 | dst_local<<19, slot = mybase[b]+rank
// ---------------------------------------------------------------------------
__global__ __launch_bounds__(256) void pass2_scatter(
    const int* __restrict__ ei, const int* __restrict__ ea,
    const int* __restrict__ ebase, int* __restrict__ ebuf)
{
    __shared__ int cnt[NBUK];
    __shared__ int mybase[NBUK];
    for (int i = threadIdx.x; i < NBUK; i += 256) {
        cnt[i] = 0;
        mybase[i] = ebase[i * NBLK + blockIdx.x];
    }
    __syncthreads();
    int e0 = blockIdx.x * EPB;
    int e1 = min(e0 + EPB, N_EDGES);
    for (int e = e0 + threadIdx.x; e < e1; e += 256) {
        int src = ei[e];
        int dst = ei[N_EDGES + e];
        int at  = ea[e];
        int pay = src | (at << 17) | ((dst & 255) << 19);
        int b   = dst >> 8;
        int r   = atomicAdd(&cnt[b], 1);
        ebuf[mybase[b] + r] = pay;
    }
}

// ---------------------------------------------------------------------------
// 4) per-bucket node sort (512 threads). Writes rs[] and node-sorted col[].
// ---------------------------------------------------------------------------
__global__ __launch_bounds__(512) void phaseB_sort(
    const int* __restrict__ bk, const int* __restrict__ ebuf,
    int* __restrict__ rs, int* __restrict__ col)
{
    __shared__ int eb[CAPB];
    __shared__ int deg[256];
    __shared__ int cur[256];
    __shared__ int s[256];

    int b = blockIdx.x;
    int lo = bk[b], hi = bk[b + 1];
    int n_e = min(hi - lo, CAPB);
    int t = threadIdx.x;

    for (int i = t; i < n_e; i += 512) eb[i] = ebuf[lo + i];
    if (t < 256) deg[t] = 0;
    __syncthreads();

    for (int i = t; i < n_e; i += 512)
        atomicAdd(&deg[((unsigned)eb[i] >> 19)], 1);
    __syncthreads();

    if (t < 256) s[t] = deg[t];
    __syncthreads();
    for (int off = 1; off < 256; off <<= 1) {
        int xv = 0;
        if (t < 256 && t >= off) xv = s[t - off];
        __syncthreads();
        if (t < 256) s[t] += xv;
        __syncthreads();
    }
    if (t < 256) {
        int v = deg[t];
        int excl = s[t] - v;
        cur[t] = excl;
        int node = b * 256 + t;
        if (node < N_NODES) rs[node] = lo + excl;
    }
    if (b == NBUK - 1 && t == 0) rs[N_NODES] = N_EDGES;
    __syncthreads();

    for (int i = t; i < n_e; i += 512) {
        int pk = eb[i];
        int p = atomicAdd(&cur[(unsigned)pk >> 19], 1);
        col[lo + p] = pk;
    }
}

// ---------------------------------------------------------------------------
// Gather (fp16, packed): 16 lanes/node x 8 dims, _Float16 pk math, dot2
// accumulate, emb LUT in LDS. Output h as split bf16 hi/lo planes.
// ---------------------------------------------------------------------------
template<int HI>
__device__ __forceinline__ float h2acc(h2 m2, float acc) {
#if __has_builtin(__builtin_amdgcn_fdot2)
    h2 b;
    b[0] = (_Float16)(HI ? 0.f : 1.f);
    b[1] = (_Float16)(HI ? 1.f : 0.f);
    return __builtin_amdgcn_fdot2(m2, b, acc, false);
#else
    return acc + (float)m2[HI];
#endif
}

__device__ __forceinline__ void edge_acc(
    int pkv, int c, const unsigned* embh, float* acc, uint4 xv)
{
    const uint4 ev = *(const uint4*)&embh[((((unsigned)pkv >> 17) & 3) << 6) | (c << 2)];
    unsigned xs[4] = {xv.x, xv.y, xv.z, xv.w};
    unsigned es[4] = {ev.x, ev.y, ev.z, ev.w};
    const h2 z2 = (h2)(_Float16)0;
    #pragma unroll
    for (int j = 0; j < 4; ++j) {
        h2 a = __builtin_bit_cast(h2, xs[j]);
        h2 b = __builtin_bit_cast(h2, es[j]);
        h2 m2 = __builtin_elementwise_max(a + b, z2);
        acc[2 * j]     = h2acc<0>(m2, acc[2 * j]);
        acc[2 * j + 1] = h2acc<1>(m2, acc[2 * j + 1]);
    }
}

__global__ __launch_bounds__(256) void gather_f16(
    const float* __restrict__ x,
    const ushort* __restrict__ xh,
    const float* __restrict__ emb,
    const int* __restrict__ rs,
    const int* __restrict__ col,
    const float* __restrict__ eps_p,
    ushort* __restrict__ hhi, ushort* __restrict__ hlo)
{
    __shared__ unsigned embh[4 * DIM / 2];   // 1KB: fp16 emb LUT (packed pairs)
    {
        float2 f = ((const float2*)emb)[threadIdx.x & 255];
        __half2 h = __floats2half2_rn(f.x, f.y);
        embh[threadIdx.x & 255] = __builtin_bit_cast(unsigned, h);
    }
    __syncthreads();

    int gid = blockIdx.x * 256 + threadIdx.x;
    int n = gid >> 4;
    if (n >= N_NODES) return;
    int c = gid & 15;    // 8 dims per lane

    int start = rs[n], end = rs[n + 1];
    float acc[8] = {0.f, 0.f, 0.f, 0.f, 0.f, 0.f, 0.f, 0.f};

    int p = start;
    for (; p + 4 <= end; p += 4) {
        int pk[4];
        uint4 xv[4];
        #pragma unroll
        for (int u = 0; u < 4; ++u) pk[u] = col[p + u];
        #pragma unroll
        for (int u = 0; u < 4; ++u)
            xv[u] = ((const uint4*)xh)[((pk[u] & 0x1FFFF) << 4) | c];
        #pragma unroll
        for (int u = 0; u < 4; ++u)
            edge_acc(pk[u], c, embh, acc, xv[u]);
    }
    for (; p < end; ++p) {
        int pkv = col[p];
        uint4 xv = ((const uint4*)xh)[((pkv & 0x1FFFF) << 4) | c];
        edge_acc(pkv, c, embh, acc, xv);
    }

    float epsv = 1.0f + eps_p[0];
    float4 xa = ((const float4*)(x + (size_t)n * DIM))[c * 2];
    float4 xb = ((const float4*)(x + (size_t)n * DIM))[c * 2 + 1];
    float o[8];
    o[0] = epsv * xa.x + acc[0];
    o[1] = epsv * xa.y + acc[1];
    o[2] = epsv * xa.z + acc[2];
    o[3] = epsv * xa.w + acc[3];
    o[4] = epsv * xb.x + acc[4];
    o[5] = epsv * xb.y + acc[5];
    o[6] = epsv * xb.z + acc[6];
    o[7] = epsv * xb.w + acc[7];

    unsigned hiw[4], low[4];
    #pragma unroll
    for (int j = 0; j < 4; ++j) {
        unsigned short h0 = f2bf(o[2 * j]);
        unsigned short h1 = f2bf(o[2 * j + 1]);
        unsigned short l0 = f2bf(o[2 * j] - bf2f(h0));
        unsigned short l1 = f2bf(o[2 * j + 1] - bf2f(h1));
        hiw[j] = (unsigned)h0 | ((unsigned)h1 << 16);
        low[j] = (unsigned)l0 | ((unsigned)l1 << 16);
    }
    ((uint4*)(hhi + (size_t)n * DIM))[c] = make_uint4(hiw[0], hiw[1], hiw[2], hiw[3]);
    ((uint4*)(hlo + (size_t)n * DIM))[c] = make_uint4(low[0], low[1], low[2], low[3]);
}

// ---------------------------------------------------------------------------
// f32 fallback gather (only if ws_size can't fit xh)
// ---------------------------------------------------------------------------
__device__ __forceinline__ float4 sel4(
    float4 e0, float4 e1, float4 e2, float4 e3, int at)
{
    float4 a = (at & 1) ? e1 : e0;
    float4 b = (at & 1) ? e3 : e2;
    return (at & 2) ? b : a;
}

__device__ __forceinline__ void write_split(
    ushort* hhi, ushort* hlo, int n, int c, float4 o)
{
    ushort4 hi4, lo4;
    hi4.x = f2bf(o.x); lo4.x = f2bf(o.x - bf2f(hi4.x));
    hi4.y = f2bf(o.y); lo4.y = f2bf(o.y - bf2f(hi4.y));
    hi4.z = f2bf(o.z); lo4.z = f2bf(o.z - bf2f(hi4.z));
    hi4.w = f2bf(o.w); lo4.w = f2bf(o.w - bf2f(hi4.w));
    ((ushort4*)(hhi + (size_t)n * DIM))[c] = hi4;
    ((ushort4*)(hlo + (size_t)n * DIM))[c] = lo4;
}

__global__ __launch_bounds__(256) void gather_f32(
    const float* __restrict__ x,
    const float* __restrict__ emb,
    const int* __restrict__ rs,
    const int* __restrict__ col,
    const float* __restrict__ eps_p,
    ushort* __restrict__ hhi, ushort* __restrict__ hlo)
{
    int gid = blockIdx.x * 256 + threadIdx.x;
    int n = gid >> 5;
    if (n >= N_NODES) return;
    int c = gid & 31;

    float4 er0 = ((const float4*)(emb + 0 * DIM))[c];
    float4 er1 = ((const float4*)(emb + 1 * DIM))[c];
    float4 er2 = ((const float4*)(emb + 2 * DIM))[c];
    float4 er3 = ((const float4*)(emb + 3 * DIM))[c];

    int start = rs[n], end = rs[n + 1];
    float4 acc = make_float4(0.f, 0.f, 0.f, 0.f);

    int p = start;
    for (; p + 4 <= end; p += 4) {
        int pk[4];
        float4 xv[4];
        #pragma unroll
        for (int u = 0; u < 4; ++u) pk[u] = col[p + u];
        #pragma unroll
        for (int u = 0; u < 4; ++u)
            xv[u] = ((const float4*)(x + (size_t)(pk[u] & 0x1FFFF) * DIM))[c];
        #pragma unroll
        for (int u = 0; u < 4; ++u) {
            float4 ev = sel4(er0, er1, er2, er3, ((unsigned)pk[u] >> 17) & 3);
            acc.x += fmaxf(xv[u].x + ev.x, 0.f);
            acc.y += fmaxf(xv[u].y + ev.y, 0.f);
            acc.z += fmaxf(xv[u].z + ev.z, 0.f);
            acc.w += fmaxf(xv[u].w + ev.w, 0.f);
        }
    }
    for (; p < end; ++p) {
        int pk = col[p];
        float4 xv = ((const float4*)(x + (size_t)(pk & 0x1FFFF) * DIM))[c];
        float4 ev = sel4(er0, er1, er2, er3, ((unsigned)pk >> 17) & 3);
        acc.x += fmaxf(xv.x + ev.x, 0.f);
        acc.y += fmaxf(xv.y + ev.y, 0.f);
        acc.z += fmaxf(xv.z + ev.z, 0.f);
        acc.w += fmaxf(xv.w + ev.w, 0.f);
    }

    float epsv = 1.0f + eps_p[0];
    float4 xn = ((const float4*)(x + (size_t)n * DIM))[c];
    float4 o;
    o.x = epsv * xn.x + acc.x;
    o.y = epsv * xn.y + acc.y;
    o.z = epsv * xn.z + acc.z;
    o.w = epsv * xn.w + acc.w;
    write_split(hhi, hlo, n, c, o);
}

// ---------------------------------------------------------------------------
// Fused MLP via MFMA: 64-node tile / 256-thread block, 80KB LDS -> 2/CU,
// A-fragments from pre-split bf16 hi/lo planes.
// ---------------------------------------------------------------------------
__global__ __launch_bounds__(256) void fused_mlp(
    const ushort* __restrict__ hhi, const ushort* __restrict__ hlo,
    const float* __restrict__ W1, const float* __restrict__ b1,
    const float* __restrict__ lng, const float* __restrict__ lnb,
    const float* __restrict__ W2, const float* __restrict__ b2,
    float* __restrict__ out)
{
    __shared__ short w1s[DIM * DIM];
    __shared__ short w2s[DIM * DIM];
    __shared__ short scr[4 * 16 * DIM];

    for (int i4 = threadIdx.x; i4 < DIM * DIM / 4; i4 += 256) {
        int i = i4 * 4;
        int k = i >> 7, n0 = i & 127;
        float4 v1 = ((const float4*)W1)[i4];
        float4 v2 = ((const float4*)W2)[i4];
        float a1[4] = {v1.x, v1.y, v1.z, v1.w};
        float a2[4] = {v2.x, v2.y, v2.z, v2.w};
        #pragma unroll
        for (int q = 0; q < 4; ++q) {
            int n = n0 + q;
            int lane = (((k >> 3) & 3) << 4) | (n & 15);
            int off = (((k >> 5) * 8 + (n >> 4)) * 64 + lane) * 8 + (k & 7);
            w1s[off] = (short)f2bf(a1[q]);
            w2s[off] = (short)f2bf(a2[q]);
        }
    }
    __syncthreads();

    const int w  = threadIdx.x >> 6;
    const int l  = threadIdx.x & 63;
    const int lc = l & 15;
    const int lr = l >> 4;

    const int rbase = blockIdx.x * 64 + w * 16;
    const int arow = min(rbase + lc, N_NODES - 1);
    const ushort* hph = hhi + (size_t)arow * DIM;
    const ushort* hpl = hlo + (size_t)arow * DIM;

    float g[8], bb[8], bi1[8], bi2[8];
    #pragma unroll
    for (int nt = 0; nt < 8; ++nt) {
        g[nt]  = lng[nt * 16 + lc];
        bb[nt] = lnb[nt * 16 + lc];
        bi1[nt] = b1[nt * 16 + lc];
        bi2[nt] = b2[nt * 16 + lc];
    }

    f32x4 acc[8];
    #pragma unroll
    for (int nt = 0; nt < 8; ++nt)
        acc[nt] = (f32x4){bi1[nt], bi1[nt], bi1[nt], bi1[nt]};

    #pragma unroll
    for (int kt = 0; kt < 4; ++kt) {
        short8v ahi = *(const short8v*)(hph + kt * 32 + lr * 8);
        short8v alo = *(const short8v*)(hpl + kt * 32 + lr * 8);
        #pragma unroll
        for (int nt = 0; nt < 8; ++nt) {
            short8v bf = *(const short8v*)&w1s[((kt * 8 + nt) * 64 + l) * 8];
            acc[nt] = __builtin_amdgcn_mfma_f32_16x16x32_bf16(ahi, bf, acc[nt], 0, 0, 0);
            acc[nt] = __builtin_amdgcn_mfma_f32_16x16x32_bf16(alo, bf, acc[nt], 0, 0, 0);
        }
    }

    #pragma unroll
    for (int r = 0; r < 4; ++r) {
        float s1 = 0.f, s2 = 0.f;
        #pragma unroll
        for (int nt = 0; nt < 8; ++nt) { float v = acc[nt][r]; s1 += v; s2 += v * v; }
        s1 += __shfl_xor(s1, 1);  s2 += __shfl_xor(s2, 1);
        s1 += __shfl_xor(s1, 2);  s2 += __shfl_xor(s2, 2);
        s1 += __shfl_xor(s1, 4);  s2 += __shfl_xor(s2, 4);
        s1 += __shfl_xor(s1, 8);  s2 += __shfl_xor(s2, 8);
        float mu  = s1 * (1.0f / DIM);
        float var = s2 * (1.0f / DIM) - mu * mu;
        float rsd = rsqrtf(var + 1e-5f);
        int row = lr * 4 + r;
        #pragma unroll
        for (int nt = 0; nt < 8; ++nt) {
            float v = (acc[nt][r] - mu) * rsd * g[nt] + bb[nt];
            v = fmaxf(v, 0.f);
            int cidx = nt * 16 + lc;
            scr[w * 2048 + row * 128 + (((cidx >> 3) ^ row) << 3) + (cidx & 7)]
                = (short)f2bf(v);
        }
    }

    f32x4 acc2[8];
    #pragma unroll
    for (int nt = 0; nt < 8; ++nt)
        acc2[nt] = (f32x4){bi2[nt], bi2[nt], bi2[nt], bi2[nt]};

    #pragma unroll
    for (int kt = 0; kt < 4; ++kt) {
        short8v a2 = *(const short8v*)&scr[w * 2048 + lc * 128 + (((kt * 4 + lr) ^ lc) << 3)];
        #pragma unroll
        for (int nt = 0; nt < 8; ++nt) {
            short8v bf = *(const short8v*)&w2s[((kt * 8 + nt) * 64 + l) * 8];
            acc2[nt] = __builtin_amdgcn_mfma_f32_16x16x32_bf16(a2, bf, acc2[nt], 0, 0, 0);
        }
    }

    #pragma unroll
    for (int r = 0; r < 4; ++r) {
        int orow = rbase + lr * 4 + r;
        if (orow < N_NODES) {
            #pragma unroll
            for (int nt = 0; nt < 8; ++nt)
                out[(size_t)orow * DIM + nt * 16 + lc] = acc2[nt][r];
        }
    }
}

extern "C" void kernel_launch(void* const* d_in, const int* in_sizes, int n_in,
                              void* d_out, int out_size, void* d_ws, size_t ws_size,
                              hipStream_t stream) {
    const float* x    = (const float*)d_in[0];
    const int*   ei   = (const int*)d_in[1];
    const int*   ea   = (const int*)d_in[2];
    const float* emb  = (const float*)d_in[3];
    const float* epsp = (const float*)d_in[4];
    const float* W1   = (const float*)d_in[5];
    const float* b1   = (const float*)d_in[6];
    const float* lng  = (const float*)d_in[7];
    const float* lnb  = (const float*)d_in[8];
    const float* W2   = (const float*)d_in[9];
    const float* b2   = (const float*)d_in[10];
    float* out = (float*)d_out;

    // workspace layout (bytes, 128-aligned)
    char* ws = (char*)d_ws;
    int* rs    = (int*)(ws);                  // [N_NODES+1]
    int* bk    = (int*)(ws +   400128);       // [NBUK+1]
    int* bsums = (int*)(ws +   401792);       // [NSC]
    int* cnts  = (int*)(ws +   402816);       // [NCNT]
    int* ebase = (int*)(ws +  1014400);       // [NCNT]
    int* col   = (int*)(ws +  1625984);       // [N_EDGES]
    int* ebuf  = (int*)(ws +  8025984);       // [N_EDGES]
    ushort* hhi = (ushort*)(ws + 8025984);    // [N,128] bf16 hi (aliases ebuf, dead)
    ushort* hlo = (ushort*)(ws + 33625984);   // [N,128] bf16 lo
    ushort* xh  = (ushort*)(ws + 59225984);   // [N,128] fp16
    const size_t NEED = 59225984 + (size_t)N_NODES * DIM * 2;   // ~84.8 MB

    const int use_f16 = (ws_size >= NEED) ? 1 : 0;

    hist2_conv<<<NBLK, 256, 0, stream>>>(ei, cnts, x, xh, use_f16);
    scanA<<<NSC, 256, 0, stream>>>(cnts, ebase, bsums);
    scanB<<<1, 256, 0, stream>>>(bsums);
    scanC<<<(NCNT + 255) / 256, 256, 0, stream>>>(ebase, bsums, bk);
    pass2_scatter<<<NBLK, 256, 0, stream>>>(ei, ea, ebase, ebuf);
    phaseB_sort<<<NBUK, 512, 0, stream>>>(bk, ebuf, rs, col);

    if (use_f16) {
        gather_f16<<<(N_NODES * 16 + 255) / 256, 256, 0, stream>>>(
            x, xh, emb, rs, col, epsp, hhi, hlo);
    } else {
        gather_f32<<<(N_NODES * 32) / 256, 256, 0, stream>>>(
            x, emb, rs, col, epsp, hhi, hlo);
    }

    fused_mlp<<<(N_NODES + 63) / 64, 256, 0, stream>>>(
        hhi, hlo, W1, b1, lng, lnb, W2, b2, out);
}

// Round 12
// 159.633 us; speedup vs baseline: 4.2693x; 1.2243x over previous
//
#include <hip/hip_runtime.h>
#include <hip/hip_fp16.h>

#define N_NODES 100000
#define N_EDGES 1600000
#define DIM 128
#define NBUK 391      // ceil(N_NODES / 256), bucket = dst >> 8
#define EPB 4096      // edges per block in hist / scatter
#define NBLK 391      // ceil(N_EDGES / EPB)
#define NCNT (NBUK * NBLK)   // 152881 (block,bucket) counters
#define NSC 150       // ceil(NCNT / 1024) scan blocks
#define CAPB 5120     // max edges per bucket (mean 4092, +16 sigma)

typedef __attribute__((ext_vector_type(8))) short short8v;
typedef __attribute__((ext_vector_type(4))) float f32x4;
typedef _Float16 h2 __attribute__((ext_vector_type(2)));

__device__ __forceinline__ unsigned short f2bf(float f) {
    unsigned u = __float_as_uint(f);
    unsigned r = u + 0x7FFFu + ((u >> 16) & 1u);   // RTN-even
    return (unsigned short)(r >> 16);
}
__device__ __forceinline__ float bf2f(unsigned short b) {
    return __uint_as_float(((unsigned)b) << 16);
}

// ---------------------------------------------------------------------------
// 1) per-block bucket histogram  +  x->fp16 conversion (merged, independent)
// ---------------------------------------------------------------------------
__global__ __launch_bounds__(256) void hist2_conv(
    const int* __restrict__ ei, int* __restrict__ cnts,
    const float* __restrict__ x, ushort* __restrict__ xh, int do_conv)
{
    __shared__ int cnt[NBUK];
    for (int i = threadIdx.x; i < NBUK; i += 256) cnt[i] = 0;

    if (do_conv) {
        for (int i = blockIdx.x * 256 + threadIdx.x; i < N_NODES * DIM / 4;
             i += NBLK * 256) {
            float4 v = ((const float4*)x)[i];
            ushort4 o;
            o.x = __half_as_ushort(__float2half(v.x));
            o.y = __half_as_ushort(__float2half(v.y));
            o.z = __half_as_ushort(__float2half(v.z));
            o.w = __half_as_ushort(__float2half(v.w));
            ((ushort4*)xh)[i] = o;
        }
    }
    __syncthreads();

    int e0 = blockIdx.x * EPB;
    int e1 = min(e0 + EPB, N_EDGES);
    for (int e = e0 + threadIdx.x; e < e1; e += 256)
        atomicAdd(&cnt[ei[N_EDGES + e] >> 8], 1);
    __syncthreads();
    for (int b = threadIdx.x; b < NBUK; b += 256)
        cnts[b * NBLK + blockIdx.x] = cnt[b];
}

// ---------------------------------------------------------------------------
// 2) exclusive scan of NCNT counts (3 kernels)
// ---------------------------------------------------------------------------
__global__ __launch_bounds__(256) void scanA(
    const int* __restrict__ cnts, int* __restrict__ ebase, int* __restrict__ bsums)
{
    __shared__ int s[256];
    int t = threadIdx.x;
    int base = blockIdx.x * 1024 + t * 4;
    int v0 = (base + 0 < NCNT) ? cnts[base + 0] : 0;
    int v1 = (base + 1 < NCNT) ? cnts[base + 1] : 0;
    int v2 = (base + 2 < NCNT) ? cnts[base + 2] : 0;
    int v3 = (base + 3 < NCNT) ? cnts[base + 3] : 0;
    int sum = v0 + v1 + v2 + v3;
    s[t] = sum;
    __syncthreads();
    for (int off = 1; off < 256; off <<= 1) {
        int x = (t >= off) ? s[t - off] : 0;
        __syncthreads();
        s[t] += x;
        __syncthreads();
    }
    int excl = s[t] - sum;
    if (base + 0 < NCNT) ebase[base + 0] = excl;  excl += v0;
    if (base + 1 < NCNT) ebase[base + 1] = excl;  excl += v1;
    if (base + 2 < NCNT) ebase[base + 2] = excl;  excl += v2;
    if (base + 3 < NCNT) ebase[base + 3] = excl;
    if (t == 255) bsums[blockIdx.x] = s[255];
}

__global__ __launch_bounds__(256) void scanB(int* __restrict__ bsums)
{
    __shared__ int s[256];
    int t = threadIdx.x;
    int v = (t < NSC) ? bsums[t] : 0;
    s[t] = v;
    __syncthreads();
    for (int off = 1; off < 256; off <<= 1) {
        int x = (t >= off) ? s[t - off] : 0;
        __syncthreads();
        s[t] += x;
        __syncthreads();
    }
    if (t < NSC) bsums[t] = s[t] - v;   // exclusive
}

__global__ __launch_bounds__(256) void scanC(
    int* __restrict__ ebase, const int* __restrict__ bsums, int* __restrict__ bk)
{
    int i = blockIdx.x * 256 + threadIdx.x;
    if (i < NCNT) {
        int v = ebase[i] + bsums[i >> 10];
        ebase[i] = v;
        if (i % NBLK == 0) bk[i / NBLK] = v;   // bucket base
    }
    if (i == 0) bk[NBUK] = N_EDGES;
}

// ---------------------------------------------------------------------------
// prep_w: one-shot W1/W2 -> bf16 MFMA fragment layout in global ws.
// off o holds W[kt*32 + (lane>>4)*8 + j][nt*16 + (lane&15)],
// with lane=(o>>3)&63, j=o&7, kt=(o>>9)>>3, nt=(o>>9)&7.
// ---------------------------------------------------------------------------
__global__ __launch_bounds__(256) void prep_w(
    const float* __restrict__ W1, const float* __restrict__ W2,
    ushort* __restrict__ wf1, ushort* __restrict__ wf2)
{
    int o = blockIdx.x * 256 + threadIdx.x;   // 0..16383
    int lane = (o >> 3) & 63;
    int j = o & 7;
    int frag = o >> 9;
    int kt = frag >> 3, nt = frag & 7;
    int k = kt * 32 + (lane >> 4) * 8 + j;
    int n = nt * 16 + (lane & 15);
    wf1[o] = f2bf(W1[k * DIM + n]);
    wf2[o] = f2bf(W2[k * DIM + n]);
}

// ---------------------------------------------------------------------------
// 3) scatter: payload = src | attr<<17 | dst_local<<19, slot = mybase[b]+rank
// ---------------------------------------------------------------------------
__global__ __launch_bounds__(256) void pass2_scatter(
    const int* __restrict__ ei, const int* __restrict__ ea,
    const int* __restrict__ ebase, int* __restrict__ ebuf)
{
    __shared__ int cnt[NBUK];
    __shared__ int mybase[NBUK];
    for (int i = threadIdx.x; i < NBUK; i += 256) {
        cnt[i] = 0;
        mybase[i] = ebase[i * NBLK + blockIdx.x];
    }
    __syncthreads();
    int e0 = blockIdx.x * EPB;
    int e1 = min(e0 + EPB, N_EDGES);
    for (int e = e0 + threadIdx.x; e < e1; e += 256) {
        int src = ei[e];
        int dst = ei[N_EDGES + e];
        int at  = ea[e];
        int pay = src | (at << 17) | ((dst & 255) << 19);
        int b   = dst >> 8;
        int r   = atomicAdd(&cnt[b], 1);
        ebuf[mybase[b] + r] = pay;
    }
}

// ---------------------------------------------------------------------------
// 4) per-bucket node sort (512 threads). Writes rs[] and node-sorted col[].
// ---------------------------------------------------------------------------
__global__ __launch_bounds__(512) void phaseB_sort(
    const int* __restrict__ bk, const int* __restrict__ ebuf,
    int* __restrict__ rs, int* __restrict__ col)
{
    __shared__ int eb[CAPB];
    __shared__ int deg[256];
    __shared__ int cur[256];
    __shared__ int s[256];

    int b = blockIdx.x;
    int lo = bk[b], hi = bk[b + 1];
    int n_e = min(hi - lo, CAPB);
    int t = threadIdx.x;

    for (int i = t; i < n_e; i += 512) eb[i] = ebuf[lo + i];
    if (t < 256) deg[t] = 0;
    __syncthreads();

    for (int i = t; i < n_e; i += 512)
        atomicAdd(&deg[((unsigned)eb[i] >> 19)], 1);
    __syncthreads();

    if (t < 256) s[t] = deg[t];
    __syncthreads();
    for (int off = 1; off < 256; off <<= 1) {
        int xv = 0;
        if (t < 256 && t >= off) xv = s[t - off];
        __syncthreads();
        if (t < 256) s[t] += xv;
        __syncthreads();
    }
    if (t < 256) {
        int v = deg[t];
        int excl = s[t] - v;
        cur[t] = excl;
        int node = b * 256 + t;
        if (node < N_NODES) rs[node] = lo + excl;
    }
    if (b == NBUK - 1 && t == 0) rs[N_NODES] = N_EDGES;
    __syncthreads();

    for (int i = t; i < n_e; i += 512) {
        int pk = eb[i];
        int p = atomicAdd(&cur[(unsigned)pk >> 19], 1);
        col[lo + p] = pk;
    }
}

// ---------------------------------------------------------------------------
// Gather (fp16, packed): 16 lanes/node x 8 dims, _Float16 pk math, dot2
// accumulate, emb LUT in LDS. Output h as split bf16 hi/lo planes.
// ---------------------------------------------------------------------------
template<int HI>
__device__ __forceinline__ float h2acc(h2 m2, float acc) {
#if __has_builtin(__builtin_amdgcn_fdot2)
    h2 b;
    b[0] = (_Float16)(HI ? 0.f : 1.f);
    b[1] = (_Float16)(HI ? 1.f : 0.f);
    return __builtin_amdgcn_fdot2(m2, b, acc, false);
#else
    return acc + (float)m2[HI];
#endif
}

__device__ __forceinline__ void edge_acc(
    int pkv, int c, const unsigned* embh, float* acc, uint4 xv)
{
    const uint4 ev = *(const uint4*)&embh[((((unsigned)pkv >> 17) & 3) << 6) | (c << 2)];
    unsigned xs[4] = {xv.x, xv.y, xv.z, xv.w};
    unsigned es[4] = {ev.x, ev.y, ev.z, ev.w};
    const h2 z2 = (h2)(_Float16)0;
    #pragma unroll
    for (int j = 0; j < 4; ++j) {
        h2 a = __builtin_bit_cast(h2, xs[j]);
        h2 b = __builtin_bit_cast(h2, es[j]);
        h2 m2 = __builtin_elementwise_max(a + b, z2);
        acc[2 * j]     = h2acc<0>(m2, acc[2 * j]);
        acc[2 * j + 1] = h2acc<1>(m2, acc[2 * j + 1]);
    }
}

__global__ __launch_bounds__(256) void gather_f16(
    const float* __restrict__ x,
    const ushort* __restrict__ xh,
    const float* __restrict__ emb,
    const int* __restrict__ rs,
    const int* __restrict__ col,
    const float* __restrict__ eps_p,
    ushort* __restrict__ hhi, ushort* __restrict__ hlo)
{
    __shared__ unsigned embh[4 * DIM / 2];   // 1KB: fp16 emb LUT (packed pairs)
    {
        float2 f = ((const float2*)emb)[threadIdx.x & 255];
        __half2 h = __floats2half2_rn(f.x, f.y);
        embh[threadIdx.x & 255] = __builtin_bit_cast(unsigned, h);
    }
    __syncthreads();

    int gid = blockIdx.x * 256 + threadIdx.x;
    int n = gid >> 4;
    if (n >= N_NODES) return;
    int c = gid & 15;    // 8 dims per lane

    int start = rs[n], end = rs[n + 1];
    float acc[8] = {0.f, 0.f, 0.f, 0.f, 0.f, 0.f, 0.f, 0.f};

    int p = start;
    for (; p + 4 <= end; p += 4) {
        int pk[4];
        uint4 xv[4];
        #pragma unroll
        for (int u = 0; u < 4; ++u) pk[u] = col[p + u];
        #pragma unroll
        for (int u = 0; u < 4; ++u)
            xv[u] = ((const uint4*)xh)[((pk[u] & 0x1FFFF) << 4) | c];
        #pragma unroll
        for (int u = 0; u < 4; ++u)
            edge_acc(pk[u], c, embh, acc, xv[u]);
    }
    for (; p < end; ++p) {
        int pkv = col[p];
        uint4 xv = ((const uint4*)xh)[((pkv & 0x1FFFF) << 4) | c];
        edge_acc(pkv, c, embh, acc, xv);
    }

    float epsv = 1.0f + eps_p[0];
    float4 xa = ((const float4*)(x + (size_t)n * DIM))[c * 2];
    float4 xb = ((const float4*)(x + (size_t)n * DIM))[c * 2 + 1];
    float o[8];
    o[0] = epsv * xa.x + acc[0];
    o[1] = epsv * xa.y + acc[1];
    o[2] = epsv * xa.z + acc[2];
    o[3] = epsv * xa.w + acc[3];
    o[4] = epsv * xb.x + acc[4];
    o[5] = epsv * xb.y + acc[5];
    o[6] = epsv * xb.z + acc[6];
    o[7] = epsv * xb.w + acc[7];

    unsigned hiw[4], low[4];
    #pragma unroll
    for (int j = 0; j < 4; ++j) {
        unsigned short h0 = f2bf(o[2 * j]);
        unsigned short h1 = f2bf(o[2 * j + 1]);
        unsigned short l0 = f2bf(o[2 * j] - bf2f(h0));
        unsigned short l1 = f2bf(o[2 * j + 1] - bf2f(h1));
        hiw[j] = (unsigned)h0 | ((unsigned)h1 << 16);
        low[j] = (unsigned)l0 | ((unsigned)l1 << 16);
    }
    ((uint4*)(hhi + (size_t)n * DIM))[c] = make_uint4(hiw[0], hiw[1], hiw[2], hiw[3]);
    ((uint4*)(hlo + (size_t)n * DIM))[c] = make_uint4(low[0], low[1], low[2], low[3]);
}

// ---------------------------------------------------------------------------
// f32 fallback gather (only if ws_size can't fit xh)
// ---------------------------------------------------------------------------
__device__ __forceinline__ float4 sel4(
    float4 e0, float4 e1, float4 e2, float4 e3, int at)
{
    float4 a = (at & 1) ? e1 : e0;
    float4 b = (at & 1) ? e3 : e2;
    return (at & 2) ? b : a;
}

__device__ __forceinline__ void write_split(
    ushort* hhi, ushort* hlo, int n, int c, float4 o)
{
    ushort4 hi4, lo4;
    hi4.x = f2bf(o.x); lo4.x = f2bf(o.x - bf2f(hi4.x));
    hi4.y = f2bf(o.y); lo4.y = f2bf(o.y - bf2f(hi4.y));
    hi4.z = f2bf(o.z); lo4.z = f2bf(o.z - bf2f(hi4.z));
    hi4.w = f2bf(o.w); lo4.w = f2bf(o.w - bf2f(hi4.w));
    ((ushort4*)(hhi + (size_t)n * DIM))[c] = hi4;
    ((ushort4*)(hlo + (size_t)n * DIM))[c] = lo4;
}

__global__ __launch_bounds__(256) void gather_f32(
    const float* __restrict__ x,
    const float* __restrict__ emb,
    const int* __restrict__ rs,
    const int* __restrict__ col,
    const float* __restrict__ eps_p,
    ushort* __restrict__ hhi, ushort* __restrict__ hlo)
{
    int gid = blockIdx.x * 256 + threadIdx.x;
    int n = gid >> 5;
    if (n >= N_NODES) return;
    int c = gid & 31;

    float4 er0 = ((const float4*)(emb + 0 * DIM))[c];
    float4 er1 = ((const float4*)(emb + 1 * DIM))[c];
    float4 er2 = ((const float4*)(emb + 2 * DIM))[c];
    float4 er3 = ((const float4*)(emb + 3 * DIM))[c];

    int start = rs[n], end = rs[n + 1];
    float4 acc = make_float4(0.f, 0.f, 0.f, 0.f);

    int p = start;
    for (; p + 4 <= end; p += 4) {
        int pk[4];
        float4 xv[4];
        #pragma unroll
        for (int u = 0; u < 4; ++u) pk[u] = col[p + u];
        #pragma unroll
        for (int u = 0; u < 4; ++u)
            xv[u] = ((const float4*)(x + (size_t)(pk[u] & 0x1FFFF) * DIM))[c];
        #pragma unroll
        for (int u = 0; u < 4; ++u) {
            float4 ev = sel4(er0, er1, er2, er3, ((unsigned)pk[u] >> 17) & 3);
            acc.x += fmaxf(xv[u].x + ev.x, 0.f);
            acc.y += fmaxf(xv[u].y + ev.y, 0.f);
            acc.z += fmaxf(xv[u].z + ev.z, 0.f);
            acc.w += fmaxf(xv[u].w + ev.w, 0.f);
        }
    }
    for (; p < end; ++p) {
        int pk = col[p];
        float4 xv = ((const float4*)(x + (size_t)(pk & 0x1FFFF) * DIM))[c];
        float4 ev = sel4(er0, er1, er2, er3, ((unsigned)pk >> 17) & 3);
        acc.x += fmaxf(xv.x + ev.x, 0.f);
        acc.y += fmaxf(xv.y + ev.y, 0.f);
        acc.z += fmaxf(xv.z + ev.z, 0.f);
        acc.w += fmaxf(xv.w + ev.w, 0.f);
    }

    float epsv = 1.0f + eps_p[0];
    float4 xn = ((const float4*)(x + (size_t)n * DIM))[c];
    float4 o;
    o.x = epsv * xn.x + acc.x;
    o.y = epsv * xn.y + acc.y;
    o.z = epsv * xn.z + acc.z;
    o.w = epsv * xn.w + acc.w;
    write_split(hhi, hlo, n, c, o);
}

// ---------------------------------------------------------------------------
// Fused MLP via MFMA: 64-node tile / 256-thread block, 80KB LDS -> 2/CU.
// W staged from PRE-FORMATTED bf16 fragment arrays (plain uint4 copies).
// ---------------------------------------------------------------------------
__global__ __launch_bounds__(256) void fused_mlp(
    const ushort* __restrict__ hhi, const ushort* __restrict__ hlo,
    const ushort* __restrict__ wf1, const ushort* __restrict__ wf2,
    const float* __restrict__ b1,
    const float* __restrict__ lng, const float* __restrict__ lnb,
    const float* __restrict__ b2,
    float* __restrict__ out)
{
    __shared__ short w1s[DIM * DIM];
    __shared__ short w2s[DIM * DIM];
    __shared__ short scr[4 * 16 * DIM];

    #pragma unroll
    for (int i = 0; i < 8; ++i) {
        int idx = i * 256 + threadIdx.x;
        ((uint4*)w1s)[idx] = ((const uint4*)wf1)[idx];
        ((uint4*)w2s)[idx] = ((const uint4*)wf2)[idx];
    }
    __syncthreads();

    const int w  = threadIdx.x >> 6;
    const int l  = threadIdx.x & 63;
    const int lc = l & 15;
    const int lr = l >> 4;

    const int rbase = blockIdx.x * 64 + w * 16;
    const int arow = min(rbase + lc, N_NODES - 1);
    const ushort* hph = hhi + (size_t)arow * DIM;
    const ushort* hpl = hlo + (size_t)arow * DIM;

    float g[8], bb[8], bi1[8], bi2[8];
    #pragma unroll
    for (int nt = 0; nt < 8; ++nt) {
        g[nt]  = lng[nt * 16 + lc];
        bb[nt] = lnb[nt * 16 + lc];
        bi1[nt] = b1[nt * 16 + lc];
        bi2[nt] = b2[nt * 16 + lc];
    }

    f32x4 acc[8];
    #pragma unroll
    for (int nt = 0; nt < 8; ++nt)
        acc[nt] = (f32x4){bi1[nt], bi1[nt], bi1[nt], bi1[nt]};

    #pragma unroll
    for (int kt = 0; kt < 4; ++kt) {
        short8v ahi = *(const short8v*)(hph + kt * 32 + lr * 8);
        short8v alo = *(const short8v*)(hpl + kt * 32 + lr * 8);
        #pragma unroll
        for (int nt = 0; nt < 8; ++nt) {
            short8v bf = *(const short8v*)&w1s[((kt * 8 + nt) * 64 + l) * 8];
            acc[nt] = __builtin_amdgcn_mfma_f32_16x16x32_bf16(ahi, bf, acc[nt], 0, 0, 0);
            acc[nt] = __builtin_amdgcn_mfma_f32_16x16x32_bf16(alo, bf, acc[nt], 0, 0, 0);
        }
    }

    #pragma unroll
    for (int r = 0; r < 4; ++r) {
        float s1 = 0.f, s2 = 0.f;
        #pragma unroll
        for (int nt = 0; nt < 8; ++nt) { float v = acc[nt][r]; s1 += v; s2 += v * v; }
        s1 += __shfl_xor(s1, 1);  s2 += __shfl_xor(s2, 1);
        s1 += __shfl_xor(s1, 2);  s2 += __shfl_xor(s2, 2);
        s1 += __shfl_xor(s1, 4);  s2 += __shfl_xor(s2, 4);
        s1 += __shfl_xor(s1, 8);  s2 += __shfl_xor(s2, 8);
        float mu  = s1 * (1.0f / DIM);
        float var = s2 * (1.0f / DIM) - mu * mu;
        float rsd = rsqrtf(var + 1e-5f);
        int row = lr * 4 + r;
        #pragma unroll
        for (int nt = 0; nt < 8; ++nt) {
            float v = (acc[nt][r] - mu) * rsd * g[nt] + bb[nt];
            v = fmaxf(v, 0.f);
            int cidx = nt * 16 + lc;
            scr[w * 2048 + row * 128 + (((cidx >> 3) ^ row) << 3) + (cidx & 7)]
                = (short)f2bf(v);
        }
    }

    f32x4 acc2[8];
    #pragma unroll
    for (int nt = 0; nt < 8; ++nt)
        acc2[nt] = (f32x4){bi2[nt], bi2[nt], bi2[nt], bi2[nt]};

    #pragma unroll
    for (int kt = 0; kt < 4; ++kt) {
        short8v a2 = *(const short8v*)&scr[w * 2048 + lc * 128 + (((kt * 4 + lr) ^ lc) << 3)];
        #pragma unroll
        for (int nt = 0; nt < 8; ++nt) {
            short8v bf = *(const short8v*)&w2s[((kt * 8 + nt) * 64 + l) * 8];
            acc2[nt] = __builtin_amdgcn_mfma_f32_16x16x32_bf16(a2, bf, acc2[nt], 0, 0, 0);
        }
    }

    #pragma unroll
    for (int r = 0; r < 4; ++r) {
        int orow = rbase + lr * 4 + r;
        if (orow < N_NODES) {
            #pragma unroll
            for (int nt = 0; nt < 8; ++nt)
                out[(size_t)orow * DIM + nt * 16 + lc] = acc2[nt][r];
        }
    }
}

extern "C" void kernel_launch(void* const* d_in, const int* in_sizes, int n_in,
                              void* d_out, int out_size, void* d_ws, size_t ws_size,
                              hipStream_t stream) {
    const float* x    = (const float*)d_in[0];
    const int*   ei   = (const int*)d_in[1];
    const int*   ea   = (const int*)d_in[2];
    const float* emb  = (const float*)d_in[3];
    const float* epsp = (const float*)d_in[4];
    const float* W1   = (const float*)d_in[5];
    const float* b1   = (const float*)d_in[6];
    const float* lng  = (const float*)d_in[7];
    const float* lnb  = (const float*)d_in[8];
    const float* W2   = (const float*)d_in[9];
    const float* b2   = (const float*)d_in[10];
    float* out = (float*)d_out;

    // workspace layout (bytes, 128-aligned)
    char* ws = (char*)d_ws;
    int* rs    = (int*)(ws);                  // [N_NODES+1]
    int* bk    = (int*)(ws +   400128);       // [NBUK+1]
    int* bsums = (int*)(ws +   401792);       // [NSC]
    int* cnts  = (int*)(ws +   402816);       // [NCNT] (dead after scanA)
    ushort* wf1 = (ushort*)(ws + 402816);     // [16384] bf16 frags (aliases cnts)
    ushort* wf2 = (ushort*)(ws + 435584);     // [16384]
    int* ebase = (int*)(ws +  1014400);       // [NCNT]
    int* col   = (int*)(ws +  1625984);       // [N_EDGES]
    int* ebuf  = (int*)(ws +  8025984);       // [N_EDGES]
    ushort* hhi = (ushort*)(ws + 8025984);    // [N,128] bf16 hi (aliases ebuf, dead)
    ushort* hlo = (ushort*)(ws + 33625984);   // [N,128] bf16 lo
    ushort* xh  = (ushort*)(ws + 59225984);   // [N,128] fp16
    const size_t NEED = 59225984 + (size_t)N_NODES * DIM * 2;   // ~84.8 MB

    const int use_f16 = (ws_size >= NEED) ? 1 : 0;

    hist2_conv<<<NBLK, 256, 0, stream>>>(ei, cnts, x, xh, use_f16);
    scanA<<<NSC, 256, 0, stream>>>(cnts, ebase, bsums);
    scanB<<<1, 256, 0, stream>>>(bsums);
    scanC<<<(NCNT + 255) / 256, 256, 0, stream>>>(ebase, bsums, bk);
    prep_w<<<64, 256, 0, stream>>>(W1, W2, wf1, wf2);   // cnts dead now
    pass2_scatter<<<NBLK, 256, 0, stream>>>(ei, ea, ebase, ebuf);
    phaseB_sort<<<NBUK, 512, 0, stream>>>(bk, ebuf, rs, col);

    if (use_f16) {
        gather_f16<<<(N_NODES * 16 + 255) / 256, 256, 0, stream>>>(
            x, xh, emb, rs, col, epsp, hhi, hlo);
    } else {
        gather_f32<<<(N_NODES * 32) / 256, 256, 0, stream>>>(
            x, emb, rs, col, epsp, hhi, hlo);
    }

    fused_mlp<<<(N_NODES + 63) / 64, 256, 0, stream>>>(
        hhi, hlo, wf1, wf2, b1, lng, lnb, b2, out);
}

// Round 13
// 158.807 us; speedup vs baseline: 4.2915x; 1.0052x over previous
//
#include <hip/hip_runtime.h>
#include <hip/hip_fp16.h>

#define N_NODES 100000
#define N_EDGES 1600000
#define DIM 128
#define NBUK 782      // ceil(N_NODES / 128), bucket = dst >> 7
#define EPB 4096      // edges per block in hist / scatter
#define NBLK 391      // ceil(N_EDGES / EPB)
#define NCNT (NBUK * NBLK)   // 305762 (bucket,block) counters
#define NSC 299       // ceil(NCNT / 1024) scan blocks
#define CAPB 2720     // max edges per bucket (mean 2048, +14 sigma)

typedef __attribute__((ext_vector_type(8))) short short8v;
typedef __attribute__((ext_vector_type(4))) float f32x4;
typedef _Float16 h2 __attribute__((ext_vector_type(2)));

__device__ __forceinline__ unsigned short f2bf(float f) {
    unsigned u = __float_as_uint(f);
    unsigned r = u + 0x7FFFu + ((u >> 16) & 1u);   // RTN-even
    return (unsigned short)(r >> 16);
}
__device__ __forceinline__ float bf2f(unsigned short b) {
    return __uint_as_float(((unsigned)b) << 16);
}

// ---------------------------------------------------------------------------
// 1) per-block bucket histogram + x->fp16 conversion (merged)
// ---------------------------------------------------------------------------
__global__ __launch_bounds__(256) void hist2_conv(
    const int* __restrict__ ei, int* __restrict__ cnts,
    const float* __restrict__ x, ushort* __restrict__ xh, int do_conv)
{
    __shared__ int cnt[NBUK];
    for (int i = threadIdx.x; i < NBUK; i += 256) cnt[i] = 0;

    if (do_conv) {
        for (int i = blockIdx.x * 256 + threadIdx.x; i < N_NODES * DIM / 4;
             i += NBLK * 256) {
            float4 v = ((const float4*)x)[i];
            ushort4 o;
            o.x = __half_as_ushort(__float2half(v.x));
            o.y = __half_as_ushort(__float2half(v.y));
            o.z = __half_as_ushort(__float2half(v.z));
            o.w = __half_as_ushort(__float2half(v.w));
            ((ushort4*)xh)[i] = o;
        }
    }
    __syncthreads();

    int e0 = blockIdx.x * EPB;
    int e1 = min(e0 + EPB, N_EDGES);
    for (int e = e0 + threadIdx.x; e < e1; e += 256)
        atomicAdd(&cnt[ei[N_EDGES + e] >> 7], 1);
    __syncthreads();
    for (int b = threadIdx.x; b < NBUK; b += 256)
        cnts[b * NBLK + blockIdx.x] = cnt[b];
}

// ---------------------------------------------------------------------------
// 2) exclusive scan of NCNT counts, IN-PLACE on cnts (3 kernels)
// ---------------------------------------------------------------------------
__global__ __launch_bounds__(256) void scanA(
    int* __restrict__ cnts, int* __restrict__ bsums)
{
    __shared__ int s[256];
    int t = threadIdx.x;
    int base = blockIdx.x * 1024 + t * 4;
    int v0 = (base + 0 < NCNT) ? cnts[base + 0] : 0;
    int v1 = (base + 1 < NCNT) ? cnts[base + 1] : 0;
    int v2 = (base + 2 < NCNT) ? cnts[base + 2] : 0;
    int v3 = (base + 3 < NCNT) ? cnts[base + 3] : 0;
    int sum = v0 + v1 + v2 + v3;
    s[t] = sum;
    __syncthreads();
    for (int off = 1; off < 256; off <<= 1) {
        int x = (t >= off) ? s[t - off] : 0;
        __syncthreads();
        s[t] += x;
        __syncthreads();
    }
    int excl = s[t] - sum;
    if (base + 0 < NCNT) cnts[base + 0] = excl;  excl += v0;
    if (base + 1 < NCNT) cnts[base + 1] = excl;  excl += v1;
    if (base + 2 < NCNT) cnts[base + 2] = excl;  excl += v2;
    if (base + 3 < NCNT) cnts[base + 3] = excl;
    if (t == 255) bsums[blockIdx.x] = s[255];
}

__global__ __launch_bounds__(512) void scanB(int* __restrict__ bsums)
{
    __shared__ int s[512];
    int t = threadIdx.x;
    int v = (t < NSC) ? bsums[t] : 0;
    s[t] = v;
    __syncthreads();
    for (int off = 1; off < 512; off <<= 1) {
        int x = (t >= off) ? s[t - off] : 0;
        __syncthreads();
        s[t] += x;
        __syncthreads();
    }
    if (t < NSC) bsums[t] = s[t] - v;   // exclusive
}

// scanC + prep_w folded: blocks also convert W1/W2 to bf16 fragment layout.
__global__ __launch_bounds__(256) void scanC_prepw(
    int* __restrict__ ebase, const int* __restrict__ bsums, int* __restrict__ bk,
    const float* __restrict__ W1, const float* __restrict__ W2,
    ushort* __restrict__ wf1, ushort* __restrict__ wf2)
{
    int i = blockIdx.x * 256 + threadIdx.x;
    if (i < NCNT) {
        int v = ebase[i] + bsums[i >> 10];
        ebase[i] = v;
        if (i % NBLK == 0) bk[i / NBLK] = v;   // bucket base
    }
    if (i == 0) bk[NBUK] = N_EDGES;

    if (i < DIM * DIM) {   // prep_w: fragment layout
        int lane = (i >> 3) & 63;
        int j = i & 7;
        int frag = i >> 9;
        int kt = frag >> 3, nt = frag & 7;
        int k = kt * 32 + (lane >> 4) * 8 + j;
        int n = nt * 16 + (lane & 15);
        wf1[i] = f2bf(W1[k * DIM + n]);
        wf2[i] = f2bf(W2[k * DIM + n]);
    }
}

// ---------------------------------------------------------------------------
// 3) scatter: payload = src | attr<<17 | dst_local<<19 (7 bits)
// ---------------------------------------------------------------------------
__global__ __launch_bounds__(256) void pass2_scatter(
    const int* __restrict__ ei, const int* __restrict__ ea,
    const int* __restrict__ ebase, int* __restrict__ ebuf)
{
    __shared__ int cnt[NBUK];
    __shared__ int mybase[NBUK];
    for (int i = threadIdx.x; i < NBUK; i += 256) {
        cnt[i] = 0;
        mybase[i] = ebase[i * NBLK + blockIdx.x];
    }
    __syncthreads();
    int e0 = blockIdx.x * EPB;
    int e1 = min(e0 + EPB, N_EDGES);
    for (int e = e0 + threadIdx.x; e < e1; e += 256) {
        int src = ei[e];
        int dst = ei[N_EDGES + e];
        int at  = ea[e];
        int pay = src | (at << 17) | ((dst & 127) << 19);
        int b   = dst >> 7;
        int r   = atomicAdd(&cnt[b], 1);
        ebuf[mybase[b] + r] = pay;
    }
}

// ---------------------------------------------------------------------------
// 4) FUSED per-bucket sort + gather. One block per bucket (128 nodes),
// 512 threads. Sort edges in LDS, then gather directly from LDS list.
// Output h as split bf16 hi/lo planes.
// ---------------------------------------------------------------------------
template<int HI>
__device__ __forceinline__ float h2acc(h2 m2, float acc) {
#if __has_builtin(__builtin_amdgcn_fdot2)
    h2 b;
    b[0] = (_Float16)(HI ? 0.f : 1.f);
    b[1] = (_Float16)(HI ? 1.f : 0.f);
    return __builtin_amdgcn_fdot2(m2, b, acc, false);
#else
    return acc + (float)m2[HI];
#endif
}

__device__ __forceinline__ void edge_acc(
    int pkv, int c, const unsigned* embh, float* acc, uint4 xv)
{
    const uint4 ev = *(const uint4*)&embh[((((unsigned)pkv >> 17) & 3) << 6) | (c << 2)];
    unsigned xs[4] = {xv.x, xv.y, xv.z, xv.w};
    unsigned es[4] = {ev.x, ev.y, ev.z, ev.w};
    const h2 z2 = (h2)(_Float16)0;
    #pragma unroll
    for (int j = 0; j < 4; ++j) {
        h2 a = __builtin_bit_cast(h2, xs[j]);
        h2 b = __builtin_bit_cast(h2, es[j]);
        h2 m2 = __builtin_elementwise_max(a + b, z2);
        acc[2 * j]     = h2acc<0>(m2, acc[2 * j]);
        acc[2 * j + 1] = h2acc<1>(m2, acc[2 * j + 1]);
    }
}

template<int USE16>
__global__ __launch_bounds__(512) void sort_gather(
    const int* __restrict__ bk, const int* __restrict__ ebuf,
    const float* __restrict__ x, const ushort* __restrict__ xh,
    const float* __restrict__ emb, const float* __restrict__ eps_p,
    ushort* __restrict__ hhi, ushort* __restrict__ hlo)
{
    __shared__ int eb[CAPB];
    __shared__ int col_l[CAPB];
    __shared__ int deg[128], sc[128], cur[128];
    __shared__ unsigned embh[256];   // fp16 LUT (USE16)
    __shared__ float femb[512];      // f32 LUT (fallback)

    const int b = blockIdx.x;
    const int t = threadIdx.x;
    const int lo = bk[b];
    const int n_e = min(bk[b + 1] - lo, CAPB);

    if (t < 256) {
        float2 f = ((const float2*)emb)[t];
        if (USE16) {
            __half2 h = __floats2half2_rn(f.x, f.y);
            embh[t] = __builtin_bit_cast(unsigned, h);
        } else {
            femb[2 * t] = f.x;
            femb[2 * t + 1] = f.y;
        }
    }
    if (t < 128) deg[t] = 0;
    for (int i = t; i < n_e; i += 512) eb[i] = ebuf[lo + i];
    __syncthreads();

    for (int i = t; i < n_e; i += 512)
        atomicAdd(&deg[((unsigned)eb[i] >> 19) & 127], 1);
    __syncthreads();

    if (t < 128) sc[t] = deg[t];
    __syncthreads();
    for (int off = 1; off < 128; off <<= 1) {
        int v = 0;
        if (t < 128 && t >= off) v = sc[t - off];
        __syncthreads();
        if (t < 128) sc[t] += v;
        __syncthreads();
    }
    if (t < 128) cur[t] = sc[t] - deg[t];
    __syncthreads();

    for (int i = t; i < n_e; i += 512) {
        int pk = eb[i];
        int p = atomicAdd(&cur[((unsigned)pk >> 19) & 127], 1);
        col_l[p] = pk;
    }
    __syncthreads();

    // ---- gather from LDS-sorted list: 32 groups x 16 lanes ----
    const int g = t >> 4, c = t & 15;
    const float epsv = 1.0f + eps_p[0];

    for (int ln = g; ln < 128; ln += 32) {
        int n = b * 128 + ln;
        if (n >= N_NODES) break;
        int start = sc[ln] - deg[ln], end = sc[ln];
        float acc[8] = {0.f, 0.f, 0.f, 0.f, 0.f, 0.f, 0.f, 0.f};

        if (USE16) {
            int p = start;
            for (; p + 4 <= end; p += 4) {
                int pk[4];
                uint4 xv[4];
                #pragma unroll
                for (int u = 0; u < 4; ++u) pk[u] = col_l[p + u];
                #pragma unroll
                for (int u = 0; u < 4; ++u)
                    xv[u] = ((const uint4*)xh)[((pk[u] & 0x1FFFF) << 4) | c];
                #pragma unroll
                for (int u = 0; u < 4; ++u)
                    edge_acc(pk[u], c, embh, acc, xv[u]);
            }
            for (; p < end; ++p) {
                int pkv = col_l[p];
                uint4 xv = ((const uint4*)xh)[((pkv & 0x1FFFF) << 4) | c];
                edge_acc(pkv, c, embh, acc, xv);
            }
        } else {
            for (int p = start; p < end; ++p) {
                int pk = col_l[p];
                const float* xr = x + (size_t)(pk & 0x1FFFF) * DIM;
                float4 xa = ((const float4*)xr)[c * 2];
                float4 xb = ((const float4*)xr)[c * 2 + 1];
                const float* er = &femb[(((unsigned)pk >> 17) & 3) * DIM + c * 8];
                acc[0] += fmaxf(xa.x + er[0], 0.f);
                acc[1] += fmaxf(xa.y + er[1], 0.f);
                acc[2] += fmaxf(xa.z + er[2], 0.f);
                acc[3] += fmaxf(xa.w + er[3], 0.f);
                acc[4] += fmaxf(xb.x + er[4], 0.f);
                acc[5] += fmaxf(xb.y + er[5], 0.f);
                acc[6] += fmaxf(xb.z + er[6], 0.f);
                acc[7] += fmaxf(xb.w + er[7], 0.f);
            }
        }

        float4 xa = ((const float4*)(x + (size_t)n * DIM))[c * 2];
        float4 xb = ((const float4*)(x + (size_t)n * DIM))[c * 2 + 1];
        float o[8];
        o[0] = epsv * xa.x + acc[0];
        o[1] = epsv * xa.y + acc[1];
        o[2] = epsv * xa.z + acc[2];
        o[3] = epsv * xa.w + acc[3];
        o[4] = epsv * xb.x + acc[4];
        o[5] = epsv * xb.y + acc[5];
        o[6] = epsv * xb.z + acc[6];
        o[7] = epsv * xb.w + acc[7];

        unsigned hiw[4], low[4];
        #pragma unroll
        for (int j = 0; j < 4; ++j) {
            unsigned short h0 = f2bf(o[2 * j]);
            unsigned short h1 = f2bf(o[2 * j + 1]);
            unsigned short l0 = f2bf(o[2 * j] - bf2f(h0));
            unsigned short l1 = f2bf(o[2 * j + 1] - bf2f(h1));
            hiw[j] = (unsigned)h0 | ((unsigned)h1 << 16);
            low[j] = (unsigned)l0 | ((unsigned)l1 << 16);
        }
        ((uint4*)(hhi + (size_t)n * DIM))[c] = make_uint4(hiw[0], hiw[1], hiw[2], hiw[3]);
        ((uint4*)(hlo + (size_t)n * DIM))[c] = make_uint4(low[0], low[1], low[2], low[3]);
    }
}

// ---------------------------------------------------------------------------
// Fused MLP via MFMA: 64-node tile / 256-thread block, 80KB LDS -> 2/CU.
// W staged from pre-formatted bf16 fragment arrays (plain uint4 copies).
// ---------------------------------------------------------------------------
__global__ __launch_bounds__(256) void fused_mlp(
    const ushort* __restrict__ hhi, const ushort* __restrict__ hlo,
    const ushort* __restrict__ wf1, const ushort* __restrict__ wf2,
    const float* __restrict__ b1,
    const float* __restrict__ lng, const float* __restrict__ lnb,
    const float* __restrict__ b2,
    float* __restrict__ out)
{
    __shared__ short w1s[DIM * DIM];
    __shared__ short w2s[DIM * DIM];
    __shared__ short scr[4 * 16 * DIM];

    #pragma unroll
    for (int i = 0; i < 8; ++i) {
        int idx = i * 256 + threadIdx.x;
        ((uint4*)w1s)[idx] = ((const uint4*)wf1)[idx];
        ((uint4*)w2s)[idx] = ((const uint4*)wf2)[idx];
    }
    __syncthreads();

    const int w  = threadIdx.x >> 6;
    const int l  = threadIdx.x & 63;
    const int lc = l & 15;
    const int lr = l >> 4;

    const int rbase = blockIdx.x * 64 + w * 16;
    const int arow = min(rbase + lc, N_NODES - 1);
    const ushort* hph = hhi + (size_t)arow * DIM;
    const ushort* hpl = hlo + (size_t)arow * DIM;

    float g[8], bb[8], bi1[8], bi2[8];
    #pragma unroll
    for (int nt = 0; nt < 8; ++nt) {
        g[nt]  = lng[nt * 16 + lc];
        bb[nt] = lnb[nt * 16 + lc];
        bi1[nt] = b1[nt * 16 + lc];
        bi2[nt] = b2[nt * 16 + lc];
    }

    f32x4 acc[8];
    #pragma unroll
    for (int nt = 0; nt < 8; ++nt)
        acc[nt] = (f32x4){bi1[nt], bi1[nt], bi1[nt], bi1[nt]};

    #pragma unroll
    for (int kt = 0; kt < 4; ++kt) {
        short8v ahi = *(const short8v*)(hph + kt * 32 + lr * 8);
        short8v alo = *(const short8v*)(hpl + kt * 32 + lr * 8);
        #pragma unroll
        for (int nt = 0; nt < 8; ++nt) {
            short8v bf = *(const short8v*)&w1s[((kt * 8 + nt) * 64 + l) * 8];
            acc[nt] = __builtin_amdgcn_mfma_f32_16x16x32_bf16(ahi, bf, acc[nt], 0, 0, 0);
            acc[nt] = __builtin_amdgcn_mfma_f32_16x16x32_bf16(alo, bf, acc[nt], 0, 0, 0);
        }
    }

    #pragma unroll
    for (int r = 0; r < 4; ++r) {
        float s1 = 0.f, s2 = 0.f;
        #pragma unroll
        for (int nt = 0; nt < 8; ++nt) { float v = acc[nt][r]; s1 += v; s2 += v * v; }
        s1 += __shfl_xor(s1, 1);  s2 += __shfl_xor(s2, 1);
        s1 += __shfl_xor(s1, 2);  s2 += __shfl_xor(s2, 2);
        s1 += __shfl_xor(s1, 4);  s2 += __shfl_xor(s2, 4);
        s1 += __shfl_xor(s1, 8);  s2 += __shfl_xor(s2, 8);
        float mu  = s1 * (1.0f / DIM);
        float var = s2 * (1.0f / DIM) - mu * mu;
        float rsd = rsqrtf(var + 1e-5f);
        int row = lr * 4 + r;
        #pragma unroll
        for (int nt = 0; nt < 8; ++nt) {
            float v = (acc[nt][r] - mu) * rsd * g[nt] + bb[nt];
            v = fmaxf(v, 0.f);
            int cidx = nt * 16 + lc;
            scr[w * 2048 + row * 128 + (((cidx >> 3) ^ row) << 3) + (cidx & 7)]
                = (short)f2bf(v);
        }
    }

    f32x4 acc2[8];
    #pragma unroll
    for (int nt = 0; nt < 8; ++nt)
        acc2[nt] = (f32x4){bi2[nt], bi2[nt], bi2[nt], bi2[nt]};

    #pragma unroll
    for (int kt = 0; kt < 4; ++kt) {
        short8v a2 = *(const short8v*)&scr[w * 2048 + lc * 128 + (((kt * 4 + lr) ^ lc) << 3)];
        #pragma unroll
        for (int nt = 0; nt < 8; ++nt) {
            short8v bf = *(const short8v*)&w2s[((kt * 8 + nt) * 64 + l) * 8];
            acc2[nt] = __builtin_amdgcn_mfma_f32_16x16x32_bf16(a2, bf, acc2[nt], 0, 0, 0);
        }
    }

    #pragma unroll
    for (int r = 0; r < 4; ++r) {
        int orow = rbase + lr * 4 + r;
        if (orow < N_NODES) {
            #pragma unroll
            for (int nt = 0; nt < 8; ++nt)
                out[(size_t)orow * DIM + nt * 16 + lc] = acc2[nt][r];
        }
    }
}

extern "C" void kernel_launch(void* const* d_in, const int* in_sizes, int n_in,
                              void* d_out, int out_size, void* d_ws, size_t ws_size,
                              hipStream_t stream) {
    const float* x    = (const float*)d_in[0];
    const int*   ei   = (const int*)d_in[1];
    const int*   ea   = (const int*)d_in[2];
    const float* emb  = (const float*)d_in[3];
    const float* epsp = (const float*)d_in[4];
    const float* W1   = (const float*)d_in[5];
    const float* b1   = (const float*)d_in[6];
    const float* lng  = (const float*)d_in[7];
    const float* lnb  = (const float*)d_in[8];
    const float* W2   = (const float*)d_in[9];
    const float* b2   = (const float*)d_in[10];
    float* out = (float*)d_out;

    // workspace layout (bytes)
    char* ws = (char*)d_ws;
    int* bk     = (int*)(ws);                 // [NBUK+1] = 3132 B
    int* bsums  = (int*)(ws + 4096);          // [NSC]
    ushort* wf1 = (ushort*)(ws + 8192);       // [16384] bf16 W1 frags
    ushort* wf2 = (ushort*)(ws + 40960);      // [16384] bf16 W2 frags
    int* cnts   = (int*)(ws + 81920);         // [NCNT] (scan in-place -> ebase)
    int* ebuf   = (int*)(ws + 1310720);       // [N_EDGES] -> ends 7,710,720
    ushort* hhi = (ushort*)(ws + 8025984);    // [N,128] bf16 hi
    ushort* hlo = (ushort*)(ws + 33625984);   // [N,128] bf16 lo
    ushort* xh  = (ushort*)(ws + 59225984);   // [N,128] fp16
    const size_t NEED = 59225984 + (size_t)N_NODES * DIM * 2;   // ~84.8 MB

    const int use_f16 = (ws_size >= NEED) ? 1 : 0;

    hist2_conv<<<NBLK, 256, 0, stream>>>(ei, cnts, x, xh, use_f16);
    scanA<<<NSC, 256, 0, stream>>>(cnts, bsums);
    scanB<<<1, 512, 0, stream>>>(bsums);
    scanC_prepw<<<(NCNT + 255) / 256, 256, 0, stream>>>(
        cnts, bsums, bk, W1, W2, wf1, wf2);
    pass2_scatter<<<NBLK, 256, 0, stream>>>(ei, ea, cnts, ebuf);

    if (use_f16) {
        sort_gather<1><<<NBUK, 512, 0, stream>>>(
            bk, ebuf, x, xh, emb, epsp, hhi, hlo);
    } else {
        sort_gather<0><<<NBUK, 512, 0, stream>>>(
            bk, ebuf, x, xh, emb, epsp, hhi, hlo);
    }

    fused_mlp<<<(N_NODES + 63) / 64, 256, 0, stream>>>(
        hhi, hlo, wf1, wf2, b1, lng, lnb, b2, out);
}

// Round 14
// 158.557 us; speedup vs baseline: 4.2982x; 1.0016x over previous
//
#include <hip/hip_runtime.h>
#include <hip/hip_fp16.h>

#define N_NODES 100000
#define N_EDGES 1600000
#define DIM 128
#define NBUK 782      // ceil(N_NODES / 128), bucket = dst >> 7
#define EPB 4096      // edges per block in hist / scatter
#define NBLK 391      // ceil(N_EDGES / EPB)
#define NCNT (NBUK * NBLK)   // 305762 (bucket,block) counters
#define NSC 299       // ceil(NCNT / 1024) scan blocks
#define CAPB 2720     // max edges per bucket (mean 2048, +14 sigma)

typedef __attribute__((ext_vector_type(8))) short short8v;
typedef __attribute__((ext_vector_type(4))) float f32x4;
typedef _Float16 h2 __attribute__((ext_vector_type(2)));

__device__ __forceinline__ unsigned short f2bf(float f) {
    unsigned u = __float_as_uint(f);
    unsigned r = u + 0x7FFFu + ((u >> 16) & 1u);   // RTN-even
    return (unsigned short)(r >> 16);
}
__device__ __forceinline__ float bf2f(unsigned short b) {
    return __uint_as_float(((unsigned)b) << 16);
}

// ---------------------------------------------------------------------------
// 1) per-block bucket histogram + x->fp16 conversion (merged)
// ---------------------------------------------------------------------------
__global__ __launch_bounds__(256) void hist2_conv(
    const int* __restrict__ ei, int* __restrict__ cnts,
    const float* __restrict__ x, ushort* __restrict__ xh, int do_conv)
{
    __shared__ int cnt[NBUK];
    for (int i = threadIdx.x; i < NBUK; i += 256) cnt[i] = 0;

    if (do_conv) {
        for (int i = blockIdx.x * 256 + threadIdx.x; i < N_NODES * DIM / 4;
             i += NBLK * 256) {
            float4 v = ((const float4*)x)[i];
            ushort4 o;
            o.x = __half_as_ushort(__float2half(v.x));
            o.y = __half_as_ushort(__float2half(v.y));
            o.z = __half_as_ushort(__float2half(v.z));
            o.w = __half_as_ushort(__float2half(v.w));
            ((ushort4*)xh)[i] = o;
        }
    }
    __syncthreads();

    int e0 = blockIdx.x * EPB;
    int e1 = min(e0 + EPB, N_EDGES);
    for (int e = e0 + threadIdx.x; e < e1; e += 256)
        atomicAdd(&cnt[ei[N_EDGES + e] >> 7], 1);
    __syncthreads();
    for (int b = threadIdx.x; b < NBUK; b += 256)
        cnts[b * NBLK + blockIdx.x] = cnt[b];
}

// ---------------------------------------------------------------------------
// 2) exclusive scan of NCNT counts, IN-PLACE on cnts (3 kernels)
// ---------------------------------------------------------------------------
__global__ __launch_bounds__(256) void scanA(
    int* __restrict__ cnts, int* __restrict__ bsums)
{
    __shared__ int s[256];
    int t = threadIdx.x;
    int base = blockIdx.x * 1024 + t * 4;
    int v0 = (base + 0 < NCNT) ? cnts[base + 0] : 0;
    int v1 = (base + 1 < NCNT) ? cnts[base + 1] : 0;
    int v2 = (base + 2 < NCNT) ? cnts[base + 2] : 0;
    int v3 = (base + 3 < NCNT) ? cnts[base + 3] : 0;
    int sum = v0 + v1 + v2 + v3;
    s[t] = sum;
    __syncthreads();
    for (int off = 1; off < 256; off <<= 1) {
        int x = (t >= off) ? s[t - off] : 0;
        __syncthreads();
        s[t] += x;
        __syncthreads();
    }
    int excl = s[t] - sum;
    if (base + 0 < NCNT) cnts[base + 0] = excl;  excl += v0;
    if (base + 1 < NCNT) cnts[base + 1] = excl;  excl += v1;
    if (base + 2 < NCNT) cnts[base + 2] = excl;  excl += v2;
    if (base + 3 < NCNT) cnts[base + 3] = excl;
    if (t == 255) bsums[blockIdx.x] = s[255];
}

__global__ __launch_bounds__(512) void scanB(int* __restrict__ bsums)
{
    __shared__ int s[512];
    int t = threadIdx.x;
    int v = (t < NSC) ? bsums[t] : 0;
    s[t] = v;
    __syncthreads();
    for (int off = 1; off < 512; off <<= 1) {
        int x = (t >= off) ? s[t - off] : 0;
        __syncthreads();
        s[t] += x;
        __syncthreads();
    }
    if (t < NSC) bsums[t] = s[t] - v;   // exclusive
}

// scanC + prep_w folded
__global__ __launch_bounds__(256) void scanC_prepw(
    int* __restrict__ ebase, const int* __restrict__ bsums, int* __restrict__ bk,
    const float* __restrict__ W1, const float* __restrict__ W2,
    ushort* __restrict__ wf1, ushort* __restrict__ wf2)
{
    int i = blockIdx.x * 256 + threadIdx.x;
    if (i < NCNT) {
        int v = ebase[i] + bsums[i >> 10];
        ebase[i] = v;
        if (i % NBLK == 0) bk[i / NBLK] = v;   // bucket base
    }
    if (i == 0) bk[NBUK] = N_EDGES;

    if (i < DIM * DIM) {   // prep_w: fragment layout
        int lane = (i >> 3) & 63;
        int j = i & 7;
        int frag = i >> 9;
        int kt = frag >> 3, nt = frag & 7;
        int k = kt * 32 + (lane >> 4) * 8 + j;
        int n = nt * 16 + (lane & 15);
        wf1[i] = f2bf(W1[k * DIM + n]);
        wf2[i] = f2bf(W2[k * DIM + n]);
    }
}

// ---------------------------------------------------------------------------
// 3) scatter: payload = src | attr<<17 | dst_local<<19 (7 bits)
// ---------------------------------------------------------------------------
__global__ __launch_bounds__(256) void pass2_scatter(
    const int* __restrict__ ei, const int* __restrict__ ea,
    const int* __restrict__ ebase, int* __restrict__ ebuf)
{
    __shared__ int cnt[NBUK];
    __shared__ int mybase[NBUK];
    for (int i = threadIdx.x; i < NBUK; i += 256) {
        cnt[i] = 0;
        mybase[i] = ebase[i * NBLK + blockIdx.x];
    }
    __syncthreads();
    int e0 = blockIdx.x * EPB;
    int e1 = min(e0 + EPB, N_EDGES);
    for (int e = e0 + threadIdx.x; e < e1; e += 256) {
        int src = ei[e];
        int dst = ei[N_EDGES + e];
        int at  = ea[e];
        int pay = src | (at << 17) | ((dst & 127) << 19);
        int b   = dst >> 7;
        int r   = atomicAdd(&cnt[b], 1);
        ebuf[mybase[b] + r] = pay;
    }
}

// ---------------------------------------------------------------------------
// 4) FUSED per-bucket sort + gather, LOW-LDS version (no eb[] staging):
// histogram and scatter passes read ebuf directly from global (2nd read is
// L2-hot). LDS ~15.5KB -> 4 blocks/CU (100% occupancy target).
// ---------------------------------------------------------------------------
template<int HI>
__device__ __forceinline__ float h2acc(h2 m2, float acc) {
#if __has_builtin(__builtin_amdgcn_fdot2)
    h2 b;
    b[0] = (_Float16)(HI ? 0.f : 1.f);
    b[1] = (_Float16)(HI ? 1.f : 0.f);
    return __builtin_amdgcn_fdot2(m2, b, acc, false);
#else
    return acc + (float)m2[HI];
#endif
}

__device__ __forceinline__ void edge_acc(
    int pkv, int c, const unsigned* embh, float* acc, uint4 xv)
{
    const uint4 ev = *(const uint4*)&embh[((((unsigned)pkv >> 17) & 3) << 6) | (c << 2)];
    unsigned xs[4] = {xv.x, xv.y, xv.z, xv.w};
    unsigned es[4] = {ev.x, ev.y, ev.z, ev.w};
    const h2 z2 = (h2)(_Float16)0;
    #pragma unroll
    for (int j = 0; j < 4; ++j) {
        h2 a = __builtin_bit_cast(h2, xs[j]);
        h2 b = __builtin_bit_cast(h2, es[j]);
        h2 m2 = __builtin_elementwise_max(a + b, z2);
        acc[2 * j]     = h2acc<0>(m2, acc[2 * j]);
        acc[2 * j + 1] = h2acc<1>(m2, acc[2 * j + 1]);
    }
}

template<int USE16>
__global__ __launch_bounds__(512) void sort_gather(
    const int* __restrict__ bk, const int* __restrict__ ebuf,
    const float* __restrict__ x, const ushort* __restrict__ xh,
    const float* __restrict__ emb, const float* __restrict__ eps_p,
    ushort* __restrict__ hhi, ushort* __restrict__ hlo)
{
    __shared__ int col_l[CAPB];                  // 10.9KB
    __shared__ int deg[128], sc[128], cur[128];  // 1.5KB
    __shared__ unsigned embh[256];               // 1KB (USE16)
    __shared__ float femb[512];                  // 2KB (fallback)

    const int b = blockIdx.x;
    const int t = threadIdx.x;
    const int lo = bk[b];
    const int n_e = min(bk[b + 1] - lo, CAPB);

    if (t < 256) {
        float2 f = ((const float2*)emb)[t];
        if (USE16) {
            __half2 h = __floats2half2_rn(f.x, f.y);
            embh[t] = __builtin_bit_cast(unsigned, h);
        } else {
            femb[2 * t] = f.x;
            femb[2 * t + 1] = f.y;
        }
    }
    if (t < 128) deg[t] = 0;
    __syncthreads();

    // pass 1: histogram (ebuf read directly, coalesced)
    for (int i = t; i < n_e; i += 512)
        atomicAdd(&deg[((unsigned)ebuf[lo + i] >> 19) & 127], 1);
    __syncthreads();

    if (t < 128) sc[t] = deg[t];
    __syncthreads();
    for (int off = 1; off < 128; off <<= 1) {
        int v = 0;
        if (t < 128 && t >= off) v = sc[t - off];
        __syncthreads();
        if (t < 128) sc[t] += v;
        __syncthreads();
    }
    if (t < 128) cur[t] = sc[t] - deg[t];
    __syncthreads();

    // pass 2: scatter into node-sorted LDS list (ebuf re-read, L2-hot)
    for (int i = t; i < n_e; i += 512) {
        int pk = ebuf[lo + i];
        int p = atomicAdd(&cur[((unsigned)pk >> 19) & 127], 1);
        col_l[p] = pk;
    }
    __syncthreads();

    // ---- gather from LDS-sorted list: 32 groups x 16 lanes ----
    const int g = t >> 4, c = t & 15;
    const float epsv = 1.0f + eps_p[0];

    for (int ln = g; ln < 128; ln += 32) {
        int n = b * 128 + ln;
        if (n >= N_NODES) break;
        int start = sc[ln] - deg[ln], end = sc[ln];
        float acc[8] = {0.f, 0.f, 0.f, 0.f, 0.f, 0.f, 0.f, 0.f};

        if (USE16) {
            int p = start;
            for (; p + 4 <= end; p += 4) {
                int pk[4];
                uint4 xv[4];
                #pragma unroll
                for (int u = 0; u < 4; ++u) pk[u] = col_l[p + u];
                #pragma unroll
                for (int u = 0; u < 4; ++u)
                    xv[u] = ((const uint4*)xh)[((pk[u] & 0x1FFFF) << 4) | c];
                #pragma unroll
                for (int u = 0; u < 4; ++u)
                    edge_acc(pk[u], c, embh, acc, xv[u]);
            }
            for (; p < end; ++p) {
                int pkv = col_l[p];
                uint4 xv = ((const uint4*)xh)[((pkv & 0x1FFFF) << 4) | c];
                edge_acc(pkv, c, embh, acc, xv);
            }
        } else {
            for (int p = start; p < end; ++p) {
                int pk = col_l[p];
                const float* xr = x + (size_t)(pk & 0x1FFFF) * DIM;
                float4 xa = ((const float4*)xr)[c * 2];
                float4 xb = ((const float4*)xr)[c * 2 + 1];
                const float* er = &femb[(((unsigned)pk >> 17) & 3) * DIM + c * 8];
                acc[0] += fmaxf(xa.x + er[0], 0.f);
                acc[1] += fmaxf(xa.y + er[1], 0.f);
                acc[2] += fmaxf(xa.z + er[2], 0.f);
                acc[3] += fmaxf(xa.w + er[3], 0.f);
                acc[4] += fmaxf(xb.x + er[4], 0.f);
                acc[5] += fmaxf(xb.y + er[5], 0.f);
                acc[6] += fmaxf(xb.z + er[6], 0.f);
                acc[7] += fmaxf(xb.w + er[7], 0.f);
            }
        }

        float4 xa = ((const float4*)(x + (size_t)n * DIM))[c * 2];
        float4 xb = ((const float4*)(x + (size_t)n * DIM))[c * 2 + 1];
        float o[8];
        o[0] = epsv * xa.x + acc[0];
        o[1] = epsv * xa.y + acc[1];
        o[2] = epsv * xa.z + acc[2];
        o[3] = epsv * xa.w + acc[3];
        o[4] = epsv * xb.x + acc[4];
        o[5] = epsv * xb.y + acc[5];
        o[6] = epsv * xb.z + acc[6];
        o[7] = epsv * xb.w + acc[7];

        unsigned hiw[4], low[4];
        #pragma unroll
        for (int j = 0; j < 4; ++j) {
            unsigned short h0 = f2bf(o[2 * j]);
            unsigned short h1 = f2bf(o[2 * j + 1]);
            unsigned short l0 = f2bf(o[2 * j] - bf2f(h0));
            unsigned short l1 = f2bf(o[2 * j + 1] - bf2f(h1));
            hiw[j] = (unsigned)h0 | ((unsigned)h1 << 16);
            low[j] = (unsigned)l0 | ((unsigned)l1 << 16);
        }
        ((uint4*)(hhi + (size_t)n * DIM))[c] = make_uint4(hiw[0], hiw[1], hiw[2], hiw[3]);
        ((uint4*)(hlo + (size_t)n * DIM))[c] = make_uint4(low[0], low[1], low[2], low[3]);
    }
}

// ---------------------------------------------------------------------------
// Fused MLP via MFMA: 64-node tile / 256-thread block, 80KB LDS -> 2/CU.
// ---------------------------------------------------------------------------
__global__ __launch_bounds__(256) void fused_mlp(
    const ushort* __restrict__ hhi, const ushort* __restrict__ hlo,
    const ushort* __restrict__ wf1, const ushort* __restrict__ wf2,
    const float* __restrict__ b1,
    const float* __restrict__ lng, const float* __restrict__ lnb,
    const float* __restrict__ b2,
    float* __restrict__ out)
{
    __shared__ short w1s[DIM * DIM];
    __shared__ short w2s[DIM * DIM];
    __shared__ short scr[4 * 16 * DIM];

    #pragma unroll
    for (int i = 0; i < 8; ++i) {
        int idx = i * 256 + threadIdx.x;
        ((uint4*)w1s)[idx] = ((const uint4*)wf1)[idx];
        ((uint4*)w2s)[idx] = ((const uint4*)wf2)[idx];
    }
    __syncthreads();

    const int w  = threadIdx.x >> 6;
    const int l  = threadIdx.x & 63;
    const int lc = l & 15;
    const int lr = l >> 4;

    const int rbase = blockIdx.x * 64 + w * 16;
    const int arow = min(rbase + lc, N_NODES - 1);
    const ushort* hph = hhi + (size_t)arow * DIM;
    const ushort* hpl = hlo + (size_t)arow * DIM;

    float g[8], bb[8], bi1[8], bi2[8];
    #pragma unroll
    for (int nt = 0; nt < 8; ++nt) {
        g[nt]  = lng[nt * 16 + lc];
        bb[nt] = lnb[nt * 16 + lc];
        bi1[nt] = b1[nt * 16 + lc];
        bi2[nt] = b2[nt * 16 + lc];
    }

    f32x4 acc[8];
    #pragma unroll
    for (int nt = 0; nt < 8; ++nt)
        acc[nt] = (f32x4){bi1[nt], bi1[nt], bi1[nt], bi1[nt]};

    #pragma unroll
    for (int kt = 0; kt < 4; ++kt) {
        short8v ahi = *(const short8v*)(hph + kt * 32 + lr * 8);
        short8v alo = *(const short8v*)(hpl + kt * 32 + lr * 8);
        #pragma unroll
        for (int nt = 0; nt < 8; ++nt) {
            short8v bf = *(const short8v*)&w1s[((kt * 8 + nt) * 64 + l) * 8];
            acc[nt] = __builtin_amdgcn_mfma_f32_16x16x32_bf16(ahi, bf, acc[nt], 0, 0, 0);
            acc[nt] = __builtin_amdgcn_mfma_f32_16x16x32_bf16(alo, bf, acc[nt], 0, 0, 0);
        }
    }

    #pragma unroll
    for (int r = 0; r < 4; ++r) {
        float s1 = 0.f, s2 = 0.f;
        #pragma unroll
        for (int nt = 0; nt < 8; ++nt) { float v = acc[nt][r]; s1 += v; s2 += v * v; }
        s1 += __shfl_xor(s1, 1);  s2 += __shfl_xor(s2, 1);
        s1 += __shfl_xor(s1, 2);  s2 += __shfl_xor(s2, 2);
        s1 += __shfl_xor(s1, 4);  s2 += __shfl_xor(s2, 4);
        s1 += __shfl_xor(s1, 8);  s2 += __shfl_xor(s2, 8);
        float mu  = s1 * (1.0f / DIM);
        float var = s2 * (1.0f / DIM) - mu * mu;
        float rsd = rsqrtf(var + 1e-5f);
        int row = lr * 4 + r;
        #pragma unroll
        for (int nt = 0; nt < 8; ++nt) {
            float v = (acc[nt][r] - mu) * rsd * g[nt] + bb[nt];
            v = fmaxf(v, 0.f);
            int cidx = nt * 16 + lc;
            scr[w * 2048 + row * 128 + (((cidx >> 3) ^ row) << 3) + (cidx & 7)]
                = (short)f2bf(v);
        }
    }

    f32x4 acc2[8];
    #pragma unroll
    for (int nt = 0; nt < 8; ++nt)
        acc2[nt] = (f32x4){bi2[nt], bi2[nt], bi2[nt], bi2[nt]};

    #pragma unroll
    for (int kt = 0; kt < 4; ++kt) {
        short8v a2 = *(const short8v*)&scr[w * 2048 + lc * 128 + (((kt * 4 + lr) ^ lc) << 3)];
        #pragma unroll
        for (int nt = 0; nt < 8; ++nt) {
            short8v bf = *(const short8v*)&w2s[((kt * 8 + nt) * 64 + l) * 8];
            acc2[nt] = __builtin_amdgcn_mfma_f32_16x16x32_bf16(a2, bf, acc2[nt], 0, 0, 0);
        }
    }

    #pragma unroll
    for (int r = 0; r < 4; ++r) {
        int orow = rbase + lr * 4 + r;
        if (orow < N_NODES) {
            #pragma unroll
            for (int nt = 0; nt < 8; ++nt)
                out[(size_t)orow * DIM + nt * 16 + lc] = acc2[nt][r];
        }
    }
}

extern "C" void kernel_launch(void* const* d_in, const int* in_sizes, int n_in,
                              void* d_out, int out_size, void* d_ws, size_t ws_size,
                              hipStream_t stream) {
    const float* x    = (const float*)d_in[0];
    const int*   ei   = (const int*)d_in[1];
    const int*   ea   = (const int*)d_in[2];
    const float* emb  = (const float*)d_in[3];
    const float* epsp = (const float*)d_in[4];
    const float* W1   = (const float*)d_in[5];
    const float* b1   = (const float*)d_in[6];
    const float* lng  = (const float*)d_in[7];
    const float* lnb  = (const float*)d_in[8];
    const float* W2   = (const float*)d_in[9];
    const float* b2   = (const float*)d_in[10];
    float* out = (float*)d_out;

    // workspace layout (bytes)
    char* ws = (char*)d_ws;
    int* bk     = (int*)(ws);                 // [NBUK+1]
    int* bsums  = (int*)(ws + 4096);          // [NSC]
    ushort* wf1 = (ushort*)(ws + 8192);       // [16384] bf16 W1 frags
    ushort* wf2 = (ushort*)(ws + 40960);      // [16384] bf16 W2 frags
    int* cnts   = (int*)(ws + 81920);         // [NCNT] (scan in-place -> ebase)
    int* ebuf   = (int*)(ws + 1310720);       // [N_EDGES]
    ushort* hhi = (ushort*)(ws + 8025984);    // [N,128] bf16 hi
    ushort* hlo = (ushort*)(ws + 33625984);   // [N,128] bf16 lo
    ushort* xh  = (ushort*)(ws + 59225984);   // [N,128] fp16
    const size_t NEED = 59225984 + (size_t)N_NODES * DIM * 2;   // ~84.8 MB

    const int use_f16 = (ws_size >= NEED) ? 1 : 0;

    hist2_conv<<<NBLK, 256, 0, stream>>>(ei, cnts, x, xh, use_f16);
    scanA<<<NSC, 256, 0, stream>>>(cnts, bsums);
    scanB<<<1, 512, 0, stream>>>(bsums);
    scanC_prepw<<<(NCNT + 255) / 256, 256, 0, stream>>>(
        cnts, bsums, bk, W1, W2, wf1, wf2);
    pass2_scatter<<<NBLK, 256, 0, stream>>>(ei, ea, cnts, ebuf);

    if (use_f16) {
        sort_gather<1><<<NBUK, 512, 0, stream>>>(
            bk, ebuf, x, xh, emb, epsp, hhi, hlo);
    } else {
        sort_gather<0><<<NBUK, 512, 0, stream>>>(
            bk, ebuf, x, xh, emb, epsp, hhi, hlo);
    }

    fused_mlp<<<(N_NODES + 63) / 64, 256, 0, stream>>>(
        hhi, hlo, wf1, wf2, b1, lng, lnb, b2, out);
}